// Round 1
// baseline (3546.723 us; speedup 1.0000x reference)
//
#include <hip/hip_runtime.h>
#include <hip/hip_bf16.h>
#include <cmath>

// ============================================================================
// System2Graph fused pipeline, MI355X (gfx950)
// out = codebook[argmin_c ||uf - codebook[c]||^2]  (straight-through => gather)
// Precision: split-bf16 MFMA (hi/lo, 3 terms) ~ 2^-16 rel err so VQ argmin
// matches the f32 reference.
// ============================================================================

typedef __bf16 bf16x8 __attribute__((ext_vector_type(8)));
typedef float  f32x4  __attribute__((ext_vector_type(4)));

#define BM 128
#define BN 128
#define BK 32
#define LDP 40   // LDS row pitch in bf16 elems (32 + 8 pad -> 80B rows, 16B aligned)

__device__ __forceinline__ unsigned short f2bf(float f) {
    unsigned int u = __builtin_bit_cast(unsigned int, f);
    u += 0x7fffu + ((u >> 16) & 1u);          // RNE
    return (unsigned short)(u >> 16);
}
__device__ __forceinline__ float bf2f(unsigned short h) {
    unsigned int u = ((unsigned int)h) << 16;
    return __builtin_bit_cast(float, u);
}
__device__ __forceinline__ float gelu_f(float v) {
    return 0.5f * v * (1.0f + erff(v * 0.7071067811865476f));
}

// ---------------------------------------------------------------------------
// Split-bf16 GEMM, 128x128 tile, BK=32, 4 waves, 16x16x32 bf16 MFMA.
// MODE 0: de_proj[f,513,1024] = delta_table @ Wl[f][2048:3072]      (K=1024)
// MODE 1: hpre_chunk = [rf | x] @ (Wl[f] rows 1024..2048 | 0..1024) (K=2048)
// MODE 2: gate_pre[f] = [x | arg_f] @ (Wg[f] rows 0..1024 | (1024..2048)+(2048..3072)) (K=2048)
// ---------------------------------------------------------------------------
template<int MODE>
__global__ __launch_bounds__(256, 2) void gemm_split_kernel(
    const float* __restrict__ A0, const float* __restrict__ A1,
    const float* __restrict__ W, float* __restrict__ Cout,
    int f_arg, int row_base)
{
    __shared__ __align__(16) unsigned short Ahi[BM * LDP];
    __shared__ __align__(16) unsigned short Alo[BM * LDP];
    __shared__ __align__(16) unsigned short Bhi[BN * LDP];
    __shared__ __align__(16) unsigned short Blo[BN * LDP];

    const int tid = threadIdx.x;
    const int f   = (MODE == 1) ? f_arg : (int)blockIdx.z;
    const int bm0 = blockIdx.x * BM;
    const int bn0 = blockIdx.y * BN;

    const float* Bf = W + (size_t)f * (3072 * 1024);
    float* Cp;
    if constexpr (MODE == 0)      Cp = Cout + (size_t)f * (513 * 1024);
    else if constexpr (MODE == 1) Cp = Cout;                       // chunk buffer
    else                          Cp = Cout + (size_t)f * (4096 * 1024);
    const float* A1f = (MODE == 2) ? (A1 + (size_t)f * (4096 * 1024)) : A1;

    const int KSTEPS = (MODE == 0) ? 32 : 64;

    const int wid = tid >> 6, lane = tid & 63;
    const int wr = (wid >> 1) * 64, wc = (wid & 1) * 64;
    const int g = lane >> 4, rl = lane & 15;

    f32x4 acc[4][4];
    f32x4 zero = {0.f, 0.f, 0.f, 0.f};
#pragma unroll
    for (int i = 0; i < 4; ++i)
#pragma unroll
        for (int j = 0; j < 4; ++j) acc[i][j] = zero;

    for (int kt = 0; kt < KSTEPS; ++kt) {
        const int kc0 = kt * BK;
        __syncthreads();
        // ---- stage A tile (128 x 32 f32 -> hi/lo bf16, row-major k-inner) ----
#pragma unroll
        for (int i = 0; i < 4; ++i) {
            int q = tid + i * 256;          // float4 slot 0..1023
            int row_l = q >> 3, kq = q & 7;
            int c = kc0 + kq * 4;
            int r = row_base + bm0 + row_l;
            const float* src;
            if constexpr (MODE == 0) {
                int rc = r > 512 ? 512 : r;  // clamp padded rows in-bounds
                src = A0 + (size_t)rc * 1024 + c;
            } else if constexpr (MODE == 1) {
                src = (c < 1024) ? (A0 + (size_t)r * 1024 + c)
                                 : (A1 + (size_t)(r >> 2) * 1024 + (c - 1024));
            } else {
                src = (c < 1024) ? (A0 + (size_t)r * 1024 + c)
                                 : (A1f + (size_t)r * 1024 + (c - 1024));
            }
            float4 v = *(const float4*)src;
            ushort4 h4, l4;
            h4.x = f2bf(v.x); l4.x = f2bf(v.x - bf2f(h4.x));
            h4.y = f2bf(v.y); l4.y = f2bf(v.y - bf2f(h4.y));
            h4.z = f2bf(v.z); l4.z = f2bf(v.z - bf2f(h4.z));
            h4.w = f2bf(v.w); l4.w = f2bf(v.w - bf2f(h4.w));
            int base = row_l * LDP + kq * 4;
            *(ushort4*)&Ahi[base] = h4;
            *(ushort4*)&Alo[base] = l4;
        }
        // ---- stage B tile (32 x 128 f32 -> transposed hi/lo bf16 col-major k-inner) ----
#pragma unroll
        for (int i = 0; i < 4; ++i) {
            int q = tid + i * 256;
            int crow = q >> 5, colq = q & 31;
            int c = kc0 + crow;
            int col = bn0 + colq * 4;
            float4 v;
            if constexpr (MODE == 0) {
                v = *(const float4*)(Bf + (size_t)(2048 + c) * 1024 + col);
            } else if constexpr (MODE == 1) {
                int brow = (c < 1024) ? (1024 + c) : (c - 1024);
                v = *(const float4*)(Bf + (size_t)brow * 1024 + col);
            } else {
                if (c < 1024) {
                    v = *(const float4*)(Bf + (size_t)c * 1024 + col);
                } else {
                    float4 v1 = *(const float4*)(Bf + (size_t)c * 1024 + col);
                    float4 v2 = *(const float4*)(Bf + (size_t)(c + 1024) * 1024 + col);
                    v.x = v1.x + v2.x; v.y = v1.y + v2.y;
                    v.z = v1.z + v2.z; v.w = v1.w + v2.w;
                }
            }
            int cl = colq * 4;
            unsigned short h;
            h = f2bf(v.x); Bhi[(cl+0)*LDP + crow] = h; Blo[(cl+0)*LDP + crow] = f2bf(v.x - bf2f(h));
            h = f2bf(v.y); Bhi[(cl+1)*LDP + crow] = h; Blo[(cl+1)*LDP + crow] = f2bf(v.y - bf2f(h));
            h = f2bf(v.z); Bhi[(cl+2)*LDP + crow] = h; Blo[(cl+2)*LDP + crow] = f2bf(v.z - bf2f(h));
            h = f2bf(v.w); Bhi[(cl+3)*LDP + crow] = h; Blo[(cl+3)*LDP + crow] = f2bf(v.w - bf2f(h));
        }
        __syncthreads();
        // ---- fragments + MFMA (hi*hi + hi*lo + lo*hi) ----
        bf16x8 ah[4], alo[4], bh[4], blo[4];
#pragma unroll
        for (int mi = 0; mi < 4; ++mi) {
            int rowi = wr + mi * 16 + rl;
            ah[mi]  = *(const bf16x8*)&Ahi[rowi * LDP + g * 8];
            alo[mi] = *(const bf16x8*)&Alo[rowi * LDP + g * 8];
        }
#pragma unroll
        for (int ni = 0; ni < 4; ++ni) {
            int coli = wc + ni * 16 + rl;
            bh[ni]  = *(const bf16x8*)&Bhi[coli * LDP + g * 8];
            blo[ni] = *(const bf16x8*)&Blo[coli * LDP + g * 8];
        }
#pragma unroll
        for (int mi = 0; mi < 4; ++mi)
#pragma unroll
            for (int ni = 0; ni < 4; ++ni) {
                acc[mi][ni] = __builtin_amdgcn_mfma_f32_16x16x32_bf16(ah[mi],  bh[ni],  acc[mi][ni], 0, 0, 0);
                acc[mi][ni] = __builtin_amdgcn_mfma_f32_16x16x32_bf16(ah[mi],  blo[ni], acc[mi][ni], 0, 0, 0);
                acc[mi][ni] = __builtin_amdgcn_mfma_f32_16x16x32_bf16(alo[mi], bh[ni],  acc[mi][ni], 0, 0, 0);
            }
    }
    // ---- epilogue: C/D layout col=lane&15, row=(lane>>4)*4+i (m89-verified) ----
    const int cg = lane & 15;
    const int rg = (lane >> 4) * 4;
#pragma unroll
    for (int mi = 0; mi < 4; ++mi) {
#pragma unroll
        for (int i = 0; i < 4; ++i) {
            int row_out = bm0 + wr + mi * 16 + rg + i;
            if constexpr (MODE == 0) { if (row_out >= 513) continue; }
#pragma unroll
            for (int ni = 0; ni < 4; ++ni) {
                int col = bn0 + wc + ni * 16 + cg;
                Cp[(size_t)row_out * 1024 + col] = acc[mi][ni][i];
            }
        }
    }
}

// ---------------------------------------------------------------------------
// Fused: h = hpre + de_proj[idx] + bl -> GELU -> LayerNorm -> *ln_g + ln_b
//        arg[f,n,:] = sum_k softmax(sim)[n,k] * h[k,:]
// One block per token; wave k handles row (n,k).
// ---------------------------------------------------------------------------
__global__ __launch_bounds__(256) void ln_fuse_kernel(
    const float* __restrict__ hpre, const float* __restrict__ de_proj,
    const float* __restrict__ bl, const float* __restrict__ ln_g,
    const float* __restrict__ ln_b, const float* __restrict__ sim,
    const int* __restrict__ topk, float* __restrict__ arg,
    int f, int token_base)
{
    __shared__ float red[4 * 1024];
    const int n = token_base + blockIdx.x;
    const int k = threadIdx.x >> 6, lane = threadIdx.x & 63;
    const float* hrow = hpre + ((size_t)blockIdx.x * 4 + k) * 1024;
    const int t  = n & 1023;
    const int tk = topk[(size_t)n * 4 + k];
    int di = t - tk + 256; di = di < 0 ? 0 : (di > 512 ? 512 : di);
    const float* drow = de_proj + ((size_t)f * 513 + di) * 1024;
    const float* blr = bl + f * 1024;
    const float* gr  = ln_g + f * 1024;
    const float* br  = ln_b + f * 1024;

    // softmax over sim[n, 0..3]
    float4 s4 = *(const float4*)&sim[(size_t)n * 4];
    float smax = fmaxf(fmaxf(s4.x, s4.y), fmaxf(s4.z, s4.w));
    float e0 = expf(s4.x - smax), e1 = expf(s4.y - smax);
    float e2 = expf(s4.z - smax), e3 = expf(s4.w - smax);
    float swk = (k == 0 ? e0 : k == 1 ? e1 : k == 2 ? e2 : e3) / (e0 + e1 + e2 + e3);

    float gv[16];
    float ssum = 0.f;
#pragma unroll
    for (int j = 0; j < 4; ++j) {
        int d4 = lane + j * 64;
        float4 h  = *(const float4*)&hrow[d4 * 4];
        float4 dd = *(const float4*)&drow[d4 * 4];
        float4 bb = *(const float4*)&blr[d4 * 4];
        float a0 = gelu_f(h.x + dd.x + bb.x);
        float a1 = gelu_f(h.y + dd.y + bb.y);
        float a2 = gelu_f(h.z + dd.z + bb.z);
        float a3 = gelu_f(h.w + dd.w + bb.w);
        gv[j*4+0] = a0; gv[j*4+1] = a1; gv[j*4+2] = a2; gv[j*4+3] = a3;
        ssum += a0 + a1 + a2 + a3;
    }
    for (int o = 32; o; o >>= 1) ssum += __shfl_xor(ssum, o);
    float mu = ssum * 0.0009765625f;
    float vs = 0.f;
#pragma unroll
    for (int i = 0; i < 16; ++i) { float dm = gv[i] - mu; vs += dm * dm; }
    for (int o = 32; o; o >>= 1) vs += __shfl_xor(vs, o);
    float rstd = 1.0f / sqrtf(vs * 0.0009765625f + 1e-5f);
#pragma unroll
    for (int j = 0; j < 4; ++j) {
        int d4 = lane + j * 64;
        float4 g4 = *(const float4*)&gr[d4 * 4];
        float4 b4 = *(const float4*)&br[d4 * 4];
        float4 y;
        y.x = ((gv[j*4+0] - mu) * rstd * g4.x + b4.x) * swk;
        y.y = ((gv[j*4+1] - mu) * rstd * g4.y + b4.y) * swk;
        y.z = ((gv[j*4+2] - mu) * rstd * g4.z + b4.z) * swk;
        y.w = ((gv[j*4+3] - mu) * rstd * g4.w + b4.w) * swk;
        *(float4*)&red[k * 1024 + d4 * 4] = y;
    }
    __syncthreads();
    const int p = threadIdx.x;     // float4 index 0..255
    float4 r0 = *(const float4*)&red[0 * 1024 + p * 4];
    float4 r1 = *(const float4*)&red[1 * 1024 + p * 4];
    float4 r2 = *(const float4*)&red[2 * 1024 + p * 4];
    float4 r3 = *(const float4*)&red[3 * 1024 + p * 4];
    float4 o;
    o.x = r0.x + r1.x + r2.x + r3.x;
    o.y = r0.y + r1.y + r2.y + r3.y;
    o.z = r0.z + r1.z + r2.z + r3.z;
    o.w = r0.w + r1.w + r2.w + r3.w;
    *(float4*)&arg[((size_t)f * 4096 + n) * 1024 + p * 4] = o;
}

// ---------------------------------------------------------------------------
// Final: fw = softmax(x@Wsel+bsel); uf = (sum_f fw*arg) * (sum_f fw*sigmoid(gate_pre+bg));
// VQ argmin (first-index tie-break) over 32 codes; out = codebook[enc].
// One block per token.
// ---------------------------------------------------------------------------
__global__ __launch_bounds__(256) void final_kernel(
    const float* __restrict__ x, const float* __restrict__ Wsel,
    const float* __restrict__ bsel, const float* __restrict__ arg,
    const float* __restrict__ gate_pre, const float* __restrict__ bg,
    const float* __restrict__ cb, float* __restrict__ out)
{
    __shared__ float sred[16];
    __shared__ float uf_s[1024];
    __shared__ float score_s[32];
    __shared__ int enc_s;
    const int n = blockIdx.x;
    const int tid = threadIdx.x, w = tid >> 6, lane = tid & 63;

    // fn-selector logits: each thread covers 4 d's (d = tid*4 + c)
    float4 xv = *(const float4*)&x[(size_t)n * 1024 + tid * 4];
    float pf0 = 0, pf1 = 0, pf2 = 0, pf3 = 0;
    {
        const float* wrp = &Wsel[(size_t)tid * 16];
        pf0 += xv.x * wrp[0];  pf1 += xv.x * wrp[1];  pf2 += xv.x * wrp[2];  pf3 += xv.x * wrp[3];
        pf0 += xv.y * wrp[4];  pf1 += xv.y * wrp[5];  pf2 += xv.y * wrp[6];  pf3 += xv.y * wrp[7];
        pf0 += xv.z * wrp[8];  pf1 += xv.z * wrp[9];  pf2 += xv.z * wrp[10]; pf3 += xv.z * wrp[11];
        pf0 += xv.w * wrp[12]; pf1 += xv.w * wrp[13]; pf2 += xv.w * wrp[14]; pf3 += xv.w * wrp[15];
    }
    for (int o = 32; o; o >>= 1) {
        pf0 += __shfl_xor(pf0, o); pf1 += __shfl_xor(pf1, o);
        pf2 += __shfl_xor(pf2, o); pf3 += __shfl_xor(pf3, o);
    }
    if (lane == 0) { sred[w*4+0] = pf0; sred[w*4+1] = pf1; sred[w*4+2] = pf2; sred[w*4+3] = pf3; }
    __syncthreads();
    float sel0 = sred[0] + sred[4] + sred[8]  + sred[12] + bsel[0];
    float sel1 = sred[1] + sred[5] + sred[9]  + sred[13] + bsel[1];
    float sel2 = sred[2] + sred[6] + sred[10] + sred[14] + bsel[2];
    float sel3 = sred[3] + sred[7] + sred[11] + sred[15] + bsel[3];
    float mx = fmaxf(fmaxf(sel0, sel1), fmaxf(sel2, sel3));
    float f0 = expf(sel0 - mx), f1 = expf(sel1 - mx), f2 = expf(sel2 - mx), f3 = expf(sel3 - mx);
    float inv = 1.0f / (f0 + f1 + f2 + f3);
    float fw[4] = { f0 * inv, f1 * inv, f2 * inv, f3 * inv };

    float4 prop = {0, 0, 0, 0}, gs = {0, 0, 0, 0};
#pragma unroll
    for (int f = 0; f < 4; ++f) {
        size_t off = ((size_t)f * 4096 + n) * 1024 + tid * 4;
        float4 av  = *(const float4*)&arg[off];
        float4 gvv = *(const float4*)&gate_pre[off];
        float4 bgv = *(const float4*)&bg[f * 1024 + tid * 4];
        float wgt = fw[f];
        prop.x += wgt * av.x; prop.y += wgt * av.y; prop.z += wgt * av.z; prop.w += wgt * av.w;
        gs.x += wgt * (1.0f / (1.0f + expf(-(gvv.x + bgv.x))));
        gs.y += wgt * (1.0f / (1.0f + expf(-(gvv.y + bgv.y))));
        gs.z += wgt * (1.0f / (1.0f + expf(-(gvv.z + bgv.z))));
        gs.w += wgt * (1.0f / (1.0f + expf(-(gvv.w + bgv.w))));
    }
    float4 uf;
    uf.x = prop.x * gs.x; uf.y = prop.y * gs.y; uf.z = prop.z * gs.z; uf.w = prop.w * gs.w;
    *(float4*)&uf_s[tid * 4] = uf;
    __syncthreads();

    // wave w handles codes w*8 .. w*8+7: score = ||c||^2 - 2 uf.c  (same argmin as d2)
#pragma unroll
    for (int cc = 0; cc < 8; ++cc) {
        int c = w * 8 + cc;
        float p = 0.f, q = 0.f;
#pragma unroll
        for (int j = 0; j < 4; ++j) {
            int d4 = lane + j * 64;
            float4 u4 = *(const float4*)&uf_s[d4 * 4];
            float4 c4 = *(const float4*)&cb[(size_t)c * 1024 + d4 * 4];
            p += u4.x * c4.x + u4.y * c4.y + u4.z * c4.z + u4.w * c4.w;
            q += c4.x * c4.x + c4.y * c4.y + c4.z * c4.z + c4.w * c4.w;
        }
        float s = q - 2.0f * p;
        for (int o = 32; o; o >>= 1) s += __shfl_xor(s, o);
        if (lane == 0) score_s[c] = s;
    }
    __syncthreads();
    if (tid < 64) {
        float v; int idx;
        if (lane < 32) { v = score_s[lane]; idx = lane; }
        else           { v = INFINITY;      idx = 1 << 30; }
        for (int o = 16; o; o >>= 1) {
            float ov = __shfl_xor(v, o); int oi = __shfl_xor(idx, o);
            if (ov < v || (ov == v && oi < idx)) { v = ov; idx = oi; }
        }
        if (lane == 0) enc_s = idx;
    }
    __syncthreads();
    const int enc = enc_s;
    float4 o4 = *(const float4*)&cb[(size_t)enc * 1024 + tid * 4];
    *(float4*)&out[(size_t)n * 1024 + tid * 4] = o4;
}

// ---------------------------------------------------------------------------
extern "C" void kernel_launch(void* const* d_in, const int* in_sizes, int n_in,
                              void* d_out, int out_size, void* d_ws, size_t ws_size,
                              hipStream_t stream)
{
    const float* x    = (const float*)d_in[0];
    const float* rf   = (const float*)d_in[1];
    const float* sim  = (const float*)d_in[2];
    const float* Wl   = (const float*)d_in[3];
    const float* bl   = (const float*)d_in[4];
    const float* ln_g = (const float*)d_in[5];
    const float* ln_b = (const float*)d_in[6];
    const float* Wg   = (const float*)d_in[7];
    const float* bg   = (const float*)d_in[8];
    const float* Wsel = (const float*)d_in[9];
    const float* bsel = (const float*)d_in[10];
    const float* dtab = (const float*)d_in[11];
    const float* cb   = (const float*)d_in[12];
    const int*   topk = (const int*)d_in[13];
    float* out = (float*)d_out;

    // ws layout: de_proj[4*513*1024] | arg[4*4096*1024] | regionX[2*8192*1024]
    // regionX = two h_pre ping-pong chunks, later reused as gate_pre[4*4096*1024].
    const size_t NEED = ((size_t)4 * 513 * 1024 + (size_t)4 * 4096 * 1024
                         + (size_t)2 * 8192 * 1024) * 4;
    if (ws_size < NEED) return;   // insufficient scratch: bail cleanly

    float* de_proj = (float*)d_ws;
    float* arg     = de_proj + (size_t)4 * 513 * 1024;
    float* regionX = arg + (size_t)4 * 4096 * 1024;
    float* hbuf0   = regionX;
    float* hbuf1   = regionX + (size_t)8192 * 1024;
    float* gate_pre = regionX;

    dim3 blk(256);

    // 1) de_proj = delta_table @ Wl[f][2048:3072]
    gemm_split_kernel<0><<<dim3(5, 8, 4), blk, 0, stream>>>(
        dtab, (const float*)nullptr, Wl, de_proj, 0, 0);

    // 2) stage B: h_pre chunks (8192 rows each) + fused GELU/LN/sw-reduce -> arg
    for (int f = 0; f < 4; ++f) {
        for (int h = 0; h < 2; ++h) {
            float* hb = ((f * 2 + h) & 1) ? hbuf1 : hbuf0;
            gemm_split_kernel<1><<<dim3(64, 8, 1), blk, 0, stream>>>(
                rf, x, Wl, hb, f, h * 8192);
            ln_fuse_kernel<<<dim3(2048), blk, 0, stream>>>(
                hb, de_proj, bl, ln_g, ln_b, sim, topk, arg, f, h * 2048);
        }
    }

    // 3) gate_pre[f] = x @ Wg0 + arg_f @ (Wg1 + Wg2)   (bias+sigmoid in final)
    gemm_split_kernel<2><<<dim3(32, 8, 4), blk, 0, stream>>>(
        x, arg, Wg, gate_pre, 0, 0);

    // 4) fw softmax, uf, VQ argmin, codebook gather
    final_kernel<<<dim3(4096), blk, 0, stream>>>(
        x, Wsel, bsel, arg, gate_pre, bg, cb, out);
}

// Round 2
// 3542.788 us; speedup vs baseline: 1.0011x; 1.0011x over previous
//
#include <hip/hip_runtime.h>
#include <hip/hip_bf16.h>
#include <cmath>

// ============================================================================
// System2Graph fused pipeline, MI355X (gfx950) — round 2
// Strategy: one-time split of all GEMM operands into hi/lo bf16 "tile images"
// stored in HBM in the exact (XOR-swizzled) LDS layout; GEMMs then stage via
// linear global_load_lds (no VALU, no LDS write conflicts) and run 3-term
// split-bf16 MFMA. Falls back to the verified round-1 path if ws is small.
// ============================================================================

typedef __bf16 bf16x8 __attribute__((ext_vector_type(8)));
typedef float  f32x4  __attribute__((ext_vector_type(4)));

__device__ __forceinline__ unsigned short f2bf(float f) {
    unsigned int u = __builtin_bit_cast(unsigned int, f);
    u += 0x7fffu + ((u >> 16) & 1u);          // RNE
    return (unsigned short)(u >> 16);
}
__device__ __forceinline__ float bf2f(unsigned short h) {
    unsigned int u = ((unsigned int)h) << 16;
    return __builtin_bit_cast(float, u);
}
__device__ __forceinline__ float gelu_f(float v) {
    return 0.5f * v * (1.0f + erff(v * 0.7071067811865476f));
}

#define GLL16(src, dst)                                                        \
    __builtin_amdgcn_global_load_lds(                                          \
        (const __attribute__((address_space(1))) void*)(src),                  \
        (__attribute__((address_space(3))) void*)(dst), 16, 0, 0)

// ---------------------------------------------------------------------------
// Tile-image layout: per (tile_r, tile_k) a 16 KB unit: [hi 8KB][lo 8KB],
// each 8KB = row(0..127)*64B + (g ^ ((row>>1)&3))*16B, unit = 8 bf16 (k order).
// Flat: tile offset = (tile_r*NKT + tile_k)*16384.
// ---------------------------------------------------------------------------
__device__ __forceinline__ void store32(char* __restrict__ dst, int tr, int tk,
                                        int nktLog, int row, const float* val)
{
    size_t tb = (((size_t)tr << nktLog) + (size_t)tk) * 16384;
    char* dh = dst + tb + row * 64;
    char* dl = dh + 8192;
    const int v = (row >> 1) & 3;
#pragma unroll
    for (int g = 0; g < 4; ++g) {
        union { unsigned short s[8]; uint4 q; } H, L;
#pragma unroll
        for (int j = 0; j < 8; ++j) {
            float x = val[g * 8 + j];
            unsigned short h = f2bf(x);
            H.s[j] = h;
            L.s[j] = f2bf(x - bf2f(h));
        }
        *(uint4*)(dh + ((g ^ v) << 4)) = H.q;
        *(uint4*)(dl + ((g ^ v) << 4)) = L.q;
    }
}

// Row-major f32 source [rows][1024] -> image. maxrow clamps padded rows.
__global__ __launch_bounds__(256) void precvt_plain(
    const float* __restrict__ src, char* __restrict__ dst,
    int nktLog, int maxrow)
{
    const int u = blockIdx.x * 256 + threadIdx.x;
    const int nktM = (1 << nktLog) - 1;
    const int row = u & 127;
    const int tk  = (u >> 7) & nktM;
    const int tr  = u >> (7 + nktLog);
    int r = tr * 128 + row; if (r > maxrow) r = maxrow;
    const float* s = src + (size_t)r * 1024 + tk * 32;
    float val[32];
#pragma unroll
    for (int j = 0; j < 8; ++j) {
        float4 v4 = ((const float4*)s)[j];
        val[j*4+0] = v4.x; val[j*4+1] = v4.y; val[j*4+2] = v4.z; val[j*4+3] = v4.w;
    }
    store32(dst, tr, tk, nktLog, row, val);
}

// Weight transpose: W [4f][3072][1024] -> image over cols (tr = f*8 + coltile).
// gateSum=0: B row (k=c) = W[browBase + c][col].
// gateSum=1: c<1024 -> W[c][col]; c>=1024 -> W[c][col] + W[c+1024][col].
__global__ __launch_bounds__(256) void precvt_w(
    const float* __restrict__ W, char* __restrict__ dst,
    int browBase, int nktLog, int gateSum)
{
    const int u = blockIdx.x * 256 + threadIdx.x;
    const int nktM = (1 << nktLog) - 1;
    const int col_in = u & 127;
    const int tk  = (u >> 7) & nktM;
    const int tr  = u >> (7 + nktLog);
    const int f   = tr >> 3;
    const int ct  = tr & 7;
    const int col = ct * 128 + col_in;
    const float* Wf = W + (size_t)f * 3072 * 1024;
    const int k0 = tk * 32;
    float val[32];
#pragma unroll
    for (int j = 0; j < 32; ++j) {
        int c = k0 + j;
        float x;
        if (!gateSum) {
            x = Wf[(size_t)(browBase + c) * 1024 + col];
        } else {
            x = Wf[(size_t)c * 1024 + col];
            if (c >= 1024) x += Wf[(size_t)(c + 1024) * 1024 + col];
        }
        val[j] = x;
    }
    store32(dst, tr, tk, nktLog, col_in, val);
}

// Gate A image: rows r = f*4096 + n, K=2048: c<1024 -> x[n][c], else arg[f][n][c-1024]
__global__ __launch_bounds__(256) void precvt_gateA(
    const float* __restrict__ x, const float* __restrict__ arg,
    char* __restrict__ dst)
{
    const int u = blockIdx.x * 256 + threadIdx.x;
    const int row = u & 127;
    const int tk  = (u >> 7) & 63;
    const int tr  = u >> 13;
    const int r = tr * 128 + row;
    const int f = r >> 12, n = r & 4095;
    const float* s = (tk < 32) ? (x + (size_t)n * 1024 + tk * 32)
                               : (arg + ((size_t)f * 4096 + n) * 1024 + (tk - 32) * 32);
    float val[32];
#pragma unroll
    for (int j = 0; j < 8; ++j) {
        float4 v4 = ((const float4*)s)[j];
        val[j*4+0] = v4.x; val[j*4+1] = v4.y; val[j*4+2] = v4.z; val[j*4+3] = v4.w;
    }
    store32(dst, tr, tk, 6, row, val);
}

// ---------------------------------------------------------------------------
// GEMM on tile images: C[128*gx x 1024] = A(img) x B(img), split-bf16 3-MFMA.
// Staging = 32 linear global_load_lds (16B) per k-tile. N=1024 (grid.y=8).
// ---------------------------------------------------------------------------
__global__ __launch_bounds__(256, 2) void gemm_img(
    const char* __restrict__ Aimg, const char* __restrict__ Bimg,
    float* __restrict__ Cbase, int nkt,
    size_t aStrideZ, size_t bStrideZ, size_t cStrideZ /*elements*/,
    int mrows)
{
    __shared__ __align__(16) char lds[32768];   // A hi/lo 16K | B hi/lo 16K
    const int tid = threadIdx.x, wid = tid >> 6, lane = tid & 63;
    const char* Ab = Aimg + blockIdx.z * aStrideZ + (size_t)blockIdx.x * nkt * 16384;
    const char* Bb = Bimg + blockIdx.z * bStrideZ + (size_t)blockIdx.y * nkt * 16384;
    float* Cp = Cbase + blockIdx.z * cStrideZ;

    const int wr = (wid >> 1) * 64, wc = (wid & 1) * 64;
    const int g = lane >> 4, rl = lane & 15;
    const int goff = ((g ^ ((rl >> 1) & 3)) << 4);

    f32x4 acc[4][4];
    f32x4 zero = {0.f, 0.f, 0.f, 0.f};
#pragma unroll
    for (int i = 0; i < 4; ++i)
#pragma unroll
        for (int j = 0; j < 4; ++j) acc[i][j] = zero;

    for (int kt = 0; kt < nkt; ++kt) {
        __syncthreads();
        const char* as = Ab + (size_t)kt * 16384 + wid * 4096 + lane * 16;
        const char* bs = Bb + (size_t)kt * 16384 + wid * 4096 + lane * 16;
        char* ad = lds + wid * 4096 + lane * 16;
        char* bd = lds + 16384 + wid * 4096 + lane * 16;
#pragma unroll
        for (int i = 0; i < 4; ++i) GLL16(as + i * 1024, ad + i * 1024);
#pragma unroll
        for (int i = 0; i < 4; ++i) GLL16(bs + i * 1024, bd + i * 1024);
        __syncthreads();

        bf16x8 ah[4], al[4], bh[4], bl_[4];
#pragma unroll
        for (int mi = 0; mi < 4; ++mi) {
            const char* pa = lds + (wr + mi * 16 + rl) * 64 + goff;
            ah[mi] = *(const bf16x8*)pa;
            al[mi] = *(const bf16x8*)(pa + 8192);
        }
#pragma unroll
        for (int ni = 0; ni < 4; ++ni) {
            const char* pb = lds + 16384 + (wc + ni * 16 + rl) * 64 + goff;
            bh[ni]  = *(const bf16x8*)pb;
            bl_[ni] = *(const bf16x8*)(pb + 8192);
        }
#pragma unroll
        for (int mi = 0; mi < 4; ++mi)
#pragma unroll
            for (int ni = 0; ni < 4; ++ni) {
                acc[mi][ni] = __builtin_amdgcn_mfma_f32_16x16x32_bf16(ah[mi], bh[ni],  acc[mi][ni], 0, 0, 0);
                acc[mi][ni] = __builtin_amdgcn_mfma_f32_16x16x32_bf16(ah[mi], bl_[ni], acc[mi][ni], 0, 0, 0);
                acc[mi][ni] = __builtin_amdgcn_mfma_f32_16x16x32_bf16(al[mi], bh[ni],  acc[mi][ni], 0, 0, 0);
            }
    }
    const int bm0 = blockIdx.x * 128, bn0 = blockIdx.y * 128;
    const int cg = lane & 15, rg = (lane >> 4) * 4;
#pragma unroll
    for (int mi = 0; mi < 4; ++mi) {
#pragma unroll
        for (int i = 0; i < 4; ++i) {
            int row_out = bm0 + wr + mi * 16 + rg + i;
            if (row_out >= mrows) continue;
#pragma unroll
            for (int ni = 0; ni < 4; ++ni) {
                int col = bn0 + wc + ni * 16 + cg;
                Cp[(size_t)row_out * 1024 + col] = acc[mi][ni][i];
            }
        }
    }
}

// ===========================================================================
// Round-1 kernels (fallback GEMM; ln_fuse/final shared by both paths)
// ===========================================================================
#define BM 128
#define BN 128
#define BK 32
#define LDP 40

template<int MODE>
__global__ __launch_bounds__(256, 2) void gemm_split_kernel(
    const float* __restrict__ A0, const float* __restrict__ A1,
    const float* __restrict__ W, float* __restrict__ Cout,
    int f_arg, int row_base)
{
    __shared__ __align__(16) unsigned short Ahi[BM * LDP];
    __shared__ __align__(16) unsigned short Alo[BM * LDP];
    __shared__ __align__(16) unsigned short Bhi[BN * LDP];
    __shared__ __align__(16) unsigned short Blo[BN * LDP];

    const int tid = threadIdx.x;
    const int f   = (MODE == 1) ? f_arg : (int)blockIdx.z;
    const int bm0 = blockIdx.x * BM;
    const int bn0 = blockIdx.y * BN;

    const float* Bf = W + (size_t)f * (3072 * 1024);
    float* Cp;
    if constexpr (MODE == 0)      Cp = Cout + (size_t)f * (513 * 1024);
    else if constexpr (MODE == 1) Cp = Cout;
    else                          Cp = Cout + (size_t)f * (4096 * 1024);
    const float* A1f = (MODE == 2) ? (A1 + (size_t)f * (4096 * 1024)) : A1;

    const int KSTEPS = (MODE == 0) ? 32 : 64;
    const int wid = tid >> 6, lane = tid & 63;
    const int wr = (wid >> 1) * 64, wc = (wid & 1) * 64;
    const int g = lane >> 4, rl = lane & 15;

    f32x4 acc[4][4];
    f32x4 zero = {0.f, 0.f, 0.f, 0.f};
#pragma unroll
    for (int i = 0; i < 4; ++i)
#pragma unroll
        for (int j = 0; j < 4; ++j) acc[i][j] = zero;

    for (int kt = 0; kt < KSTEPS; ++kt) {
        const int kc0 = kt * BK;
        __syncthreads();
#pragma unroll
        for (int i = 0; i < 4; ++i) {
            int q = tid + i * 256;
            int row_l = q >> 3, kq = q & 7;
            int c = kc0 + kq * 4;
            int r = row_base + bm0 + row_l;
            const float* src;
            if constexpr (MODE == 0) {
                int rc = r > 512 ? 512 : r;
                src = A0 + (size_t)rc * 1024 + c;
            } else if constexpr (MODE == 1) {
                src = (c < 1024) ? (A0 + (size_t)r * 1024 + c)
                                 : (A1 + (size_t)(r >> 2) * 1024 + (c - 1024));
            } else {
                src = (c < 1024) ? (A0 + (size_t)r * 1024 + c)
                                 : (A1f + (size_t)r * 1024 + (c - 1024));
            }
            float4 v = *(const float4*)src;
            ushort4 h4, l4;
            h4.x = f2bf(v.x); l4.x = f2bf(v.x - bf2f(h4.x));
            h4.y = f2bf(v.y); l4.y = f2bf(v.y - bf2f(h4.y));
            h4.z = f2bf(v.z); l4.z = f2bf(v.z - bf2f(h4.z));
            h4.w = f2bf(v.w); l4.w = f2bf(v.w - bf2f(h4.w));
            int base = row_l * LDP + kq * 4;
            *(ushort4*)&Ahi[base] = h4;
            *(ushort4*)&Alo[base] = l4;
        }
#pragma unroll
        for (int i = 0; i < 4; ++i) {
            int q = tid + i * 256;
            int crow = q >> 5, colq = q & 31;
            int c = kc0 + crow;
            int col = bn0 + colq * 4;
            float4 v;
            if constexpr (MODE == 0) {
                v = *(const float4*)(Bf + (size_t)(2048 + c) * 1024 + col);
            } else if constexpr (MODE == 1) {
                int brow = (c < 1024) ? (1024 + c) : (c - 1024);
                v = *(const float4*)(Bf + (size_t)brow * 1024 + col);
            } else {
                if (c < 1024) {
                    v = *(const float4*)(Bf + (size_t)c * 1024 + col);
                } else {
                    float4 v1 = *(const float4*)(Bf + (size_t)c * 1024 + col);
                    float4 v2 = *(const float4*)(Bf + (size_t)(c + 1024) * 1024 + col);
                    v.x = v1.x + v2.x; v.y = v1.y + v2.y;
                    v.z = v1.z + v2.z; v.w = v1.w + v2.w;
                }
            }
            int cl = colq * 4;
            unsigned short h;
            h = f2bf(v.x); Bhi[(cl+0)*LDP + crow] = h; Blo[(cl+0)*LDP + crow] = f2bf(v.x - bf2f(h));
            h = f2bf(v.y); Bhi[(cl+1)*LDP + crow] = h; Blo[(cl+1)*LDP + crow] = f2bf(v.y - bf2f(h));
            h = f2bf(v.z); Bhi[(cl+2)*LDP + crow] = h; Blo[(cl+2)*LDP + crow] = f2bf(v.z - bf2f(h));
            h = f2bf(v.w); Bhi[(cl+3)*LDP + crow] = h; Blo[(cl+3)*LDP + crow] = f2bf(v.w - bf2f(h));
        }
        __syncthreads();
        bf16x8 ah[4], alo[4], bh[4], blo[4];
#pragma unroll
        for (int mi = 0; mi < 4; ++mi) {
            int rowi = wr + mi * 16 + rl;
            ah[mi]  = *(const bf16x8*)&Ahi[rowi * LDP + g * 8];
            alo[mi] = *(const bf16x8*)&Alo[rowi * LDP + g * 8];
        }
#pragma unroll
        for (int ni = 0; ni < 4; ++ni) {
            int coli = wc + ni * 16 + rl;
            bh[ni]  = *(const bf16x8*)&Bhi[coli * LDP + g * 8];
            blo[ni] = *(const bf16x8*)&Blo[coli * LDP + g * 8];
        }
#pragma unroll
        for (int mi = 0; mi < 4; ++mi)
#pragma unroll
            for (int ni = 0; ni < 4; ++ni) {
                acc[mi][ni] = __builtin_amdgcn_mfma_f32_16x16x32_bf16(ah[mi],  bh[ni],  acc[mi][ni], 0, 0, 0);
                acc[mi][ni] = __builtin_amdgcn_mfma_f32_16x16x32_bf16(ah[mi],  blo[ni], acc[mi][ni], 0, 0, 0);
                acc[mi][ni] = __builtin_amdgcn_mfma_f32_16x16x32_bf16(alo[mi], bh[ni],  acc[mi][ni], 0, 0, 0);
            }
    }
    const int cg = lane & 15;
    const int rg = (lane >> 4) * 4;
#pragma unroll
    for (int mi = 0; mi < 4; ++mi) {
#pragma unroll
        for (int i = 0; i < 4; ++i) {
            int row_out = bm0 + wr + mi * 16 + rg + i;
            if constexpr (MODE == 0) { if (row_out >= 513) continue; }
#pragma unroll
            for (int ni = 0; ni < 4; ++ni) {
                int col = bn0 + wc + ni * 16 + cg;
                Cp[(size_t)row_out * 1024 + col] = acc[mi][ni][i];
            }
        }
    }
}

// ---------------------------------------------------------------------------
// h = hpre [+ xl] + de_proj[idx] + bl -> GELU -> LN -> *g+b; arg = sum_k sw*h
// ---------------------------------------------------------------------------
__global__ __launch_bounds__(256) void ln_fuse_kernel(
    const float* __restrict__ hpre, const float* __restrict__ de_proj,
    const float* __restrict__ bl, const float* __restrict__ ln_g,
    const float* __restrict__ ln_b, const float* __restrict__ sim,
    const int* __restrict__ topk, float* __restrict__ arg,
    int f, int token_base, const float* __restrict__ xl)
{
    __shared__ float red[4 * 1024];
    const int n = token_base + blockIdx.x;
    const int k = threadIdx.x >> 6, lane = threadIdx.x & 63;
    const float* hrow = hpre + ((size_t)blockIdx.x * 4 + k) * 1024;
    const int t  = n & 1023;
    const int tk = topk[(size_t)n * 4 + k];
    int di = t - tk + 256; di = di < 0 ? 0 : (di > 512 ? 512 : di);
    const float* drow = de_proj + ((size_t)f * 513 + di) * 1024;
    const float* blr = bl + f * 1024;
    const float* gr  = ln_g + f * 1024;
    const float* br  = ln_b + f * 1024;
    const float* xr  = xl ? (xl + ((size_t)f * 4096 + n) * 1024) : nullptr;

    float4 s4 = *(const float4*)&sim[(size_t)n * 4];
    float smax = fmaxf(fmaxf(s4.x, s4.y), fmaxf(s4.z, s4.w));
    float e0 = expf(s4.x - smax), e1 = expf(s4.y - smax);
    float e2 = expf(s4.z - smax), e3 = expf(s4.w - smax);
    float swk = (k == 0 ? e0 : k == 1 ? e1 : k == 2 ? e2 : e3) / (e0 + e1 + e2 + e3);

    float gv[16];
    float ssum = 0.f;
#pragma unroll
    for (int j = 0; j < 4; ++j) {
        int d4 = lane + j * 64;
        float4 h  = *(const float4*)&hrow[d4 * 4];
        float4 dd = *(const float4*)&drow[d4 * 4];
        float4 bb = *(const float4*)&blr[d4 * 4];
        if (xr) {
            float4 xv = *(const float4*)&xr[d4 * 4];
            h.x += xv.x; h.y += xv.y; h.z += xv.z; h.w += xv.w;
        }
        float a0 = gelu_f(h.x + dd.x + bb.x);
        float a1 = gelu_f(h.y + dd.y + bb.y);
        float a2 = gelu_f(h.z + dd.z + bb.z);
        float a3 = gelu_f(h.w + dd.w + bb.w);
        gv[j*4+0] = a0; gv[j*4+1] = a1; gv[j*4+2] = a2; gv[j*4+3] = a3;
        ssum += a0 + a1 + a2 + a3;
    }
    for (int o = 32; o; o >>= 1) ssum += __shfl_xor(ssum, o);
    float mu = ssum * 0.0009765625f;
    float vs = 0.f;
#pragma unroll
    for (int i = 0; i < 16; ++i) { float dm = gv[i] - mu; vs += dm * dm; }
    for (int o = 32; o; o >>= 1) vs += __shfl_xor(vs, o);
    float rstd = 1.0f / sqrtf(vs * 0.0009765625f + 1e-5f);
#pragma unroll
    for (int j = 0; j < 4; ++j) {
        int d4 = lane + j * 64;
        float4 g4 = *(const float4*)&gr[d4 * 4];
        float4 b4 = *(const float4*)&br[d4 * 4];
        float4 y;
        y.x = ((gv[j*4+0] - mu) * rstd * g4.x + b4.x) * swk;
        y.y = ((gv[j*4+1] - mu) * rstd * g4.y + b4.y) * swk;
        y.z = ((gv[j*4+2] - mu) * rstd * g4.z + b4.z) * swk;
        y.w = ((gv[j*4+3] - mu) * rstd * g4.w + b4.w) * swk;
        *(float4*)&red[k * 1024 + d4 * 4] = y;
    }
    __syncthreads();
    const int p = threadIdx.x;
    float4 r0 = *(const float4*)&red[0 * 1024 + p * 4];
    float4 r1 = *(const float4*)&red[1 * 1024 + p * 4];
    float4 r2 = *(const float4*)&red[2 * 1024 + p * 4];
    float4 r3 = *(const float4*)&red[3 * 1024 + p * 4];
    float4 o;
    o.x = r0.x + r1.x + r2.x + r3.x;
    o.y = r0.y + r1.y + r2.y + r3.y;
    o.z = r0.z + r1.z + r2.z + r3.z;
    o.w = r0.w + r1.w + r2.w + r3.w;
    *(float4*)&arg[((size_t)f * 4096 + n) * 1024 + p * 4] = o;
}

// ---------------------------------------------------------------------------
__global__ __launch_bounds__(256) void final_kernel(
    const float* __restrict__ x, const float* __restrict__ Wsel,
    const float* __restrict__ bsel, const float* __restrict__ arg,
    const float* __restrict__ gate_pre, const float* __restrict__ bg,
    const float* __restrict__ cb, float* __restrict__ out)
{
    __shared__ float sred[16];
    __shared__ float uf_s[1024];
    __shared__ float score_s[32];
    __shared__ int enc_s;
    const int n = blockIdx.x;
    const int tid = threadIdx.x, w = tid >> 6, lane = tid & 63;

    float4 xv = *(const float4*)&x[(size_t)n * 1024 + tid * 4];
    float pf0 = 0, pf1 = 0, pf2 = 0, pf3 = 0;
    {
        const float* wrp = &Wsel[(size_t)tid * 16];
        pf0 += xv.x * wrp[0];  pf1 += xv.x * wrp[1];  pf2 += xv.x * wrp[2];  pf3 += xv.x * wrp[3];
        pf0 += xv.y * wrp[4];  pf1 += xv.y * wrp[5];  pf2 += xv.y * wrp[6];  pf3 += xv.y * wrp[7];
        pf0 += xv.z * wrp[8];  pf1 += xv.z * wrp[9];  pf2 += xv.z * wrp[10]; pf3 += xv.z * wrp[11];
        pf0 += xv.w * wrp[12]; pf1 += xv.w * wrp[13]; pf2 += xv.w * wrp[14]; pf3 += xv.w * wrp[15];
    }
    for (int o = 32; o; o >>= 1) {
        pf0 += __shfl_xor(pf0, o); pf1 += __shfl_xor(pf1, o);
        pf2 += __shfl_xor(pf2, o); pf3 += __shfl_xor(pf3, o);
    }
    if (lane == 0) { sred[w*4+0] = pf0; sred[w*4+1] = pf1; sred[w*4+2] = pf2; sred[w*4+3] = pf3; }
    __syncthreads();
    float sel0 = sred[0] + sred[4] + sred[8]  + sred[12] + bsel[0];
    float sel1 = sred[1] + sred[5] + sred[9]  + sred[13] + bsel[1];
    float sel2 = sred[2] + sred[6] + sred[10] + sred[14] + bsel[2];
    float sel3 = sred[3] + sred[7] + sred[11] + sred[15] + bsel[3];
    float mx = fmaxf(fmaxf(sel0, sel1), fmaxf(sel2, sel3));
    float f0 = expf(sel0 - mx), f1 = expf(sel1 - mx), f2 = expf(sel2 - mx), f3 = expf(sel3 - mx);
    float inv = 1.0f / (f0 + f1 + f2 + f3);
    float fw[4] = { f0 * inv, f1 * inv, f2 * inv, f3 * inv };

    float4 prop = {0, 0, 0, 0}, gs = {0, 0, 0, 0};
#pragma unroll
    for (int f = 0; f < 4; ++f) {
        size_t off = ((size_t)f * 4096 + n) * 1024 + tid * 4;
        float4 av  = *(const float4*)&arg[off];
        float4 gvv = *(const float4*)&gate_pre[off];
        float4 bgv = *(const float4*)&bg[f * 1024 + tid * 4];
        float wgt = fw[f];
        prop.x += wgt * av.x; prop.y += wgt * av.y; prop.z += wgt * av.z; prop.w += wgt * av.w;
        gs.x += wgt * (1.0f / (1.0f + expf(-(gvv.x + bgv.x))));
        gs.y += wgt * (1.0f / (1.0f + expf(-(gvv.y + bgv.y))));
        gs.z += wgt * (1.0f / (1.0f + expf(-(gvv.z + bgv.z))));
        gs.w += wgt * (1.0f / (1.0f + expf(-(gvv.w + bgv.w))));
    }
    float4 uf;
    uf.x = prop.x * gs.x; uf.y = prop.y * gs.y; uf.z = prop.z * gs.z; uf.w = prop.w * gs.w;
    *(float4*)&uf_s[tid * 4] = uf;
    __syncthreads();

#pragma unroll
    for (int cc = 0; cc < 8; ++cc) {
        int c = w * 8 + cc;
        float p = 0.f, q = 0.f;
#pragma unroll
        for (int j = 0; j < 4; ++j) {
            int d4 = lane + j * 64;
            float4 u4 = *(const float4*)&uf_s[d4 * 4];
            float4 c4 = *(const float4*)&cb[(size_t)c * 1024 + d4 * 4];
            p += u4.x * c4.x + u4.y * c4.y + u4.z * c4.z + u4.w * c4.w;
            q += c4.x * c4.x + c4.y * c4.y + c4.z * c4.z + c4.w * c4.w;
        }
        float s = q - 2.0f * p;
        for (int o = 32; o; o >>= 1) s += __shfl_xor(s, o);
        if (lane == 0) score_s[c] = s;
    }
    __syncthreads();
    if (tid < 64) {
        float v; int idx;
        if (lane < 32) { v = score_s[lane]; idx = lane; }
        else           { v = INFINITY;      idx = 1 << 30; }
        for (int o = 16; o; o >>= 1) {
            float ov = __shfl_xor(v, o); int oi = __shfl_xor(idx, o);
            if (ov < v || (ov == v && oi < idx)) { v = ov; idx = oi; }
        }
        if (lane == 0) enc_s = idx;
    }
    __syncthreads();
    const int enc = enc_s;
    float4 o4 = *(const float4*)&cb[(size_t)enc * 1024 + tid * 4];
    *(float4*)&out[(size_t)n * 1024 + tid * 4] = o4;
}

// ---------------------------------------------------------------------------
extern "C" void kernel_launch(void* const* d_in, const int* in_sizes, int n_in,
                              void* d_out, int out_size, void* d_ws, size_t ws_size,
                              hipStream_t stream)
{
    const float* x    = (const float*)d_in[0];
    const float* rf   = (const float*)d_in[1];
    const float* sim  = (const float*)d_in[2];
    const float* Wl   = (const float*)d_in[3];
    const float* bl   = (const float*)d_in[4];
    const float* ln_g = (const float*)d_in[5];
    const float* ln_b = (const float*)d_in[6];
    const float* Wg   = (const float*)d_in[7];
    const float* bg   = (const float*)d_in[8];
    const float* Wsel = (const float*)d_in[9];
    const float* bsel = (const float*)d_in[10];
    const float* dtab = (const float*)d_in[11];
    const float* cb   = (const float*)d_in[12];
    const int*   topk = (const int*)d_in[13];
    float* out = (float*)d_out;
    dim3 blk(256);

    const size_t NEED_NEW = 430456832ull;
    if (ws_size >= NEED_NEW) {
        // ---- fast path: preconverted tile images + global_load_lds GEMMs ----
        char* ws = (char*)d_ws;
        float* arg      = (float*)(ws + 0);                        // 64 MB
        float* xl       = (float*)(ws + 67108864);                 // 64 MB (later gate_pre)
        float* gate_pre = xl;
        float* hbuf0    = (float*)(ws + 134217728);                // 32 MB
        float* hbuf1    = (float*)(ws + 134217728 + 33554432);     // 32 MB
        float* de_proj  = (float*)(ws + 201326592);                // 8 MB
        char*  rfimg    = ws + 209731584;                          // 64 MB
        char*  ximg     = rfimg + 67108864;                        // 16 MB
        char*  gateimg  = rfimg;                                   // 128 MB (phase 2)
        char*  Wl0t     = ws + 343949312;                          // 16 MB each
        char*  Wl1t     = Wl0t + 16777216;
        char*  Wl2t     = Wl0t + 33554432;
        char*  Wgt      = Wl0t + 50331648;                         // 32 MB
        char*  dtimg    = ws + 427835392;                          // 2.5 MB

        // one-time operand preconversion
        precvt_w<<<512,  blk, 0, stream>>>(Wl, Wl0t, 0,    5, 0);
        precvt_w<<<512,  blk, 0, stream>>>(Wl, Wl1t, 1024, 5, 0);
        precvt_w<<<512,  blk, 0, stream>>>(Wl, Wl2t, 2048, 5, 0);
        precvt_w<<<1024, blk, 0, stream>>>(Wg, Wgt,  0,    6, 1);
        precvt_plain<<<80,   blk, 0, stream>>>(dtab, dtimg, 5, 512);
        precvt_plain<<<2048, blk, 0, stream>>>(rf,   rfimg, 5, 16383);
        precvt_plain<<<512,  blk, 0, stream>>>(x,    ximg,  5, 4095);

        // de_proj[f] = dtab @ Wl[f][2048:3072];  xl[f] = x @ Wl[f][0:1024]
        gemm_img<<<dim3(5, 8, 4),  blk, 0, stream>>>(dtimg, Wl2t, de_proj, 32,
                                                     0, 4194304, 525312, 513);
        gemm_img<<<dim3(32, 8, 4), blk, 0, stream>>>(ximg, Wl0t, xl, 32,
                                                     0, 4194304, 4194304, 4096);

        // hpre chunks = rf @ Wl[f][1024:2048], fused GELU/LN/softmax-reduce
        for (int f = 0; f < 4; ++f) {
            for (int h = 0; h < 2; ++h) {
                float* hb = ((f * 2 + h) & 1) ? hbuf1 : hbuf0;
                gemm_img<<<dim3(64, 8, 1), blk, 0, stream>>>(
                    rfimg + (size_t)h * 33554432, Wl1t + (size_t)f * 4194304,
                    hb, 32, 0, 0, 0, 8192);
                ln_fuse_kernel<<<2048, blk, 0, stream>>>(
                    hb, de_proj, bl, ln_g, ln_b, sim, topk, arg, f, h * 2048, xl);
            }
        }

        // gate_pre[f] = x @ Wg0[f] + arg_f @ (Wg1[f]+Wg2[f])
        precvt_gateA<<<4096, blk, 0, stream>>>(x, arg, gateimg);
        gemm_img<<<dim3(32, 8, 4), blk, 0, stream>>>(gateimg, Wgt, gate_pre, 64,
                                                     33554432, 8388608, 4194304, 4096);

        final_kernel<<<4096, blk, 0, stream>>>(x, Wsel, bsel, arg, gate_pre, bg, cb, out);
    } else {
        // ---- fallback: verified round-1 path ----
        const size_t NEED_OLD = ((size_t)4 * 513 * 1024 + (size_t)4 * 4096 * 1024
                                 + (size_t)2 * 8192 * 1024) * 4;
        if (ws_size < NEED_OLD) return;
        float* de_proj = (float*)d_ws;
        float* arg     = de_proj + (size_t)4 * 513 * 1024;
        float* regionX = arg + (size_t)4 * 4096 * 1024;
        float* hbuf0   = regionX;
        float* hbuf1   = regionX + (size_t)8192 * 1024;
        float* gate_pre = regionX;

        gemm_split_kernel<0><<<dim3(5, 8, 4), blk, 0, stream>>>(
            dtab, (const float*)nullptr, Wl, de_proj, 0, 0);
        for (int f = 0; f < 4; ++f) {
            for (int h = 0; h < 2; ++h) {
                float* hb = ((f * 2 + h) & 1) ? hbuf1 : hbuf0;
                gemm_split_kernel<1><<<dim3(64, 8, 1), blk, 0, stream>>>(
                    rf, x, Wl, hb, f, h * 8192);
                ln_fuse_kernel<<<2048, blk, 0, stream>>>(
                    hb, de_proj, bl, ln_g, ln_b, sim, topk, arg, f, h * 2048,
                    (const float*)nullptr);
            }
        }
        gemm_split_kernel<2><<<dim3(32, 8, 4), blk, 0, stream>>>(
            x, arg, Wg, gate_pre, 0, 0);
        final_kernel<<<4096, blk, 0, stream>>>(
            x, Wsel, bsel, arg, gate_pre, bg, cb, out);
    }
}

// Round 3
// 3188.486 us; speedup vs baseline: 1.1124x; 1.1111x over previous
//
#include <hip/hip_runtime.h>
#include <hip/hip_bf16.h>
#include <cmath>

// ============================================================================
// System2Graph fused pipeline, MI355X (gfx950) — round 3
// In-kernel f32 -> hi/lo bf16 split with conflict-free swizzled LDS layout.
// out = codebook[argmin_c ||uf - codebook[c]||^2]  (straight-through gather).
// ws layout sized to the known-available 142,622,720 bytes.
// ============================================================================

typedef __bf16 bf16x8 __attribute__((ext_vector_type(8)));
typedef float  f32x4  __attribute__((ext_vector_type(4)));

__device__ __forceinline__ float gelu_f(float v) {
    return 0.5f * v * (1.0f + erff(v * 0.7071067811865476f));
}

// split 8 f32 into hi/lo bf16 (lo exactly compensates hi's rounding)
__device__ __forceinline__ void split8(const float* v, bf16x8& H, bf16x8& L) {
#pragma unroll
    for (int j = 0; j < 8; ++j) {
        float x = v[j];
        __bf16 h = (__bf16)x;
        float hf = (float)h;
        H[j] = h;
        L[j] = (__bf16)(x - hf);
    }
}

// ---------------------------------------------------------------------------
// LDS tile layout (per 128x32 tile, 16 KB = hi 8K | lo 8K):
//   unit(row, g) = k's [g*8, g*8+8) of row; byte addr = row*64 + ((g^((row>>1)&3))<<4)
// Staging writes: ds_write_b128, all 8 slot-positions uniformly covered (BW-opt).
// Fragment reads: ds_read_b128, 2 lanes/bank (free).
// ---------------------------------------------------------------------------

#define MFMA_BLOCK(LDSA, LDSB)                                                   \
    bf16x8 ah[4], al[4], bh[4], bl_[4];                                          \
    _Pragma("unroll")                                                            \
    for (int mi = 0; mi < 4; ++mi) {                                             \
        const char* pa = (LDSA) + (wr + mi * 16 + rl) * 64 + goff;               \
        ah[mi] = *(const bf16x8*)pa;                                             \
        al[mi] = *(const bf16x8*)(pa + 8192);                                    \
    }                                                                            \
    _Pragma("unroll")                                                            \
    for (int ni = 0; ni < 4; ++ni) {                                             \
        const char* pb = (LDSB) + (wc + ni * 16 + rl) * 64 + goff;               \
        bh[ni]  = *(const bf16x8*)pb;                                            \
        bl_[ni] = *(const bf16x8*)(pb + 8192);                                   \
    }                                                                            \
    _Pragma("unroll")                                                            \
    for (int mi = 0; mi < 4; ++mi)                                               \
        _Pragma("unroll")                                                        \
        for (int ni = 0; ni < 4; ++ni) {                                         \
            acc[mi][ni] = __builtin_amdgcn_mfma_f32_16x16x32_bf16(ah[mi], bh[ni],  acc[mi][ni], 0, 0, 0); \
            acc[mi][ni] = __builtin_amdgcn_mfma_f32_16x16x32_bf16(ah[mi], bl_[ni], acc[mi][ni], 0, 0, 0); \
            acc[mi][ni] = __builtin_amdgcn_mfma_f32_16x16x32_bf16(al[mi], bh[ni],  acc[mi][ni], 0, 0, 0); \
        }

// ---------------------------------------------------------------------------
// Plain GEMM: C = A[rows][1024-K slice] @ W[kbase..kbase+K][1024]
// A rows: arowBase + bm0 + row, clamped to maxrow. grid.z over f via strides.
// ---------------------------------------------------------------------------
__global__ __launch_bounds__(256, 2) void gemm_cvt(
    const float* __restrict__ A, int arowBase, int maxrow,
    const float* __restrict__ B, int kbase,
    float* __restrict__ C, int nkt,
    size_t bStrideZ, size_t cStrideZ, int mrows)
{
    __shared__ __align__(16) char lds[32768];
    const int tid = threadIdx.x, wid = tid >> 6, lane = tid & 63;
    const int bm0 = blockIdx.x * 128, bn0 = blockIdx.y * 128;
    const float* Bf = B + blockIdx.z * bStrideZ;
    float* Cp = C + blockIdx.z * cStrideZ;

    const int wr = (wid >> 1) * 64, wc = (wid & 1) * 64;
    const int g = lane >> 4, rl = lane & 15;
    const int goff = ((g ^ ((rl >> 1) & 3)) << 4);

    f32x4 acc[4][4];
    f32x4 zero = {0.f, 0.f, 0.f, 0.f};
#pragma unroll
    for (int i = 0; i < 4; ++i)
#pragma unroll
        for (int j = 0; j < 4; ++j) acc[i][j] = zero;

    for (int kt = 0; kt < nkt; ++kt) {
        const int kc0 = kt * 32;
        __syncthreads();
        // ---- stage A: 2 units/thread, unit = 8 k's of one row ----
#pragma unroll
        for (int i = 0; i < 2; ++i) {
            int u = tid + i * 256;
            int row = u >> 2, ga = u & 3;
            int r = arowBase + bm0 + row; if (r > maxrow) r = maxrow;
            const float* s = A + (size_t)r * 1024 + kc0 + ga * 8;
            float vv[8];
            *(float4*)&vv[0] = ((const float4*)s)[0];
            *(float4*)&vv[4] = ((const float4*)s)[1];
            bf16x8 H, L; split8(vv, H, L);
            char* dst = lds + row * 64 + ((ga ^ ((row >> 1) & 3)) << 4);
            *(bf16x8*)dst = H;
            *(bf16x8*)(dst + 8192) = L;
        }
        // ---- stage B: 2 units/thread, unit = 8 k's of one col (transpose) ----
#pragma unroll
        for (int i = 0; i < 2; ++i) {
            int u = tid + i * 256;
            int col = u & 127, kg = u >> 7;
            int cgl = bn0 + col;
            float vv[8];
#pragma unroll
            for (int j = 0; j < 8; ++j) {
                int k = kbase + kc0 + kg * 8 + j;
                vv[j] = Bf[(size_t)k * 1024 + cgl];
            }
            bf16x8 H, L; split8(vv, H, L);
            char* dst = lds + 16384 + col * 64 + ((kg ^ ((col >> 1) & 3)) << 4);
            *(bf16x8*)dst = H;
            *(bf16x8*)(dst + 8192) = L;
        }
        __syncthreads();
        MFMA_BLOCK(lds, lds + 16384)
    }
    const int cg = lane & 15, rg = (lane >> 4) * 4;
#pragma unroll
    for (int mi = 0; mi < 4; ++mi) {
#pragma unroll
        for (int i = 0; i < 4; ++i) {
            int row_out = bm0 + wr + mi * 16 + rg + i;
            if (row_out >= mrows) continue;
#pragma unroll
            for (int ni = 0; ni < 4; ++ni) {
                int col = bn0 + wc + ni * 16 + cg;
                Cp[(size_t)row_out * 1024 + col] = acc[mi][ni][i];
            }
        }
    }
}

// ---------------------------------------------------------------------------
// Gate GEMM (per f): T = [x | arg_f] @ (Wg0 | Wg1+Wg2), K=2048.
// Epilogue: gsum[n][d] (+)= fw[n][f] * sigmoid(T + bg[f][d]).  f=0 stores.
// ---------------------------------------------------------------------------
__global__ __launch_bounds__(256, 2) void gate_cvt(
    const float* __restrict__ x, const float* __restrict__ arg,
    const float* __restrict__ Wg, const float* __restrict__ fw,
    const float* __restrict__ bg, float* __restrict__ gsum, int farg)
{
    __shared__ __align__(16) char lds[32768];
    const int tid = threadIdx.x, wid = tid >> 6, lane = tid & 63;
    const int bm0 = blockIdx.x * 128, bn0 = blockIdx.y * 128;
    const float* Wf = Wg + (size_t)farg * 3072 * 1024;
    const float* argf = arg + (size_t)farg * 4096 * 1024;

    const int wr = (wid >> 1) * 64, wc = (wid & 1) * 64;
    const int g = lane >> 4, rl = lane & 15;
    const int goff = ((g ^ ((rl >> 1) & 3)) << 4);

    f32x4 acc[4][4];
    f32x4 zero = {0.f, 0.f, 0.f, 0.f};
#pragma unroll
    for (int i = 0; i < 4; ++i)
#pragma unroll
        for (int j = 0; j < 4; ++j) acc[i][j] = zero;

    for (int kt = 0; kt < 64; ++kt) {
        const int kc0 = kt * 32;
        __syncthreads();
#pragma unroll
        for (int i = 0; i < 2; ++i) {
            int u = tid + i * 256;
            int row = u >> 2, ga = u & 3;
            int n = bm0 + row;
            int k0 = kc0 + ga * 8;
            const float* s = (k0 < 1024) ? (x + (size_t)n * 1024 + k0)
                                         : (argf + (size_t)n * 1024 + (k0 - 1024));
            float vv[8];
            *(float4*)&vv[0] = ((const float4*)s)[0];
            *(float4*)&vv[4] = ((const float4*)s)[1];
            bf16x8 H, L; split8(vv, H, L);
            char* dst = lds + row * 64 + ((ga ^ ((row >> 1) & 3)) << 4);
            *(bf16x8*)dst = H;
            *(bf16x8*)(dst + 8192) = L;
        }
#pragma unroll
        for (int i = 0; i < 2; ++i) {
            int u = tid + i * 256;
            int col = u & 127, kg = u >> 7;
            int cgl = bn0 + col;
            float vv[8];
#pragma unroll
            for (int j = 0; j < 8; ++j) {
                int k = kc0 + kg * 8 + j;
                float v = Wf[(size_t)k * 1024 + cgl];
                if (k >= 1024) v += Wf[(size_t)(k + 1024) * 1024 + cgl];
                vv[j] = v;
            }
            bf16x8 H, L; split8(vv, H, L);
            char* dst = lds + 16384 + col * 64 + ((kg ^ ((col >> 1) & 3)) << 4);
            *(bf16x8*)dst = H;
            *(bf16x8*)(dst + 8192) = L;
        }
        __syncthreads();
        MFMA_BLOCK(lds, lds + 16384)
    }
    const int cg = lane & 15, rg = (lane >> 4) * 4;
    const bool accum = (farg > 0);
#pragma unroll
    for (int mi = 0; mi < 4; ++mi) {
#pragma unroll
        for (int i = 0; i < 4; ++i) {
            int row_out = bm0 + wr + mi * 16 + rg + i;
            float fwv = fw[(size_t)row_out * 4 + farg];
#pragma unroll
            for (int ni = 0; ni < 4; ++ni) {
                int col = bn0 + wc + ni * 16 + cg;
                float v = acc[mi][ni][i] + bg[farg * 1024 + col];
                float s = fwv / (1.0f + expf(-v));
                size_t off = (size_t)row_out * 1024 + col;
                if (accum) gsum[off] += s; else gsum[off] = s;
            }
        }
    }
}

// ---------------------------------------------------------------------------
// fw[n][0..3] = softmax(x[n] @ Wsel + bsel). One block per token.
// ---------------------------------------------------------------------------
__global__ __launch_bounds__(256) void fw_kernel(
    const float* __restrict__ x, const float* __restrict__ Wsel,
    const float* __restrict__ bsel, float* __restrict__ fw)
{
    __shared__ float sred[16];
    const int n = blockIdx.x;
    const int tid = threadIdx.x, w = tid >> 6, lane = tid & 63;

    float4 xv = *(const float4*)&x[(size_t)n * 1024 + tid * 4];
    float pf0 = 0, pf1 = 0, pf2 = 0, pf3 = 0;
    const float* wrp = &Wsel[(size_t)tid * 16];
    pf0 += xv.x * wrp[0];  pf1 += xv.x * wrp[1];  pf2 += xv.x * wrp[2];  pf3 += xv.x * wrp[3];
    pf0 += xv.y * wrp[4];  pf1 += xv.y * wrp[5];  pf2 += xv.y * wrp[6];  pf3 += xv.y * wrp[7];
    pf0 += xv.z * wrp[8];  pf1 += xv.z * wrp[9];  pf2 += xv.z * wrp[10]; pf3 += xv.z * wrp[11];
    pf0 += xv.w * wrp[12]; pf1 += xv.w * wrp[13]; pf2 += xv.w * wrp[14]; pf3 += xv.w * wrp[15];
    for (int o = 32; o; o >>= 1) {
        pf0 += __shfl_xor(pf0, o); pf1 += __shfl_xor(pf1, o);
        pf2 += __shfl_xor(pf2, o); pf3 += __shfl_xor(pf3, o);
    }
    if (lane == 0) { sred[w*4+0] = pf0; sred[w*4+1] = pf1; sred[w*4+2] = pf2; sred[w*4+3] = pf3; }
    __syncthreads();
    if (tid == 0) {
        float s0 = sred[0] + sred[4] + sred[8]  + sred[12] + bsel[0];
        float s1 = sred[1] + sred[5] + sred[9]  + sred[13] + bsel[1];
        float s2 = sred[2] + sred[6] + sred[10] + sred[14] + bsel[2];
        float s3 = sred[3] + sred[7] + sred[11] + sred[15] + bsel[3];
        float mx = fmaxf(fmaxf(s0, s1), fmaxf(s2, s3));
        float e0 = expf(s0 - mx), e1 = expf(s1 - mx), e2 = expf(s2 - mx), e3 = expf(s3 - mx);
        float inv = 1.0f / (e0 + e1 + e2 + e3);
        float4 o = { e0 * inv, e1 * inv, e2 * inv, e3 * inv };
        *(float4*)&fw[(size_t)n * 4] = o;
    }
}

// ---------------------------------------------------------------------------
// h = hpre + xl + de_proj[idx] + bl -> GELU -> LN -> *g+b; arg = sum_k sw*h
// ---------------------------------------------------------------------------
__global__ __launch_bounds__(256) void ln_fuse_kernel(
    const float* __restrict__ hpre, const float* __restrict__ de_proj,
    const float* __restrict__ bl, const float* __restrict__ ln_g,
    const float* __restrict__ ln_b, const float* __restrict__ sim,
    const int* __restrict__ topk, float* __restrict__ arg,
    int f, int token_base, const float* __restrict__ xl)
{
    __shared__ float red[4 * 1024];
    const int n = token_base + blockIdx.x;
    const int k = threadIdx.x >> 6, lane = threadIdx.x & 63;
    const float* hrow = hpre + ((size_t)blockIdx.x * 4 + k) * 1024;
    const int t  = n & 1023;
    const int tk = topk[(size_t)n * 4 + k];
    int di = t - tk + 256; di = di < 0 ? 0 : (di > 512 ? 512 : di);
    const float* drow = de_proj + ((size_t)f * 513 + di) * 1024;
    const float* blr = bl + f * 1024;
    const float* gr  = ln_g + f * 1024;
    const float* br  = ln_b + f * 1024;
    const float* xr  = xl + (size_t)n * 1024;

    float4 s4 = *(const float4*)&sim[(size_t)n * 4];
    float smax = fmaxf(fmaxf(s4.x, s4.y), fmaxf(s4.z, s4.w));
    float e0 = expf(s4.x - smax), e1 = expf(s4.y - smax);
    float e2 = expf(s4.z - smax), e3 = expf(s4.w - smax);
    float swk = (k == 0 ? e0 : k == 1 ? e1 : k == 2 ? e2 : e3) / (e0 + e1 + e2 + e3);

    float gv[16];
    float ssum = 0.f;
#pragma unroll
    for (int j = 0; j < 4; ++j) {
        int d4 = lane + j * 64;
        float4 h  = *(const float4*)&hrow[d4 * 4];
        float4 dd = *(const float4*)&drow[d4 * 4];
        float4 bb = *(const float4*)&blr[d4 * 4];
        float4 xv = *(const float4*)&xr[d4 * 4];
        float a0 = gelu_f(h.x + xv.x + dd.x + bb.x);
        float a1 = gelu_f(h.y + xv.y + dd.y + bb.y);
        float a2 = gelu_f(h.z + xv.z + dd.z + bb.z);
        float a3 = gelu_f(h.w + xv.w + dd.w + bb.w);
        gv[j*4+0] = a0; gv[j*4+1] = a1; gv[j*4+2] = a2; gv[j*4+3] = a3;
        ssum += a0 + a1 + a2 + a3;
    }
    for (int o = 32; o; o >>= 1) ssum += __shfl_xor(ssum, o);
    float mu = ssum * 0.0009765625f;
    float vs = 0.f;
#pragma unroll
    for (int i = 0; i < 16; ++i) { float dm = gv[i] - mu; vs += dm * dm; }
    for (int o = 32; o; o >>= 1) vs += __shfl_xor(vs, o);
    float rstd = 1.0f / sqrtf(vs * 0.0009765625f + 1e-5f);
#pragma unroll
    for (int j = 0; j < 4; ++j) {
        int d4 = lane + j * 64;
        float4 g4 = *(const float4*)&gr[d4 * 4];
        float4 b4 = *(const float4*)&br[d4 * 4];
        float4 y;
        y.x = ((gv[j*4+0] - mu) * rstd * g4.x + b4.x) * swk;
        y.y = ((gv[j*4+1] - mu) * rstd * g4.y + b4.y) * swk;
        y.z = ((gv[j*4+2] - mu) * rstd * g4.z + b4.z) * swk;
        y.w = ((gv[j*4+3] - mu) * rstd * g4.w + b4.w) * swk;
        *(float4*)&red[k * 1024 + d4 * 4] = y;
    }
    __syncthreads();
    const int p = threadIdx.x;
    float4 r0 = *(const float4*)&red[0 * 1024 + p * 4];
    float4 r1 = *(const float4*)&red[1 * 1024 + p * 4];
    float4 r2 = *(const float4*)&red[2 * 1024 + p * 4];
    float4 r3 = *(const float4*)&red[3 * 1024 + p * 4];
    float4 o;
    o.x = r0.x + r1.x + r2.x + r3.x;
    o.y = r0.y + r1.y + r2.y + r3.y;
    o.z = r0.z + r1.z + r2.z + r3.z;
    o.w = r0.w + r1.w + r2.w + r3.w;
    *(float4*)&arg[((size_t)f * 4096 + n) * 1024 + p * 4] = o;
}

// ---------------------------------------------------------------------------
// Final: uf = (sum_f fw*arg) * gsum; VQ argmin over 32 codes; gather codebook.
// ---------------------------------------------------------------------------
__global__ __launch_bounds__(256) void final_kernel(
    const float* __restrict__ fw, const float* __restrict__ arg,
    const float* __restrict__ gsum, const float* __restrict__ cb,
    float* __restrict__ out)
{
    __shared__ float uf_s[1024];
    __shared__ float score_s[32];
    __shared__ int enc_s;
    const int n = blockIdx.x;
    const int tid = threadIdx.x, w = tid >> 6, lane = tid & 63;

    float4 fwv = *(const float4*)&fw[(size_t)n * 4];
    float fwa[4] = { fwv.x, fwv.y, fwv.z, fwv.w };

    float4 prop = {0, 0, 0, 0};
#pragma unroll
    for (int f = 0; f < 4; ++f) {
        float4 av = *(const float4*)&arg[((size_t)f * 4096 + n) * 1024 + tid * 4];
        prop.x += fwa[f] * av.x; prop.y += fwa[f] * av.y;
        prop.z += fwa[f] * av.z; prop.w += fwa[f] * av.w;
    }
    float4 gs = *(const float4*)&gsum[(size_t)n * 1024 + tid * 4];
    float4 uf;
    uf.x = prop.x * gs.x; uf.y = prop.y * gs.y;
    uf.z = prop.z * gs.z; uf.w = prop.w * gs.w;
    *(float4*)&uf_s[tid * 4] = uf;
    __syncthreads();

#pragma unroll
    for (int cc = 0; cc < 8; ++cc) {
        int c = w * 8 + cc;
        float p = 0.f, q = 0.f;
#pragma unroll
        for (int j = 0; j < 4; ++j) {
            int d4 = lane + j * 64;
            float4 u4 = *(const float4*)&uf_s[d4 * 4];
            float4 c4 = *(const float4*)&cb[(size_t)c * 1024 + d4 * 4];
            p += u4.x * c4.x + u4.y * c4.y + u4.z * c4.z + u4.w * c4.w;
            q += c4.x * c4.x + c4.y * c4.y + c4.z * c4.z + c4.w * c4.w;
        }
        float s = q - 2.0f * p;
        for (int o = 32; o; o >>= 1) s += __shfl_xor(s, o);
        if (lane == 0) score_s[c] = s;
    }
    __syncthreads();
    if (tid < 64) {
        float v; int idx;
        if (lane < 32) { v = score_s[lane]; idx = lane; }
        else           { v = INFINITY;      idx = 1 << 30; }
        for (int o = 16; o; o >>= 1) {
            float ov = __shfl_xor(v, o); int oi = __shfl_xor(idx, o);
            if (ov < v || (ov == v && oi < idx)) { v = ov; idx = oi; }
        }
        if (lane == 0) enc_s = idx;
    }
    __syncthreads();
    const int enc = enc_s;
    float4 o4 = *(const float4*)&cb[(size_t)enc * 1024 + tid * 4];
    *(float4*)&out[(size_t)n * 1024 + tid * 4] = o4;
}

// ---------------------------------------------------------------------------
extern "C" void kernel_launch(void* const* d_in, const int* in_sizes, int n_in,
                              void* d_out, int out_size, void* d_ws, size_t ws_size,
                              hipStream_t stream)
{
    const float* x    = (const float*)d_in[0];
    const float* rf   = (const float*)d_in[1];
    const float* sim  = (const float*)d_in[2];
    const float* Wl   = (const float*)d_in[3];
    const float* bl   = (const float*)d_in[4];
    const float* ln_g = (const float*)d_in[5];
    const float* ln_b = (const float*)d_in[6];
    const float* Wg   = (const float*)d_in[7];
    const float* bg   = (const float*)d_in[8];
    const float* Wsel = (const float*)d_in[9];
    const float* bsel = (const float*)d_in[10];
    const float* dtab = (const float*)d_in[11];
    const float* cb   = (const float*)d_in[12];
    const int*   topk = (const int*)d_in[13];
    float* out = (float*)d_out;
    dim3 blk(256);

    // ws layout (bytes), total = 142,622,720 (== round-1 verified budget):
    //   arg      @ 0           67,108,864   (4 x 4096 x 1024 f32)
    //   gsum     @ 67,108,864  16,777,216   (4096 x 1024 f32)
    //   de_proj  @ 83,886,080   8,404,992   (4 x 513 x 1024 f32)
    //   xl       @ 92,291,072  16,777,216   (per-f, reused)
    //   hbuf0    @109,068,288  16,777,216   (chunk ping; later fw 64 KB)
    //   hbuf1    @125,845,504  16,777,216   (chunk pong)
    const size_t NEED = 142622720ull;
    if (ws_size < NEED) return;
    char* ws = (char*)d_ws;
    float* arg     = (float*)(ws + 0);
    float* gsum    = (float*)(ws + 67108864);
    float* de_proj = (float*)(ws + 83886080);
    float* xl      = (float*)(ws + 92291072);
    float* hbuf0   = (float*)(ws + 109068288);
    float* hbuf1   = (float*)(ws + 125845504);
    float* fw      = hbuf0;                      // reused after ln_fuse phase

    // 1) de_proj[f] = dtab(513, clamped) @ Wl[f][2048:3072]
    gemm_cvt<<<dim3(5, 8, 4), blk, 0, stream>>>(
        dtab, 0, 512, Wl, 2048, de_proj, 32,
        (size_t)3072 * 1024, (size_t)513 * 1024, 513);

    // 2) per f: xl = x @ Wl[f][0:1024]; then 4 chunks of rf @ Wl[f][1024:2048]
    for (int f = 0; f < 4; ++f) {
        const float* Wlf = Wl + (size_t)f * 3072 * 1024;
        gemm_cvt<<<dim3(32, 8, 1), blk, 0, stream>>>(
            x, 0, 4095, Wlf, 0, xl, 32, 0, 0, 4096);
        for (int ch = 0; ch < 4; ++ch) {
            float* hb = (ch & 1) ? hbuf1 : hbuf0;
            gemm_cvt<<<dim3(32, 8, 1), blk, 0, stream>>>(
                rf, ch * 4096, 16383, Wlf, 1024, hb, 32, 0, 0, 4096);
            ln_fuse_kernel<<<1024, blk, 0, stream>>>(
                hb, de_proj, bl, ln_g, ln_b, sim, topk, arg, f, ch * 1024, xl);
        }
    }

    // 3) fw = softmax(x @ Wsel + bsel)   (into dead hbuf0 region)
    fw_kernel<<<4096, blk, 0, stream>>>(x, Wsel, bsel, fw);

    // 4) gsum (+)= fw[:,f] * sigmoid([x|arg_f] @ Wg_summed[f] + bg[f]), f serial
    for (int f = 0; f < 4; ++f)
        gate_cvt<<<dim3(32, 8), blk, 0, stream>>>(x, arg, Wg, fw, bg, gsum, f);

    // 5) uf = (sum_f fw*arg) * gsum; VQ argmin; codebook gather
    final_kernel<<<4096, blk, 0, stream>>>(fw, arg, gsum, cb, out);
}

// Round 4
// 1397.163 us; speedup vs baseline: 2.5385x; 2.2821x over previous
//
#include <hip/hip_runtime.h>
#include <hip/hip_bf16.h>
#include <cmath>

// ============================================================================
// System2Graph fused pipeline, MI355X (gfx950) — round 4
// Split-bf16 (hi/lo) MFMA GEMMs, BK=64, register-prefetch pipelined K-loop,
// conflict-free swizzled LDS, gate as one 1024-block dispatch with per-f
// stores. out = codebook[argmin ||uf - codebook||^2] (gather).
// ws budget: 142,622,720 bytes (verified available).
// ============================================================================

typedef __bf16 bf16x8 __attribute__((ext_vector_type(8)));
typedef float  f32x4  __attribute__((ext_vector_type(4)));

__device__ __forceinline__ float gelu_f(float v) {
    return 0.5f * v * (1.0f + erff(v * 0.7071067811865476f));
}

__device__ __forceinline__ void split8(const float* v, bf16x8& H, bf16x8& L) {
#pragma unroll
    for (int j = 0; j < 8; ++j) {
        float x = v[j];
        __bf16 h = (__bf16)x;
        H[j] = h;
        L[j] = (__bf16)(x - (float)h);
    }
}

// ---------------------------------------------------------------------------
// LDS layout (BK=64): A hi [0,16K) | A lo [16K,32K) | B hi [32K,48K) | B lo [48K,64K)
// unit(row, g) = 8 k's; byte addr = region + row*128 + ((g ^ (row&7))<<4).
// Writes: 2 lanes/bank (free). Reads (ds_read_b128): 2 lanes/bank (free).
// ---------------------------------------------------------------------------

#define STAGE_WRITE()                                                          \
    _Pragma("unroll")                                                          \
    for (int i = 0; i < 4; ++i) {                                              \
        int u = tid + i * 256;                                                 \
        int arow = u >> 3, ag = u & 7;                                         \
        bf16x8 H, L; split8(ra[i], H, L);                                      \
        char* dst = lds + arow * 128 + ((ag ^ (arow & 7)) << 4);               \
        *(bf16x8*)dst = H; *(bf16x8*)(dst + 16384) = L;                        \
    }                                                                          \
    _Pragma("unroll")                                                          \
    for (int i = 0; i < 4; ++i) {                                              \
        int u = tid + i * 256;                                                 \
        int bcol = u & 127, bgu = u >> 7;                                      \
        bf16x8 H, L; split8(rb[i], H, L);                                      \
        char* dst = lds + 32768 + bcol * 128 + ((bgu ^ (bcol & 7)) << 4);      \
        *(bf16x8*)dst = H; *(bf16x8*)(dst + 16384) = L;                        \
    }

#define MFMA64()                                                               \
    _Pragma("unroll")                                                          \
    for (int ks = 0; ks < 2; ++ks) {                                           \
        bf16x8 ah[4], al[4], bh[4], bl_[4];                                    \
        _Pragma("unroll")                                                      \
        for (int mi = 0; mi < 4; ++mi) {                                       \
            const char* pa = lds + (wr + mi * 16 + rl) * 128                   \
                             + (((ks * 4 + g) ^ (rl & 7)) << 4);               \
            ah[mi] = *(const bf16x8*)pa;                                       \
            al[mi] = *(const bf16x8*)(pa + 16384);                             \
        }                                                                      \
        _Pragma("unroll")                                                      \
        for (int ni = 0; ni < 4; ++ni) {                                       \
            const char* pb = lds + 32768 + (wc + ni * 16 + rl) * 128           \
                             + (((ks * 4 + g) ^ (rl & 7)) << 4);               \
            bh[ni]  = *(const bf16x8*)pb;                                      \
            bl_[ni] = *(const bf16x8*)(pb + 16384);                            \
        }                                                                      \
        _Pragma("unroll")                                                      \
        for (int mi = 0; mi < 4; ++mi)                                         \
            _Pragma("unroll")                                                  \
            for (int ni = 0; ni < 4; ++ni) {                                   \
                acc[mi][ni] = __builtin_amdgcn_mfma_f32_16x16x32_bf16(ah[mi], bh[ni],  acc[mi][ni], 0, 0, 0); \
                acc[mi][ni] = __builtin_amdgcn_mfma_f32_16x16x32_bf16(ah[mi], bl_[ni], acc[mi][ni], 0, 0, 0); \
                acc[mi][ni] = __builtin_amdgcn_mfma_f32_16x16x32_bf16(al[mi], bh[ni],  acc[mi][ni], 0, 0, 0); \
            }                                                                  \
    }

// ---------------------------------------------------------------------------
// Plain GEMM: C[z] = A[rows, K-slice] @ B[z][kbase..][1024].  BK=64 pipelined.
// ---------------------------------------------------------------------------
__global__ __launch_bounds__(256, 2) void gemm64(
    const float* __restrict__ A, int arowBase, int maxrow,
    const float* __restrict__ B, int kbase,
    float* __restrict__ C, int nkt,
    size_t bStrideZ, size_t cStrideZ, int mrows)
{
    __shared__ __align__(16) char lds[65536];
    const int tid = threadIdx.x, wid = tid >> 6, lane = tid & 63;
    const int bm0 = blockIdx.x * 128, bn0 = blockIdx.y * 128;
    const float* Bf = B + blockIdx.z * bStrideZ;
    float* Cp = C + blockIdx.z * cStrideZ;
    const int wr = (wid >> 1) * 64, wc = (wid & 1) * 64;
    const int g = lane >> 4, rl = lane & 15;

    float ra[4][8], rb[4][8];

#define LOADA64(KC0)                                                           \
    _Pragma("unroll")                                                          \
    for (int i = 0; i < 4; ++i) {                                              \
        int u = tid + i * 256;                                                 \
        int r = arowBase + bm0 + (u >> 3); if (r > maxrow) r = maxrow;         \
        const float* s = A + (size_t)r * 1024 + (KC0) + (u & 7) * 8;           \
        *(float4*)&ra[i][0] = ((const float4*)s)[0];                           \
        *(float4*)&ra[i][4] = ((const float4*)s)[1];                           \
    }
#define LOADB64(KC0)                                                           \
    _Pragma("unroll")                                                          \
    for (int i = 0; i < 4; ++i) {                                              \
        int u = tid + i * 256;                                                 \
        int bcol = bn0 + (u & 127);                                            \
        int k0 = kbase + (KC0) + (u >> 7) * 8;                                 \
        _Pragma("unroll")                                                      \
        for (int j = 0; j < 8; ++j)                                            \
            rb[i][j] = Bf[(size_t)(k0 + j) * 1024 + bcol];                     \
    }

    f32x4 acc[4][4];
    f32x4 zero = {0.f, 0.f, 0.f, 0.f};
#pragma unroll
    for (int i = 0; i < 4; ++i)
#pragma unroll
        for (int j = 0; j < 4; ++j) acc[i][j] = zero;

    LOADA64(0) LOADB64(0)
    for (int kt = 0; kt < nkt; ++kt) {
        STAGE_WRITE()
        __syncthreads();
        if (kt + 1 < nkt) { LOADA64((kt + 1) * 64) LOADB64((kt + 1) * 64) }
        MFMA64()
        __syncthreads();
    }
#undef LOADA64
#undef LOADB64

    const int cg = lane & 15, rg = (lane >> 4) * 4;
#pragma unroll
    for (int mi = 0; mi < 4; ++mi) {
#pragma unroll
        for (int i = 0; i < 4; ++i) {
            int row_out = bm0 + wr + mi * 16 + rg + i;
            if (row_out >= mrows) continue;
#pragma unroll
            for (int ni = 0; ni < 4; ++ni) {
                int col = bn0 + wc + ni * 16 + cg;
                Cp[(size_t)row_out * 1024 + col] = acc[mi][ni][i];
            }
        }
    }
}

// ---------------------------------------------------------------------------
// Gate GEMM (all f in grid.z): T = [x | arg_f] @ (Wg0 | Wg1+Wg2), K=2048.
// Epilogue: g4[f][n][d] = fw[n][f] * sigmoid(T + bg[f][d]).
// ---------------------------------------------------------------------------
__global__ __launch_bounds__(256, 2) void gate64(
    const float* __restrict__ x, const float* __restrict__ arg,
    const float* __restrict__ Wg, const float* __restrict__ fw,
    const float* __restrict__ bg, float* __restrict__ g4)
{
    __shared__ __align__(16) char lds[65536];
    const int tid = threadIdx.x, wid = tid >> 6, lane = tid & 63;
    const int bm0 = blockIdx.x * 128, bn0 = blockIdx.y * 128;
    const int f = blockIdx.z;
    const float* Wf = Wg + (size_t)f * 3072 * 1024;
    const float* argf = arg + (size_t)f * 4096 * 1024;
    const int wr = (wid >> 1) * 64, wc = (wid & 1) * 64;
    const int g = lane >> 4, rl = lane & 15;

    float ra[4][8], rb[4][8];

#define LOADA64G(KC0)                                                          \
    _Pragma("unroll")                                                          \
    for (int i = 0; i < 4; ++i) {                                              \
        int u = tid + i * 256;                                                 \
        int n = bm0 + (u >> 3);                                                \
        int k0 = (KC0) + (u & 7) * 8;                                          \
        const float* s = (k0 < 1024) ? (x + (size_t)n * 1024 + k0)             \
                                     : (argf + (size_t)n * 1024 + (k0 - 1024));\
        *(float4*)&ra[i][0] = ((const float4*)s)[0];                           \
        *(float4*)&ra[i][4] = ((const float4*)s)[1];                           \
    }
#define LOADB64G(KC0)                                                          \
    _Pragma("unroll")                                                          \
    for (int i = 0; i < 4; ++i) {                                              \
        int u = tid + i * 256;                                                 \
        int bcol = bn0 + (u & 127);                                            \
        int k0 = (KC0) + (u >> 7) * 8;                                         \
        _Pragma("unroll")                                                      \
        for (int j = 0; j < 8; ++j) {                                          \
            float v = Wf[(size_t)(k0 + j) * 1024 + bcol];                      \
            if (k0 >= 1024) v += Wf[(size_t)(k0 + j + 1024) * 1024 + bcol];    \
            rb[i][j] = v;                                                      \
        }                                                                      \
    }

    f32x4 acc[4][4];
    f32x4 zero = {0.f, 0.f, 0.f, 0.f};
#pragma unroll
    for (int i = 0; i < 4; ++i)
#pragma unroll
        for (int j = 0; j < 4; ++j) acc[i][j] = zero;

    LOADA64G(0) LOADB64G(0)
    for (int kt = 0; kt < 32; ++kt) {
        STAGE_WRITE()
        __syncthreads();
        if (kt + 1 < 32) { LOADA64G((kt + 1) * 64) LOADB64G((kt + 1) * 64) }
        MFMA64()
        __syncthreads();
    }
#undef LOADA64G
#undef LOADB64G

    const int cg = lane & 15, rg = (lane >> 4) * 4;
#pragma unroll
    for (int mi = 0; mi < 4; ++mi) {
#pragma unroll
        for (int i = 0; i < 4; ++i) {
            int row_out = bm0 + wr + mi * 16 + rg + i;
            float fwv = fw[(size_t)row_out * 4 + f];
#pragma unroll
            for (int ni = 0; ni < 4; ++ni) {
                int col = bn0 + wc + ni * 16 + cg;
                float v = acc[mi][ni][i] + bg[f * 1024 + col];
                g4[((size_t)f * 4096 + row_out) * 1024 + col] =
                    fwv / (1.0f + expf(-v));
            }
        }
    }
}

// ---------------------------------------------------------------------------
// fw[n][0..3] = softmax(x[n] @ Wsel + bsel)
// ---------------------------------------------------------------------------
__global__ __launch_bounds__(256) void fw_kernel(
    const float* __restrict__ x, const float* __restrict__ Wsel,
    const float* __restrict__ bsel, float* __restrict__ fw)
{
    __shared__ float sred[16];
    const int n = blockIdx.x;
    const int tid = threadIdx.x, w = tid >> 6, lane = tid & 63;

    float4 xv = *(const float4*)&x[(size_t)n * 1024 + tid * 4];
    float pf0 = 0, pf1 = 0, pf2 = 0, pf3 = 0;
    const float* wrp = &Wsel[(size_t)tid * 16];
    pf0 += xv.x * wrp[0];  pf1 += xv.x * wrp[1];  pf2 += xv.x * wrp[2];  pf3 += xv.x * wrp[3];
    pf0 += xv.y * wrp[4];  pf1 += xv.y * wrp[5];  pf2 += xv.y * wrp[6];  pf3 += xv.y * wrp[7];
    pf0 += xv.z * wrp[8];  pf1 += xv.z * wrp[9];  pf2 += xv.z * wrp[10]; pf3 += xv.z * wrp[11];
    pf0 += xv.w * wrp[12]; pf1 += xv.w * wrp[13]; pf2 += xv.w * wrp[14]; pf3 += xv.w * wrp[15];
    for (int o = 32; o; o >>= 1) {
        pf0 += __shfl_xor(pf0, o); pf1 += __shfl_xor(pf1, o);
        pf2 += __shfl_xor(pf2, o); pf3 += __shfl_xor(pf3, o);
    }
    if (lane == 0) { sred[w*4+0] = pf0; sred[w*4+1] = pf1; sred[w*4+2] = pf2; sred[w*4+3] = pf3; }
    __syncthreads();
    if (tid == 0) {
        float s0 = sred[0] + sred[4] + sred[8]  + sred[12] + bsel[0];
        float s1 = sred[1] + sred[5] + sred[9]  + sred[13] + bsel[1];
        float s2 = sred[2] + sred[6] + sred[10] + sred[14] + bsel[2];
        float s3 = sred[3] + sred[7] + sred[11] + sred[15] + bsel[3];
        float mx = fmaxf(fmaxf(s0, s1), fmaxf(s2, s3));
        float e0 = expf(s0 - mx), e1 = expf(s1 - mx), e2 = expf(s2 - mx), e3 = expf(s3 - mx);
        float inv = 1.0f / (e0 + e1 + e2 + e3);
        float4 o = { e0 * inv, e1 * inv, e2 * inv, e3 * inv };
        *(float4*)&fw[(size_t)n * 4] = o;
    }
}

// ---------------------------------------------------------------------------
// h = hpre + xl + de_proj[idx] + bl -> GELU -> LN -> *g+b; arg = sum_k sw*h
// ---------------------------------------------------------------------------
__global__ __launch_bounds__(256) void ln_fuse_kernel(
    const float* __restrict__ hpre, const float* __restrict__ de_proj,
    const float* __restrict__ bl, const float* __restrict__ ln_g,
    const float* __restrict__ ln_b, const float* __restrict__ sim,
    const int* __restrict__ topk, float* __restrict__ arg,
    int f, int token_base, const float* __restrict__ xl)
{
    __shared__ float red[4 * 1024];
    const int n = token_base + blockIdx.x;
    const int k = threadIdx.x >> 6, lane = threadIdx.x & 63;
    const float* hrow = hpre + ((size_t)blockIdx.x * 4 + k) * 1024;
    const int t  = n & 1023;
    const int tk = topk[(size_t)n * 4 + k];
    int di = t - tk + 256; di = di < 0 ? 0 : (di > 512 ? 512 : di);
    const float* drow = de_proj + ((size_t)f * 513 + di) * 1024;
    const float* blr = bl + f * 1024;
    const float* gr  = ln_g + f * 1024;
    const float* br  = ln_b + f * 1024;
    const float* xr  = xl + (size_t)n * 1024;

    float4 s4 = *(const float4*)&sim[(size_t)n * 4];
    float smax = fmaxf(fmaxf(s4.x, s4.y), fmaxf(s4.z, s4.w));
    float e0 = expf(s4.x - smax), e1 = expf(s4.y - smax);
    float e2 = expf(s4.z - smax), e3 = expf(s4.w - smax);
    float swk = (k == 0 ? e0 : k == 1 ? e1 : k == 2 ? e2 : e3) / (e0 + e1 + e2 + e3);

    float gv[16];
    float ssum = 0.f;
#pragma unroll
    for (int j = 0; j < 4; ++j) {
        int d4 = lane + j * 64;
        float4 h  = *(const float4*)&hrow[d4 * 4];
        float4 dd = *(const float4*)&drow[d4 * 4];
        float4 bb = *(const float4*)&blr[d4 * 4];
        float4 xv = *(const float4*)&xr[d4 * 4];
        float a0 = gelu_f(h.x + xv.x + dd.x + bb.x);
        float a1 = gelu_f(h.y + xv.y + dd.y + bb.y);
        float a2 = gelu_f(h.z + xv.z + dd.z + bb.z);
        float a3 = gelu_f(h.w + xv.w + dd.w + bb.w);
        gv[j*4+0] = a0; gv[j*4+1] = a1; gv[j*4+2] = a2; gv[j*4+3] = a3;
        ssum += a0 + a1 + a2 + a3;
    }
    for (int o = 32; o; o >>= 1) ssum += __shfl_xor(ssum, o);
    float mu = ssum * 0.0009765625f;
    float vs = 0.f;
#pragma unroll
    for (int i = 0; i < 16; ++i) { float dm = gv[i] - mu; vs += dm * dm; }
    for (int o = 32; o; o >>= 1) vs += __shfl_xor(vs, o);
    float rstd = 1.0f / sqrtf(vs * 0.0009765625f + 1e-5f);
#pragma unroll
    for (int j = 0; j < 4; ++j) {
        int d4 = lane + j * 64;
        float4 g4 = *(const float4*)&gr[d4 * 4];
        float4 b4 = *(const float4*)&br[d4 * 4];
        float4 y;
        y.x = ((gv[j*4+0] - mu) * rstd * g4.x + b4.x) * swk;
        y.y = ((gv[j*4+1] - mu) * rstd * g4.y + b4.y) * swk;
        y.z = ((gv[j*4+2] - mu) * rstd * g4.z + b4.z) * swk;
        y.w = ((gv[j*4+3] - mu) * rstd * g4.w + b4.w) * swk;
        *(float4*)&red[k * 1024 + d4 * 4] = y;
    }
    __syncthreads();
    const int p = threadIdx.x;
    float4 r0 = *(const float4*)&red[0 * 1024 + p * 4];
    float4 r1 = *(const float4*)&red[1 * 1024 + p * 4];
    float4 r2 = *(const float4*)&red[2 * 1024 + p * 4];
    float4 r3 = *(const float4*)&red[3 * 1024 + p * 4];
    float4 o;
    o.x = r0.x + r1.x + r2.x + r3.x;
    o.y = r0.y + r1.y + r2.y + r3.y;
    o.z = r0.z + r1.z + r2.z + r3.z;
    o.w = r0.w + r1.w + r2.w + r3.w;
    *(float4*)&arg[((size_t)f * 4096 + n) * 1024 + p * 4] = o;
}

// ---------------------------------------------------------------------------
// uf = (sum_f fw*arg) * (sum_f g4[f]); VQ argmin over 32 codes; gather.
// ---------------------------------------------------------------------------
__global__ __launch_bounds__(256) void final_kernel(
    const float* __restrict__ fw, const float* __restrict__ arg,
    const float* __restrict__ g4, const float* __restrict__ cb,
    float* __restrict__ out)
{
    __shared__ float uf_s[1024];
    __shared__ float score_s[32];
    __shared__ int enc_s;
    const int n = blockIdx.x;
    const int tid = threadIdx.x, w = tid >> 6, lane = tid & 63;

    float4 fwv = *(const float4*)&fw[(size_t)n * 4];
    float fwa[4] = { fwv.x, fwv.y, fwv.z, fwv.w };

    float4 prop = {0, 0, 0, 0}, gs = {0, 0, 0, 0};
#pragma unroll
    for (int f = 0; f < 4; ++f) {
        size_t off = ((size_t)f * 4096 + n) * 1024 + tid * 4;
        float4 av = *(const float4*)&arg[off];
        float4 gv = *(const float4*)&g4[off];
        prop.x += fwa[f] * av.x; prop.y += fwa[f] * av.y;
        prop.z += fwa[f] * av.z; prop.w += fwa[f] * av.w;
        gs.x += gv.x; gs.y += gv.y; gs.z += gv.z; gs.w += gv.w;
    }
    float4 uf;
    uf.x = prop.x * gs.x; uf.y = prop.y * gs.y;
    uf.z = prop.z * gs.z; uf.w = prop.w * gs.w;
    *(float4*)&uf_s[tid * 4] = uf;
    __syncthreads();

#pragma unroll
    for (int cc = 0; cc < 8; ++cc) {
        int c = w * 8 + cc;
        float p = 0.f, q = 0.f;
#pragma unroll
        for (int j = 0; j < 4; ++j) {
            int d4 = lane + j * 64;
            float4 u4 = *(const float4*)&uf_s[d4 * 4];
            float4 c4 = *(const float4*)&cb[(size_t)c * 1024 + d4 * 4];
            p += u4.x * c4.x + u4.y * c4.y + u4.z * c4.z + u4.w * c4.w;
            q += c4.x * c4.x + c4.y * c4.y + c4.z * c4.z + c4.w * c4.w;
        }
        float s = q - 2.0f * p;
        for (int o = 32; o; o >>= 1) s += __shfl_xor(s, o);
        if (lane == 0) score_s[c] = s;
    }
    __syncthreads();
    if (tid < 64) {
        float v; int idx;
        if (lane < 32) { v = score_s[lane]; idx = lane; }
        else           { v = INFINITY;      idx = 1 << 30; }
        for (int o = 16; o; o >>= 1) {
            float ov = __shfl_xor(v, o); int oi = __shfl_xor(idx, o);
            if (ov < v || (ov == v && oi < idx)) { v = ov; idx = oi; }
        }
        if (lane == 0) enc_s = idx;
    }
    __syncthreads();
    const int enc = enc_s;
    float4 o4 = *(const float4*)&cb[(size_t)enc * 1024 + tid * 4];
    *(float4*)&out[(size_t)n * 1024 + tid * 4] = o4;
}

// ---------------------------------------------------------------------------
extern "C" void kernel_launch(void* const* d_in, const int* in_sizes, int n_in,
                              void* d_out, int out_size, void* d_ws, size_t ws_size,
                              hipStream_t stream)
{
    const float* x    = (const float*)d_in[0];
    const float* rf   = (const float*)d_in[1];
    const float* sim  = (const float*)d_in[2];
    const float* Wl   = (const float*)d_in[3];
    const float* bl   = (const float*)d_in[4];
    const float* ln_g = (const float*)d_in[5];
    const float* ln_b = (const float*)d_in[6];
    const float* Wg   = (const float*)d_in[7];
    const float* bg   = (const float*)d_in[8];
    const float* Wsel = (const float*)d_in[9];
    const float* bsel = (const float*)d_in[10];
    const float* dtab = (const float*)d_in[11];
    const float* cb   = (const float*)d_in[12];
    const int*   topk = (const int*)d_in[13];
    float* out = (float*)d_out;
    dim3 blk(256);

    // ws layout (bytes), total budget 142,622,720:
    //   arg @ 0                        67,108,864  (live whole run)
    //   Phase B pool @ 67,108,864:
    //     de_proj @  67,108,864         8,404,992
    //     xl2     @  75,513,856        33,554,432  (2 f's worth)
    //     hbuf    @ 109,068,288        33,554,432  (8192-row chunk)
    //   Phase C (after all ln done, pool dead):
    //     g4      @  67,108,864        67,108,864
    //     fw      @ 134,217,728            65,536
    const size_t NEED = 142622720ull;
    if (ws_size < NEED) return;
    char* ws = (char*)d_ws;
    float* arg     = (float*)(ws + 0);
    float* de_proj = (float*)(ws + 67108864);
    float* xl2     = (float*)(ws + 75513856);
    float* hbuf    = (float*)(ws + 109068288);
    float* g4      = (float*)(ws + 67108864);
    float* fw      = (float*)(ws + 134217728);

    // 1) de_proj[f] = dtab(513, clamped) @ Wl[f][2048:3072]
    gemm64<<<dim3(5, 8, 4), blk, 0, stream>>>(
        dtab, 0, 512, Wl, 2048, de_proj, 16,
        (size_t)3072 * 1024, (size_t)513 * 1024, 513);

    // 2) per f-pair: xl2 = x @ Wl[f][0:1024]; per f: 2 chunks rf @ Wl[f][1024:2048]
    for (int pair = 0; pair < 2; ++pair) {
        gemm64<<<dim3(32, 8, 2), blk, 0, stream>>>(
            x, 0, 4095, Wl + (size_t)pair * 2 * 3072 * 1024, 0, xl2, 16,
            (size_t)3072 * 1024, (size_t)4096 * 1024, 4096);
        for (int fi = 0; fi < 2; ++fi) {
            int f = pair * 2 + fi;
            const float* Wlf = Wl + (size_t)f * 3072 * 1024;
            const float* xlf = xl2 + (size_t)fi * 4096 * 1024;
            for (int ch = 0; ch < 2; ++ch) {
                gemm64<<<dim3(64, 8, 1), blk, 0, stream>>>(
                    rf, ch * 8192, 16383, Wlf, 1024, hbuf, 16, 0, 0, 8192);
                ln_fuse_kernel<<<2048, blk, 0, stream>>>(
                    hbuf, de_proj, bl, ln_g, ln_b, sim, topk, arg,
                    f, ch * 2048, xlf);
            }
        }
    }

    // 3) fw = softmax(x @ Wsel + bsel)
    fw_kernel<<<4096, blk, 0, stream>>>(x, Wsel, bsel, fw);

    // 4) g4[f] = fw[:,f] * sigmoid([x|arg_f] @ (Wg0|Wg1+Wg2) + bg[f])
    gate64<<<dim3(32, 8, 4), blk, 0, stream>>>(x, arg, Wg, fw, bg, g4);

    // 5) uf = (sum_f fw*arg) * (sum_f g4); VQ argmin; codebook gather
    final_kernel<<<4096, blk, 0, stream>>>(fw, arg, g4, cb, out);
}

// Round 5
// 1094.125 us; speedup vs baseline: 3.2416x; 1.2770x over previous
//
#include <hip/hip_runtime.h>
#include <hip/hip_bf16.h>
#include <cmath>

// ============================================================================
// System2Graph fused pipeline, MI355X (gfx950) — round 5
// gate GEMM: B pre-split to hi/lo bf16 tile image (swizzled LDS layout) staged
// via global_load_lds, double-buffered across the MFMA cluster; XCD-chunked
// block swizzle on all GEMMs. h/xl/de GEMMs keep the verified round-4 path.
// ws budget: 142,622,720 bytes.
// ============================================================================

typedef __bf16 bf16x8 __attribute__((ext_vector_type(8)));
typedef float  f32x4  __attribute__((ext_vector_type(4)));

__device__ __forceinline__ float gelu_f(float v) {
    return 0.5f * v * (1.0f + erff(v * 0.7071067811865476f));
}

__device__ __forceinline__ void split8(const float* v, bf16x8& H, bf16x8& L) {
#pragma unroll
    for (int j = 0; j < 8; ++j) {
        float x = v[j];
        __bf16 h = (__bf16)x;
        H[j] = h;
        L[j] = (__bf16)(x - (float)h);
    }
}

#define GLL16(src, dst)                                                        \
    __builtin_amdgcn_global_load_lds(                                          \
        (const __attribute__((address_space(1))) void*)(src),                  \
        (__attribute__((address_space(3))) void*)(dst), 16, 0, 0)

// XCD-chunked bijective remap; requires gridDim product % 8 == 0.
#define SWZ_DECODE()                                                           \
    int bx, by, bz;                                                            \
    {                                                                          \
        const int nx = gridDim.x, ny = gridDim.y;                              \
        const int nwg = nx * ny * (int)gridDim.z;                              \
        const int bid = blockIdx.x + nx * (blockIdx.y + ny * blockIdx.z);      \
        const int q = nwg >> 3;                                                \
        const int rm = (bid & 7) * q + (bid >> 3);                             \
        bx = rm % nx; by = (rm / nx) % ny; bz = rm / (nx * ny);                \
    }

// ---------------------------------------------------------------------------
// Round-4 BK=64 macros (A/B reg-staged, in-kernel split) for gemm64.
// LDS: A hi [0,16K) | A lo [16K,32K) | B hi [32K,48K) | B lo [48K,64K)
// ---------------------------------------------------------------------------
#define STAGE_WRITE()                                                          \
    _Pragma("unroll")                                                          \
    for (int i = 0; i < 4; ++i) {                                              \
        int u = tid + i * 256;                                                 \
        int arow = u >> 3, ag = u & 7;                                         \
        bf16x8 H, L; split8(ra[i], H, L);                                      \
        char* dst = lds + arow * 128 + ((ag ^ (arow & 7)) << 4);               \
        *(bf16x8*)dst = H; *(bf16x8*)(dst + 16384) = L;                        \
    }                                                                          \
    _Pragma("unroll")                                                          \
    for (int i = 0; i < 4; ++i) {                                              \
        int u = tid + i * 256;                                                 \
        int bcol = u & 127, bgu = u >> 7;                                      \
        bf16x8 H, L; split8(rb[i], H, L);                                      \
        char* dst = lds + 32768 + bcol * 128 + ((bgu ^ (bcol & 7)) << 4);      \
        *(bf16x8*)dst = H; *(bf16x8*)(dst + 16384) = L;                        \
    }

#define MFMA64()                                                               \
    _Pragma("unroll")                                                          \
    for (int ks = 0; ks < 2; ++ks) {                                           \
        bf16x8 ah[4], al[4], bh[4], bl_[4];                                    \
        _Pragma("unroll")                                                      \
        for (int mi = 0; mi < 4; ++mi) {                                       \
            const char* pa = lds + (wr + mi * 16 + rl) * 128                   \
                             + (((ks * 4 + g) ^ (rl & 7)) << 4);               \
            ah[mi] = *(const bf16x8*)pa;                                       \
            al[mi] = *(const bf16x8*)(pa + 16384);                             \
        }                                                                      \
        _Pragma("unroll")                                                      \
        for (int ni = 0; ni < 4; ++ni) {                                       \
            const char* pb = lds + 32768 + (wc + ni * 16 + rl) * 128           \
                             + (((ks * 4 + g) ^ (rl & 7)) << 4);               \
            bh[ni]  = *(const bf16x8*)pb;                                      \
            bl_[ni] = *(const bf16x8*)(pb + 16384);                            \
        }                                                                      \
        _Pragma("unroll")                                                      \
        for (int mi = 0; mi < 4; ++mi)                                         \
            _Pragma("unroll")                                                  \
            for (int ni = 0; ni < 4; ++ni) {                                   \
                acc[mi][ni] = __builtin_amdgcn_mfma_f32_16x16x32_bf16(ah[mi], bh[ni],  acc[mi][ni], 0, 0, 0); \
                acc[mi][ni] = __builtin_amdgcn_mfma_f32_16x16x32_bf16(ah[mi], bl_[ni], acc[mi][ni], 0, 0, 0); \
                acc[mi][ni] = __builtin_amdgcn_mfma_f32_16x16x32_bf16(al[mi], bh[ni],  acc[mi][ni], 0, 0, 0); \
            }                                                                  \
    }

// ---------------------------------------------------------------------------
// Plain GEMM (de_proj / xl / h): C[z] = A[rows,K] @ B[z][kbase..][1024], BK=64.
// ---------------------------------------------------------------------------
__global__ __launch_bounds__(256, 2) void gemm64(
    const float* __restrict__ A, int arowBase, int maxrow,
    const float* __restrict__ B, int kbase,
    float* __restrict__ C, int nkt,
    size_t bStrideZ, size_t cStrideZ, int mrows)
{
    __shared__ __align__(16) char lds[65536];
    const int tid = threadIdx.x, wid = tid >> 6, lane = tid & 63;
    SWZ_DECODE();
    const int bm0 = bx * 128, bn0 = by * 128;
    const float* Bf = B + bz * bStrideZ;
    float* Cp = C + bz * cStrideZ;
    const int wr = (wid >> 1) * 64, wc = (wid & 1) * 64;
    const int g = lane >> 4, rl = lane & 15;

    float ra[4][8], rb[4][8];

#define LOADA64(KC0)                                                           \
    _Pragma("unroll")                                                          \
    for (int i = 0; i < 4; ++i) {                                              \
        int u = tid + i * 256;                                                 \
        int r = arowBase + bm0 + (u >> 3); if (r > maxrow) r = maxrow;         \
        const float* s = A + (size_t)r * 1024 + (KC0) + (u & 7) * 8;           \
        *(float4*)&ra[i][0] = ((const float4*)s)[0];                           \
        *(float4*)&ra[i][4] = ((const float4*)s)[1];                           \
    }
#define LOADB64(KC0)                                                           \
    _Pragma("unroll")                                                          \
    for (int i = 0; i < 4; ++i) {                                              \
        int u = tid + i * 256;                                                 \
        int bcol = bn0 + (u & 127);                                            \
        int k0 = kbase + (KC0) + (u >> 7) * 8;                                 \
        _Pragma("unroll")                                                      \
        for (int j = 0; j < 8; ++j)                                            \
            rb[i][j] = Bf[(size_t)(k0 + j) * 1024 + bcol];                     \
    }

    f32x4 acc[4][4];
    f32x4 zero = {0.f, 0.f, 0.f, 0.f};
#pragma unroll
    for (int i = 0; i < 4; ++i)
#pragma unroll
        for (int j = 0; j < 4; ++j) acc[i][j] = zero;

    LOADA64(0) LOADB64(0)
    for (int kt = 0; kt < nkt; ++kt) {
        STAGE_WRITE()
        __syncthreads();
        if (kt + 1 < nkt) { LOADA64((kt + 1) * 64) LOADB64((kt + 1) * 64) }
        MFMA64()
        __syncthreads();
    }
#undef LOADA64
#undef LOADB64

    const int cg = lane & 15, rg = (lane >> 4) * 4;
#pragma unroll
    for (int mi = 0; mi < 4; ++mi) {
#pragma unroll
        for (int i = 0; i < 4; ++i) {
            int row_out = bm0 + wr + mi * 16 + rg + i;
            if (row_out >= mrows) continue;
#pragma unroll
            for (int ni = 0; ni < 4; ++ni) {
                int col = bn0 + wc + ni * 16 + cg;
                Cp[(size_t)row_out * 1024 + col] = acc[mi][ni][i];
            }
        }
    }
}

// ---------------------------------------------------------------------------
// precvt_wg: Wg-summed -> hi/lo bf16 tile image in swizzled LDS layout.
// Image: per (f, colTile ct 0..7, kTile kt 0..63) a 16 KB tile (hi 8K | lo 8K);
// unit(col,g) at col*64 + ((g ^ ((col>>1)&3))<<4). One thread = one col row.
// ---------------------------------------------------------------------------
__global__ __launch_bounds__(256) void precvt_wg(
    const float* __restrict__ Wg, char* __restrict__ img)
{
    const int u = blockIdx.x * 256 + threadIdx.x;   // 262,144 total
    const int col = u & 127;
    const int kt  = (u >> 7) & 63;
    const int ct  = (u >> 13) & 7;
    const int f   = u >> 16;
    const int colg = ct * 128 + col;
    const float* Wf = Wg + (size_t)f * 3072 * 1024;
    const bool sum2 = (kt >= 32);

    float vv[32];
#pragma unroll
    for (int j = 0; j < 32; ++j) {
        int k = kt * 32 + j;
        float v = Wf[(size_t)k * 1024 + colg];
        if (sum2) v += Wf[(size_t)(k + 1024) * 1024 + colg];
        vv[j] = v;
    }
    char* tb = img + ((((size_t)f * 8 + ct) * 64) + kt) * 16384;
    const int swz = (col >> 1) & 3;
#pragma unroll
    for (int g = 0; g < 4; ++g) {
        bf16x8 H, L; split8(&vv[g * 8], H, L);
        char* dst = tb + col * 64 + ((g ^ swz) << 4);
        *(bf16x8*)dst = H;
        *(bf16x8*)(dst + 8192) = L;
    }
}

// ---------------------------------------------------------------------------
// gate_bimg: T = [x | arg_f] @ WgImg (K=2048, BK=32). A reg-staged+split,
// B via global_load_lds double-buffered across the MFMA cluster.
// Epilogue: g2[z] (+)= fw[:,f] * sigmoid(T + bg[f]).   f = fbase + z.
// LDS: A hi [0,8K) lo [8K,16K) | B buf0 [16K,32K) | B buf1 [32K,48K)
// ---------------------------------------------------------------------------
__global__ __launch_bounds__(256, 3) void gate_bimg(
    const float* __restrict__ x, const float* __restrict__ arg,
    const char* __restrict__ img, const float* __restrict__ fw,
    const float* __restrict__ bg, float* __restrict__ g2, int fbase)
{
    __shared__ __align__(16) char lds[49152];
    const int tid = threadIdx.x, wid = tid >> 6, lane = tid & 63;
    SWZ_DECODE();
    const int bm0 = bx * 128, bn0 = by * 128;
    const int z = bz, f = fbase + z;
    const float* argf = arg + (size_t)f * 4096 * 1024;
    const char* Bt = img + (((size_t)f * 8 + by) * 64) * 16384;  // + kt*16384
    const int wr = (wid >> 1) * 64, wc = (wid & 1) * 64;
    const int g = lane >> 4, rl = lane & 15;
    const int goff = ((g ^ ((rl >> 1) & 3)) << 4);
    const int boff = wid * 4096 + lane * 16;

    float ra[2][8];

#define LOADA_G(KT)                                                            \
    _Pragma("unroll")                                                          \
    for (int i = 0; i < 2; ++i) {                                              \
        int u = tid + i * 256;                                                 \
        int r = bm0 + (u >> 2);                                                \
        int k0 = (KT) * 32 + (u & 3) * 8;                                      \
        const float* s = (k0 < 1024) ? (x + (size_t)r * 1024 + k0)             \
                                     : (argf + (size_t)r * 1024 + (k0 - 1024));\
        *(float4*)&ra[i][0] = ((const float4*)s)[0];                           \
        *(float4*)&ra[i][4] = ((const float4*)s)[1];                           \
    }
#define LOADB_G(KT, BUF)                                                       \
    {                                                                          \
        const char* sb = Bt + (size_t)(KT) * 16384 + boff;                     \
        char* db = lds + 16384 + (BUF) * 16384 + boff;                         \
        GLL16(sb,        db);                                                  \
        GLL16(sb + 1024, db + 1024);                                           \
        GLL16(sb + 2048, db + 2048);                                           \
        GLL16(sb + 3072, db + 3072);                                           \
    }

    f32x4 acc[4][4];
    f32x4 zero = {0.f, 0.f, 0.f, 0.f};
#pragma unroll
    for (int i = 0; i < 4; ++i)
#pragma unroll
        for (int j = 0; j < 4; ++j) acc[i][j] = zero;

    LOADA_G(0)
    LOADB_G(0, 0)
    for (int kt = 0; kt < 64; ++kt) {
        __syncthreads();   // drains: B(kt) GLL16s + ra(kt) loads; prev MFMA done
        // stage A(kt)
#pragma unroll
        for (int i = 0; i < 2; ++i) {
            int u = tid + i * 256;
            int row = u >> 2, ag = u & 3;
            bf16x8 H, L; split8(ra[i], H, L);
            char* dst = lds + row * 64 + ((ag ^ ((row >> 1) & 3)) << 4);
            *(bf16x8*)dst = H;
            *(bf16x8*)(dst + 8192) = L;
        }
        __syncthreads();   // A(kt) visible
        if (kt + 1 < 64) {
            LOADB_G(kt + 1, (kt + 1) & 1)   // in flight across MFMA
            LOADA_G(kt + 1)
        }
        {
            const char* LDSA = lds;
            const char* LDSB = lds + 16384 + (kt & 1) * 16384;
            bf16x8 ah[4], al[4], bh[4], bl_[4];
#pragma unroll
            for (int mi = 0; mi < 4; ++mi) {
                const char* pa = LDSA + (wr + mi * 16 + rl) * 64 + goff;
                ah[mi] = *(const bf16x8*)pa;
                al[mi] = *(const bf16x8*)(pa + 8192);
            }
#pragma unroll
            for (int ni = 0; ni < 4; ++ni) {
                const char* pb = LDSB + (wc + ni * 16 + rl) * 64 + goff;
                bh[ni]  = *(const bf16x8*)pb;
                bl_[ni] = *(const bf16x8*)(pb + 8192);
            }
#pragma unroll
            for (int mi = 0; mi < 4; ++mi)
#pragma unroll
                for (int ni = 0; ni < 4; ++ni) {
                    acc[mi][ni] = __builtin_amdgcn_mfma_f32_16x16x32_bf16(ah[mi], bh[ni],  acc[mi][ni], 0, 0, 0);
                    acc[mi][ni] = __builtin_amdgcn_mfma_f32_16x16x32_bf16(ah[mi], bl_[ni], acc[mi][ni], 0, 0, 0);
                    acc[mi][ni] = __builtin_amdgcn_mfma_f32_16x16x32_bf16(al[mi], bh[ni],  acc[mi][ni], 0, 0, 0);
                }
        }
    }
#undef LOADA_G
#undef LOADB_G

    const int cg = lane & 15, rg = (lane >> 4) * 4;
    const bool accum = (fbase > 0);
#pragma unroll
    for (int mi = 0; mi < 4; ++mi) {
#pragma unroll
        for (int i = 0; i < 4; ++i) {
            int row_out = bm0 + wr + mi * 16 + rg + i;
            float fwv = fw[(size_t)row_out * 4 + f];
#pragma unroll
            for (int ni = 0; ni < 4; ++ni) {
                int col = bn0 + wc + ni * 16 + cg;
                float v = acc[mi][ni][i] + bg[f * 1024 + col];
                float s = fwv / (1.0f + expf(-v));
                size_t off = ((size_t)z * 4096 + row_out) * 1024 + col;
                if (accum) g2[off] += s; else g2[off] = s;
            }
        }
    }
}

// ---------------------------------------------------------------------------
// fw[n][0..3] = softmax(x[n] @ Wsel + bsel)
// ---------------------------------------------------------------------------
__global__ __launch_bounds__(256) void fw_kernel(
    const float* __restrict__ x, const float* __restrict__ Wsel,
    const float* __restrict__ bsel, float* __restrict__ fw)
{
    __shared__ float sred[16];
    const int n = blockIdx.x;
    const int tid = threadIdx.x, w = tid >> 6, lane = tid & 63;

    float4 xv = *(const float4*)&x[(size_t)n * 1024 + tid * 4];
    float pf0 = 0, pf1 = 0, pf2 = 0, pf3 = 0;
    const float* wrp = &Wsel[(size_t)tid * 16];
    pf0 += xv.x * wrp[0];  pf1 += xv.x * wrp[1];  pf2 += xv.x * wrp[2];  pf3 += xv.x * wrp[3];
    pf0 += xv.y * wrp[4];  pf1 += xv.y * wrp[5];  pf2 += xv.y * wrp[6];  pf3 += xv.y * wrp[7];
    pf0 += xv.z * wrp[8];  pf1 += xv.z * wrp[9];  pf2 += xv.z * wrp[10]; pf3 += xv.z * wrp[11];
    pf0 += xv.w * wrp[12]; pf1 += xv.w * wrp[13]; pf2 += xv.w * wrp[14]; pf3 += xv.w * wrp[15];
    for (int o = 32; o; o >>= 1) {
        pf0 += __shfl_xor(pf0, o); pf1 += __shfl_xor(pf1, o);
        pf2 += __shfl_xor(pf2, o); pf3 += __shfl_xor(pf3, o);
    }
    if (lane == 0) { sred[w*4+0] = pf0; sred[w*4+1] = pf1; sred[w*4+2] = pf2; sred[w*4+3] = pf3; }
    __syncthreads();
    if (tid == 0) {
        float s0 = sred[0] + sred[4] + sred[8]  + sred[12] + bsel[0];
        float s1 = sred[1] + sred[5] + sred[9]  + sred[13] + bsel[1];
        float s2 = sred[2] + sred[6] + sred[10] + sred[14] + bsel[2];
        float s3 = sred[3] + sred[7] + sred[11] + sred[15] + bsel[3];
        float mx = fmaxf(fmaxf(s0, s1), fmaxf(s2, s3));
        float e0 = expf(s0 - mx), e1 = expf(s1 - mx), e2 = expf(s2 - mx), e3 = expf(s3 - mx);
        float inv = 1.0f / (e0 + e1 + e2 + e3);
        float4 o = { e0 * inv, e1 * inv, e2 * inv, e3 * inv };
        *(float4*)&fw[(size_t)n * 4] = o;
    }
}

// ---------------------------------------------------------------------------
// h = hpre + xl + de_proj[idx] + bl -> GELU -> LN -> *g+b; arg = sum_k sw*h
// ---------------------------------------------------------------------------
__global__ __launch_bounds__(256) void ln_fuse_kernel(
    const float* __restrict__ hpre, const float* __restrict__ de_proj,
    const float* __restrict__ bl, const float* __restrict__ ln_g,
    const float* __restrict__ ln_b, const float* __restrict__ sim,
    const int* __restrict__ topk, float* __restrict__ arg,
    int f, int token_base, const float* __restrict__ xl)
{
    __shared__ float red[4 * 1024];
    const int n = token_base + blockIdx.x;
    const int k = threadIdx.x >> 6, lane = threadIdx.x & 63;
    const float* hrow = hpre + ((size_t)blockIdx.x * 4 + k) * 1024;
    const int t  = n & 1023;
    const int tk = topk[(size_t)n * 4 + k];
    int di = t - tk + 256; di = di < 0 ? 0 : (di > 512 ? 512 : di);
    const float* drow = de_proj + ((size_t)f * 513 + di) * 1024;
    const float* blr = bl + f * 1024;
    const float* gr  = ln_g + f * 1024;
    const float* br  = ln_b + f * 1024;
    const float* xr  = xl + (size_t)n * 1024;

    float4 s4 = *(const float4*)&sim[(size_t)n * 4];
    float smax = fmaxf(fmaxf(s4.x, s4.y), fmaxf(s4.z, s4.w));
    float e0 = expf(s4.x - smax), e1 = expf(s4.y - smax);
    float e2 = expf(s4.z - smax), e3 = expf(s4.w - smax);
    float swk = (k == 0 ? e0 : k == 1 ? e1 : k == 2 ? e2 : e3) / (e0 + e1 + e2 + e3);

    float gv[16];
    float ssum = 0.f;
#pragma unroll
    for (int j = 0; j < 4; ++j) {
        int d4 = lane + j * 64;
        float4 h  = *(const float4*)&hrow[d4 * 4];
        float4 dd = *(const float4*)&drow[d4 * 4];
        float4 bb = *(const float4*)&blr[d4 * 4];
        float4 xv = *(const float4*)&xr[d4 * 4];
        float a0 = gelu_f(h.x + xv.x + dd.x + bb.x);
        float a1 = gelu_f(h.y + xv.y + dd.y + bb.y);
        float a2 = gelu_f(h.z + xv.z + dd.z + bb.z);
        float a3 = gelu_f(h.w + xv.w + dd.w + bb.w);
        gv[j*4+0] = a0; gv[j*4+1] = a1; gv[j*4+2] = a2; gv[j*4+3] = a3;
        ssum += a0 + a1 + a2 + a3;
    }
    for (int o = 32; o; o >>= 1) ssum += __shfl_xor(ssum, o);
    float mu = ssum * 0.0009765625f;
    float vs = 0.f;
#pragma unroll
    for (int i = 0; i < 16; ++i) { float dm = gv[i] - mu; vs += dm * dm; }
    for (int o = 32; o; o >>= 1) vs += __shfl_xor(vs, o);
    float rstd = 1.0f / sqrtf(vs * 0.0009765625f + 1e-5f);
#pragma unroll
    for (int j = 0; j < 4; ++j) {
        int d4 = lane + j * 64;
        float4 g4 = *(const float4*)&gr[d4 * 4];
        float4 b4 = *(const float4*)&br[d4 * 4];
        float4 y;
        y.x = ((gv[j*4+0] - mu) * rstd * g4.x + b4.x) * swk;
        y.y = ((gv[j*4+1] - mu) * rstd * g4.y + b4.y) * swk;
        y.z = ((gv[j*4+2] - mu) * rstd * g4.z + b4.z) * swk;
        y.w = ((gv[j*4+3] - mu) * rstd * g4.w + b4.w) * swk;
        *(float4*)&red[k * 1024 + d4 * 4] = y;
    }
    __syncthreads();
    const int p = threadIdx.x;
    float4 r0 = *(const float4*)&red[0 * 1024 + p * 4];
    float4 r1 = *(const float4*)&red[1 * 1024 + p * 4];
    float4 r2 = *(const float4*)&red[2 * 1024 + p * 4];
    float4 r3 = *(const float4*)&red[3 * 1024 + p * 4];
    float4 o;
    o.x = r0.x + r1.x + r2.x + r3.x;
    o.y = r0.y + r1.y + r2.y + r3.y;
    o.z = r0.z + r1.z + r2.z + r3.z;
    o.w = r0.w + r1.w + r2.w + r3.w;
    *(float4*)&arg[((size_t)f * 4096 + n) * 1024 + p * 4] = o;
}

// ---------------------------------------------------------------------------
// uf = (sum_f fw*arg) * (g2[0]+g2[1]); VQ argmin over 32 codes; gather.
// ---------------------------------------------------------------------------
__global__ __launch_bounds__(256) void final_kernel(
    const float* __restrict__ fw, const float* __restrict__ arg,
    const float* __restrict__ g2, const float* __restrict__ cb,
    float* __restrict__ out)
{
    __shared__ float uf_s[1024];
    __shared__ float score_s[32];
    __shared__ int enc_s;
    const int n = blockIdx.x;
    const int tid = threadIdx.x, w = tid >> 6, lane = tid & 63;

    float4 fwv = *(const float4*)&fw[(size_t)n * 4];
    float fwa[4] = { fwv.x, fwv.y, fwv.z, fwv.w };

    float4 prop = {0, 0, 0, 0};
#pragma unroll
    for (int f = 0; f < 4; ++f) {
        float4 av = *(const float4*)&arg[((size_t)f * 4096 + n) * 1024 + tid * 4];
        prop.x += fwa[f] * av.x; prop.y += fwa[f] * av.y;
        prop.z += fwa[f] * av.z; prop.w += fwa[f] * av.w;
    }
    float4 ga = *(const float4*)&g2[(size_t)n * 1024 + tid * 4];
    float4 gb = *(const float4*)&g2[(size_t)(4096 + n) * 1024 + tid * 4];
    float4 uf;
    uf.x = prop.x * (ga.x + gb.x); uf.y = prop.y * (ga.y + gb.y);
    uf.z = prop.z * (ga.z + gb.z); uf.w = prop.w * (ga.w + gb.w);
    *(float4*)&uf_s[tid * 4] = uf;
    __syncthreads();

#pragma unroll
    for (int cc = 0; cc < 8; ++cc) {
        int c = w * 8 + cc;
        float p = 0.f, q = 0.f;
#pragma unroll
        for (int j = 0; j < 4; ++j) {
            int d4 = lane + j * 64;
            float4 u4 = *(const float4*)&uf_s[d4 * 4];
            float4 c4 = *(const float4*)&cb[(size_t)c * 1024 + d4 * 4];
            p += u4.x * c4.x + u4.y * c4.y + u4.z * c4.z + u4.w * c4.w;
            q += c4.x * c4.x + c4.y * c4.y + c4.z * c4.z + c4.w * c4.w;
        }
        float s = q - 2.0f * p;
        for (int o = 32; o; o >>= 1) s += __shfl_xor(s, o);
        if (lane == 0) score_s[c] = s;
    }
    __syncthreads();
    if (tid < 64) {
        float v; int idx;
        if (lane < 32) { v = score_s[lane]; idx = lane; }
        else           { v = INFINITY;      idx = 1 << 30; }
        for (int o = 16; o; o >>= 1) {
            float ov = __shfl_xor(v, o); int oi = __shfl_xor(idx, o);
            if (ov < v || (ov == v && oi < idx)) { v = ov; idx = oi; }
        }
        if (lane == 0) enc_s = idx;
    }
    __syncthreads();
    const int enc = enc_s;
    float4 o4 = *(const float4*)&cb[(size_t)enc * 1024 + tid * 4];
    *(float4*)&out[(size_t)n * 1024 + tid * 4] = o4;
}

// ---------------------------------------------------------------------------
extern "C" void kernel_launch(void* const* d_in, const int* in_sizes, int n_in,
                              void* d_out, int out_size, void* d_ws, size_t ws_size,
                              hipStream_t stream)
{
    const float* x    = (const float*)d_in[0];
    const float* rf   = (const float*)d_in[1];
    const float* sim  = (const float*)d_in[2];
    const float* Wl   = (const float*)d_in[3];
    const float* bl   = (const float*)d_in[4];
    const float* ln_g = (const float*)d_in[5];
    const float* ln_b = (const float*)d_in[6];
    const float* Wg   = (const float*)d_in[7];
    const float* bg   = (const float*)d_in[8];
    const float* Wsel = (const float*)d_in[9];
    const float* bsel = (const float*)d_in[10];
    const float* dtab = (const float*)d_in[11];
    const float* cb   = (const float*)d_in[12];
    const int*   topk = (const int*)d_in[13];
    float* out = (float*)d_out;
    dim3 blk(256);

    // ws layout (bytes), budget 142,622,720:
    //   arg     @ 0            67,108,864   (live ln -> final)
    //   phase B pool:
    //     de_proj @ 67,108,864  8,404,992
    //     xl2     @ 75,513,856 33,554,432
    //     hbuf    @109,068,288 33,554,432   (ends exactly at 142,622,720)
    //   phase C (pool dead after last ln):
    //     Wgimg   @ 67,108,864 33,554,432
    //     g2      @100,663,296 33,554,432
    //     fw      @134,217,728     65,536
    const size_t NEED = 142622720ull;
    if (ws_size < NEED) return;
    char* ws = (char*)d_ws;
    float* arg     = (float*)(ws + 0);
    float* de_proj = (float*)(ws + 67108864);
    float* xl2     = (float*)(ws + 75513856);
    float* hbuf    = (float*)(ws + 109068288);
    char*  Wgimg   = ws + 67108864;
    float* g2      = (float*)(ws + 100663296);
    float* fw      = (float*)(ws + 134217728);

    // 1) de_proj[f] = dtab(513, clamped) @ Wl[f][2048:3072]
    gemm64<<<dim3(5, 8, 4), blk, 0, stream>>>(
        dtab, 0, 512, Wl, 2048, de_proj, 16,
        (size_t)3072 * 1024, (size_t)513 * 1024, 513);

    // 2) per f-pair: xl2 = x @ Wl[f][0:1024]; per f: 2 chunks rf @ Wl[f][1024:2048]
    for (int pair = 0; pair < 2; ++pair) {
        gemm64<<<dim3(32, 8, 2), blk, 0, stream>>>(
            x, 0, 4095, Wl + (size_t)pair * 2 * 3072 * 1024, 0, xl2, 16,
            (size_t)3072 * 1024, (size_t)4096 * 1024, 4096);
        for (int fi = 0; fi < 2; ++fi) {
            int f = pair * 2 + fi;
            const float* Wlf = Wl + (size_t)f * 3072 * 1024;
            const float* xlf = xl2 + (size_t)fi * 4096 * 1024;
            for (int ch = 0; ch < 2; ++ch) {
                gemm64<<<dim3(64, 8, 1), blk, 0, stream>>>(
                    rf, ch * 8192, 16383, Wlf, 1024, hbuf, 16, 0, 0, 8192);
                ln_fuse_kernel<<<2048, blk, 0, stream>>>(
                    hbuf, de_proj, bl, ln_g, ln_b, sim, topk, arg,
                    f, ch * 2048, xlf);
            }
        }
    }

    // 3) Wg image (summed, split, swizzled tile layout) — pool now dead
    precvt_wg<<<1024, blk, 0, stream>>>(Wg, Wgimg);

    // 4) fw = softmax(x @ Wsel + bsel)
    fw_kernel<<<4096, blk, 0, stream>>>(x, Wsel, bsel, fw);

    // 5) g2[z] = fw[:,z] * sigmoid([x|arg_z] @ Wg[z] + bg[z]);  then += f=z+2
    gate_bimg<<<dim3(32, 8, 2), blk, 0, stream>>>(x, arg, Wgimg, fw, bg, g2, 0);
    gate_bimg<<<dim3(32, 8, 2), blk, 0, stream>>>(x, arg, Wgimg, fw, bg, g2, 2);

    // 6) uf = (sum_f fw*arg) * (g2[0]+g2[1]); VQ argmin; codebook gather
    final_kernel<<<4096, blk, 0, stream>>>(fw, arg, g2, cb, out);
}

// Round 6
// 1012.164 us; speedup vs baseline: 3.5041x; 1.0810x over previous
//
#include <hip/hip_runtime.h>
#include <hip/hip_bf16.h>
#include <cmath>

// ============================================================================
// System2Graph fused pipeline, MI355X (gfx950) — round 6
// All heavy GEMMs (h, gate) use pre-split hi/lo bf16 B-images staged via
// global_load_lds with a single-barrier A/B double-buffered K-loop.
// xl is written directly into arg[f] (in-place RMW in ln_fuse) to free memory
// for the Wl1 image. ws budget: 142,622,720 bytes.
// ============================================================================

typedef __bf16 bf16x8 __attribute__((ext_vector_type(8)));
typedef float  f32x4  __attribute__((ext_vector_type(4)));

__device__ __forceinline__ float gelu_f(float v) {
    return 0.5f * v * (1.0f + erff(v * 0.7071067811865476f));
}

__device__ __forceinline__ void split8(const float* v, bf16x8& H, bf16x8& L) {
#pragma unroll
    for (int j = 0; j < 8; ++j) {
        float x = v[j];
        __bf16 h = (__bf16)x;
        H[j] = h;
        L[j] = (__bf16)(x - (float)h);
    }
}

#define GLL16(src, dst)                                                        \
    __builtin_amdgcn_global_load_lds(                                          \
        (const __attribute__((address_space(1))) void*)(src),                  \
        (__attribute__((address_space(3))) void*)(dst), 16, 0, 0)

// XCD-chunked bijective remap; requires gridDim product % 8 == 0.
#define SWZ_DECODE()                                                           \
    int bx, by, bz;                                                            \
    {                                                                          \
        const int nx = gridDim.x, ny = gridDim.y;                              \
        const int nwg = nx * ny * (int)gridDim.z;                              \
        const int bid = blockIdx.x + nx * (blockIdx.y + ny * blockIdx.z);      \
        const int q = nwg >> 3;                                                \
        const int rm = (bid & 7) * q + (bid >> 3);                             \
        bx = rm % nx; by = (rm / nx) % ny; bz = rm / (nx * ny);                \
    }

// ---------------------------------------------------------------------------
// Image tile layout: per (f, colTile ct, kTile kt): 16 KB (hi 8K | lo 8K);
// unit(col, g) at col*64 + ((g ^ ((col>>1)&3))<<4), 8 bf16 of k.
// Tile base = (((f*8 + ct) << nktLog) + kt) * 16384.
// ---------------------------------------------------------------------------
__global__ __launch_bounds__(256) void precvt_img(
    const float* __restrict__ W, char* __restrict__ img,
    int krowBase, int nktLog, int sumFromKt)
{
    const int u = blockIdx.x * 256 + threadIdx.x;
    const int col = u & 127;
    const int kt  = (u >> 7) & ((1 << nktLog) - 1);
    const int ct  = (u >> (7 + nktLog)) & 7;
    const int f   = u >> (10 + nktLog);
    const int colg = ct * 128 + col;
    const float* Wf = W + (size_t)f * 3072 * 1024;
    const bool sum2 = (kt >= sumFromKt);

    float vv[32];
#pragma unroll
    for (int j = 0; j < 32; ++j) {
        int k = krowBase + kt * 32 + j;
        float v = Wf[(size_t)k * 1024 + colg];
        if (sum2) v += Wf[(size_t)(k + 1024) * 1024 + colg];
        vv[j] = v;
    }
    char* tb = img + ((((size_t)f * 8 + ct) << nktLog) + kt) * 16384;
    const int swz = (col >> 1) & 3;
#pragma unroll
    for (int g = 0; g < 4; ++g) {
        bf16x8 H, L; split8(&vv[g * 8], H, L);
        char* dst = tb + col * 64 + ((g ^ swz) << 4);
        *(bf16x8*)dst = H;
        *(bf16x8*)(dst + 8192) = L;
    }
}

// ---------------------------------------------------------------------------
// Shared macros for the image GEMMs (BK=32, A/B double-buffered, 1 barrier/kt)
// LDS: A0 [0,16K) | A1 [16K,32K) | B0 [32K,48K) | B1 [48K,64K)
// ---------------------------------------------------------------------------
#define WRITEA_SPLIT(AB)                                                       \
    {                                                                          \
        int row = tid >> 2, ag = tid & 3;                                      \
        bf16x8 H, L; split8(ra[0], H, L);                                      \
        char* d = (AB) + row * 64 + ((ag ^ ((row >> 1) & 3)) << 4);            \
        *(bf16x8*)d = H; *(bf16x8*)(d + 8192) = L;                             \
        int row2 = row + 64;                                                   \
        split8(ra[1], H, L);                                                   \
        char* d2 = (AB) + row2 * 64 + ((ag ^ ((row2 >> 1) & 3)) << 4);         \
        *(bf16x8*)d2 = H; *(bf16x8*)(d2 + 8192) = L;                           \
    }

#define LOADB_IMG(KT, BB)                                                      \
    {                                                                          \
        const char* sb = Bt + (size_t)(KT) * 16384 + boff;                     \
        char* db = (BB) + boff;                                                \
        GLL16(sb,        db);                                                  \
        GLL16(sb + 1024, db + 1024);                                           \
        GLL16(sb + 2048, db + 2048);                                           \
        GLL16(sb + 3072, db + 3072);                                           \
    }

#define MFMA32(AB, BB)                                                         \
    {                                                                          \
        bf16x8 ah[4], al[4], bh[4], bl_[4];                                    \
        _Pragma("unroll")                                                      \
        for (int mi = 0; mi < 4; ++mi) {                                       \
            const char* pa = (AB) + (wr + mi * 16 + rl) * 64 + goff;           \
            ah[mi] = *(const bf16x8*)pa;                                       \
            al[mi] = *(const bf16x8*)(pa + 8192);                              \
        }                                                                      \
        _Pragma("unroll")                                                      \
        for (int ni = 0; ni < 4; ++ni) {                                       \
            const char* pb = (BB) + (wc + ni * 16 + rl) * 64 + goff;           \
            bh[ni]  = *(const bf16x8*)pb;                                      \
            bl_[ni] = *(const bf16x8*)(pb + 8192);                             \
        }                                                                      \
        _Pragma("unroll")                                                      \
        for (int mi = 0; mi < 4; ++mi)                                         \
            _Pragma("unroll")                                                  \
            for (int ni = 0; ni < 4; ++ni) {                                   \
                acc[mi][ni] = __builtin_amdgcn_mfma_f32_16x16x32_bf16(ah[mi], bh[ni],  acc[mi][ni], 0, 0, 0); \
                acc[mi][ni] = __builtin_amdgcn_mfma_f32_16x16x32_bf16(ah[mi], bl_[ni], acc[mi][ni], 0, 0, 0); \
                acc[mi][ni] = __builtin_amdgcn_mfma_f32_16x16x32_bf16(al[mi], bh[ni],  acc[mi][ni], 0, 0, 0); \
            }                                                                  \
    }

// ---------------------------------------------------------------------------
// himg: hbuf = rf[rowBase..rowBase+8192) @ Wl1img[fimg]   (K=1024, 32 kt)
// ---------------------------------------------------------------------------
__global__ __launch_bounds__(256, 2) void himg(
    const float* __restrict__ rfA, int rowBase,
    const char* __restrict__ img, int fimg,
    float* __restrict__ hbuf)
{
    __shared__ __align__(16) char lds[65536];
    const int tid = threadIdx.x, wid = tid >> 6, lane = tid & 63;
    SWZ_DECODE();
    (void)bz;
    const int bm0 = bx * 128, bn0 = by * 128;
    const char* Bt = img + (size_t)((fimg * 8 + by) << 5) * 16384;
    const int wr = (wid >> 1) * 64, wc = (wid & 1) * 64;
    const int g = lane >> 4, rl = lane & 15;
    const int goff = ((g ^ ((rl >> 1) & 3)) << 4);
    const int boff = wid * 4096 + lane * 16;
    char* A0 = lds;            char* A1 = lds + 16384;
    char* B0 = lds + 32768;    char* B1 = lds + 49152;

    const float* abase = rfA + (size_t)(rowBase + bm0 + (tid >> 2)) * 1024 + (tid & 3) * 8;
    float ra[2][8];
#define LOADA_H(KT)                                                            \
    {                                                                          \
        const float* s = abase + (KT) * 32;                                    \
        *(float4*)&ra[0][0] = ((const float4*)s)[0];                           \
        *(float4*)&ra[0][4] = ((const float4*)s)[1];                           \
        const float* s2 = s + 64 * 1024;                                       \
        *(float4*)&ra[1][0] = ((const float4*)s2)[0];                          \
        *(float4*)&ra[1][4] = ((const float4*)s2)[1];                          \
    }

    f32x4 acc[4][4];
    f32x4 zero = {0.f, 0.f, 0.f, 0.f};
#pragma unroll
    for (int i = 0; i < 4; ++i)
#pragma unroll
        for (int j = 0; j < 4; ++j) acc[i][j] = zero;

    LOADA_H(0)
    LOADB_IMG(0, B0)
    WRITEA_SPLIT(A0)
    LOADA_H(1)
    __syncthreads();                // B0 GLL16 drained, A0 visible
    for (int kt = 0; kt < 32; ++kt) {
        char* Ac = (kt & 1) ? A1 : A0;  char* Bc = (kt & 1) ? B1 : B0;
        char* An = (kt & 1) ? A0 : A1;  char* Bn = (kt & 1) ? B0 : B1;
        if (kt < 31) {
            LOADB_IMG(kt + 1, Bn)
            WRITEA_SPLIT(An)
            if (kt < 30) LOADA_H(kt + 2)
        }
        MFMA32(Ac, Bc)
        __syncthreads();
    }
#undef LOADA_H

    const int cg = lane & 15, rg = (lane >> 4) * 4;
#pragma unroll
    for (int mi = 0; mi < 4; ++mi)
#pragma unroll
        for (int i = 0; i < 4; ++i) {
            int row_out = bm0 + wr + mi * 16 + rg + i;
#pragma unroll
            for (int ni = 0; ni < 4; ++ni) {
                int col = bn0 + wc + ni * 16 + cg;
                hbuf[(size_t)row_out * 1024 + col] = acc[mi][ni][i];
            }
        }
}

// ---------------------------------------------------------------------------
// gate_img: T = [x | arg_f] @ WgImg (K=2048, 64 kt); epilogue:
// g2[z] (+)= fw[:,f] * sigmoid(T + bg[f]),  f = fbase + z.
// ---------------------------------------------------------------------------
__global__ __launch_bounds__(256, 2) void gate_img(
    const float* __restrict__ x, const float* __restrict__ arg,
    const char* __restrict__ img, const float* __restrict__ fw,
    const float* __restrict__ bg, float* __restrict__ g2, int fbase)
{
    __shared__ __align__(16) char lds[65536];
    const int tid = threadIdx.x, wid = tid >> 6, lane = tid & 63;
    SWZ_DECODE();
    const int bm0 = bx * 128, bn0 = by * 128;
    const int z = bz, f = fbase + z;
    const float* argf = arg + (size_t)f * 4096 * 1024;
    const char* Bt = img + (size_t)((f * 8 + by) << 6) * 16384;
    const int wr = (wid >> 1) * 64, wc = (wid & 1) * 64;
    const int g = lane >> 4, rl = lane & 15;
    const int goff = ((g ^ ((rl >> 1) & 3)) << 4);
    const int boff = wid * 4096 + lane * 16;
    char* A0 = lds;            char* A1 = lds + 16384;
    char* B0 = lds + 32768;    char* B1 = lds + 49152;

    const int arow = bm0 + (tid >> 2);
    const int akc  = (tid & 3) * 8;
    float ra[2][8];
#define LOADA_G(KT)                                                            \
    {                                                                          \
        int k0 = (KT) * 32 + akc;                                              \
        const float* base = (k0 < 1024) ? x : (argf - 1024);                   \
        const float* s  = base + (size_t)arow * 1024 + k0;                     \
        const float* s2 = base + (size_t)(arow + 64) * 1024 + k0;              \
        *(float4*)&ra[0][0] = ((const float4*)s)[0];                           \
        *(float4*)&ra[0][4] = ((const float4*)s)[1];                           \
        *(float4*)&ra[1][0] = ((const float4*)s2)[0];                          \
        *(float4*)&ra[1][4] = ((const float4*)s2)[1];                          \
    }

    f32x4 acc[4][4];
    f32x4 zero = {0.f, 0.f, 0.f, 0.f};
#pragma unroll
    for (int i = 0; i < 4; ++i)
#pragma unroll
        for (int j = 0; j < 4; ++j) acc[i][j] = zero;

    LOADA_G(0)
    LOADB_IMG(0, B0)
    WRITEA_SPLIT(A0)
    LOADA_G(1)
    __syncthreads();
    for (int kt = 0; kt < 64; ++kt) {
        char* Ac = (kt & 1) ? A1 : A0;  char* Bc = (kt & 1) ? B1 : B0;
        char* An = (kt & 1) ? A0 : A1;  char* Bn = (kt & 1) ? B0 : B1;
        if (kt < 63) {
            LOADB_IMG(kt + 1, Bn)
            WRITEA_SPLIT(An)
            if (kt < 62) LOADA_G(kt + 2)
        }
        MFMA32(Ac, Bc)
        __syncthreads();
    }
#undef LOADA_G

    const int cg = lane & 15, rg = (lane >> 4) * 4;
    const bool accum = (fbase > 0);
#pragma unroll
    for (int mi = 0; mi < 4; ++mi)
#pragma unroll
        for (int i = 0; i < 4; ++i) {
            int row_out = bm0 + wr + mi * 16 + rg + i;
            float fwv = fw[(size_t)row_out * 4 + f];
#pragma unroll
            for (int ni = 0; ni < 4; ++ni) {
                int col = bn0 + wc + ni * 16 + cg;
                float v = acc[mi][ni][i] + bg[f * 1024 + col];
                float s = fwv / (1.0f + expf(-v));
                size_t off = ((size_t)z * 4096 + row_out) * 1024 + col;
                if (accum) g2[off] += s; else g2[off] = s;
            }
        }
}

// ---------------------------------------------------------------------------
// gemm64 (round-5, reg-staged): used for de_proj and xl4.
// ---------------------------------------------------------------------------
#define STAGE_WRITE64()                                                        \
    _Pragma("unroll")                                                          \
    for (int i = 0; i < 4; ++i) {                                              \
        int u = tid + i * 256;                                                 \
        int arow = u >> 3, ag = u & 7;                                         \
        bf16x8 H, L; split8(rav[i], H, L);                                     \
        char* dst = lds + arow * 128 + ((ag ^ (arow & 7)) << 4);               \
        *(bf16x8*)dst = H; *(bf16x8*)(dst + 16384) = L;                        \
    }                                                                          \
    _Pragma("unroll")                                                          \
    for (int i = 0; i < 4; ++i) {                                              \
        int u = tid + i * 256;                                                 \
        int bcol = u & 127, bgu = u >> 7;                                      \
        bf16x8 H, L; split8(rbv[i], H, L);                                     \
        char* dst = lds + 32768 + bcol * 128 + ((bgu ^ (bcol & 7)) << 4);      \
        *(bf16x8*)dst = H; *(bf16x8*)(dst + 16384) = L;                        \
    }

#define MFMA64()                                                               \
    _Pragma("unroll")                                                          \
    for (int ks = 0; ks < 2; ++ks) {                                           \
        bf16x8 ah[4], al[4], bh[4], bl_[4];                                    \
        _Pragma("unroll")                                                      \
        for (int mi = 0; mi < 4; ++mi) {                                       \
            const char* pa = lds + (wr + mi * 16 + rl) * 128                   \
                             + (((ks * 4 + g) ^ (rl & 7)) << 4);               \
            ah[mi] = *(const bf16x8*)pa;                                       \
            al[mi] = *(const bf16x8*)(pa + 16384);                             \
        }                                                                      \
        _Pragma("unroll")                                                      \
        for (int ni = 0; ni < 4; ++ni) {                                       \
            const char* pb = lds + 32768 + (wc + ni * 16 + rl) * 128           \
                             + (((ks * 4 + g) ^ (rl & 7)) << 4);               \
            bh[ni]  = *(const bf16x8*)pb;                                      \
            bl_[ni] = *(const bf16x8*)(pb + 16384);                            \
        }                                                                      \
        _Pragma("unroll")                                                      \
        for (int mi = 0; mi < 4; ++mi)                                         \
            _Pragma("unroll")                                                  \
            for (int ni = 0; ni < 4; ++ni) {                                   \
                acc[mi][ni] = __builtin_amdgcn_mfma_f32_16x16x32_bf16(ah[mi], bh[ni],  acc[mi][ni], 0, 0, 0); \
                acc[mi][ni] = __builtin_amdgcn_mfma_f32_16x16x32_bf16(ah[mi], bl_[ni], acc[mi][ni], 0, 0, 0); \
                acc[mi][ni] = __builtin_amdgcn_mfma_f32_16x16x32_bf16(al[mi], bh[ni],  acc[mi][ni], 0, 0, 0); \
            }                                                                  \
    }

__global__ __launch_bounds__(256, 2) void gemm64(
    const float* __restrict__ A, int arowBase, int maxrow,
    const float* __restrict__ B, int kbase,
    float* __restrict__ C, int nkt,
    size_t bStrideZ, size_t cStrideZ, int mrows)
{
    __shared__ __align__(16) char lds[65536];
    const int tid = threadIdx.x, wid = tid >> 6, lane = tid & 63;
    SWZ_DECODE();
    const int bm0 = bx * 128, bn0 = by * 128;
    const float* Bf = B + bz * bStrideZ;
    float* Cp = C + bz * cStrideZ;
    const int wr = (wid >> 1) * 64, wc = (wid & 1) * 64;
    const int g = lane >> 4, rl = lane & 15;

    float rav[4][8], rbv[4][8];

#define LOADA64(KC0)                                                           \
    _Pragma("unroll")                                                          \
    for (int i = 0; i < 4; ++i) {                                              \
        int u = tid + i * 256;                                                 \
        int r = arowBase + bm0 + (u >> 3); if (r > maxrow) r = maxrow;         \
        const float* s = A + (size_t)r * 1024 + (KC0) + (u & 7) * 8;           \
        *(float4*)&rav[i][0] = ((const float4*)s)[0];                          \
        *(float4*)&rav[i][4] = ((const float4*)s)[1];                          \
    }
#define LOADB64(KC0)                                                           \
    _Pragma("unroll")                                                          \
    for (int i = 0; i < 4; ++i) {                                              \
        int u = tid + i * 256;                                                 \
        int bcol = bn0 + (u & 127);                                            \
        int k0 = kbase + (KC0) + (u >> 7) * 8;                                 \
        _Pragma("unroll")                                                      \
        for (int j = 0; j < 8; ++j)                                            \
            rbv[i][j] = Bf[(size_t)(k0 + j) * 1024 + bcol];                    \
    }

    f32x4 acc[4][4];
    f32x4 zero = {0.f, 0.f, 0.f, 0.f};
#pragma unroll
    for (int i = 0; i < 4; ++i)
#pragma unroll
        for (int j = 0; j < 4; ++j) acc[i][j] = zero;

    LOADA64(0) LOADB64(0)
    for (int kt = 0; kt < nkt; ++kt) {
        STAGE_WRITE64()
        __syncthreads();
        if (kt + 1 < nkt) { LOADA64((kt + 1) * 64) LOADB64((kt + 1) * 64) }
        MFMA64()
        __syncthreads();
    }
#undef LOADA64
#undef LOADB64

    const int cg = lane & 15, rg = (lane >> 4) * 4;
#pragma unroll
    for (int mi = 0; mi < 4; ++mi)
#pragma unroll
        for (int i = 0; i < 4; ++i) {
            int row_out = bm0 + wr + mi * 16 + rg + i;
            if (row_out >= mrows) continue;
#pragma unroll
            for (int ni = 0; ni < 4; ++ni) {
                int col = bn0 + wc + ni * 16 + cg;
                Cp[(size_t)row_out * 1024 + col] = acc[mi][ni][i];
            }
        }
}

// ---------------------------------------------------------------------------
// fw[n][0..3] = softmax(x[n] @ Wsel + bsel)
// ---------------------------------------------------------------------------
__global__ __launch_bounds__(256) void fw_kernel(
    const float* __restrict__ x, const float* __restrict__ Wsel,
    const float* __restrict__ bsel, float* __restrict__ fw)
{
    __shared__ float sred[16];
    const int n = blockIdx.x;
    const int tid = threadIdx.x, w = tid >> 6, lane = tid & 63;

    float4 xv = *(const float4*)&x[(size_t)n * 1024 + tid * 4];
    float pf0 = 0, pf1 = 0, pf2 = 0, pf3 = 0;
    const float* wrp = &Wsel[(size_t)tid * 16];
    pf0 += xv.x * wrp[0];  pf1 += xv.x * wrp[1];  pf2 += xv.x * wrp[2];  pf3 += xv.x * wrp[3];
    pf0 += xv.y * wrp[4];  pf1 += xv.y * wrp[5];  pf2 += xv.y * wrp[6];  pf3 += xv.y * wrp[7];
    pf0 += xv.z * wrp[8];  pf1 += xv.z * wrp[9];  pf2 += xv.z * wrp[10]; pf3 += xv.z * wrp[11];
    pf0 += xv.w * wrp[12]; pf1 += xv.w * wrp[13]; pf2 += xv.w * wrp[14]; pf3 += xv.w * wrp[15];
    for (int o = 32; o; o >>= 1) {
        pf0 += __shfl_xor(pf0, o); pf1 += __shfl_xor(pf1, o);
        pf2 += __shfl_xor(pf2, o); pf3 += __shfl_xor(pf3, o);
    }
    if (lane == 0) { sred[w*4+0] = pf0; sred[w*4+1] = pf1; sred[w*4+2] = pf2; sred[w*4+3] = pf3; }
    __syncthreads();
    if (tid == 0) {
        float s0 = sred[0] + sred[4] + sred[8]  + sred[12] + bsel[0];
        float s1 = sred[1] + sred[5] + sred[9]  + sred[13] + bsel[1];
        float s2 = sred[2] + sred[6] + sred[10] + sred[14] + bsel[2];
        float s3 = sred[3] + sred[7] + sred[11] + sred[15] + bsel[3];
        float mx = fmaxf(fmaxf(s0, s1), fmaxf(s2, s3));
        float e0 = expf(s0 - mx), e1 = expf(s1 - mx), e2 = expf(s2 - mx), e3 = expf(s3 - mx);
        float inv = 1.0f / (e0 + e1 + e2 + e3);
        float4 o = { e0 * inv, e1 * inv, e2 * inv, e3 * inv };
        *(float4*)&fw[(size_t)n * 4] = o;
    }
}

// ---------------------------------------------------------------------------
// h = hpre + xl + de_proj[idx] + bl -> GELU -> LN -> *g+b; arg = sum_k sw*h
// xl aliases the output row (arg[f,n]) — read-before-write within the block.
// ---------------------------------------------------------------------------
__global__ __launch_bounds__(256) void ln_fuse_kernel(
    const float* __restrict__ hpre, const float* __restrict__ de_proj,
    const float* __restrict__ bl, const float* __restrict__ ln_g,
    const float* __restrict__ ln_b, const float* __restrict__ sim,
    const int* __restrict__ topk, float* arg,
    int f, int token_base, const float* xl)
{
    __shared__ float red[4 * 1024];
    const int n = token_base + blockIdx.x;
    const int k = threadIdx.x >> 6, lane = threadIdx.x & 63;
    const float* hrow = hpre + ((size_t)blockIdx.x * 4 + k) * 1024;
    const int t  = n & 1023;
    const int tk = topk[(size_t)n * 4 + k];
    int di = t - tk + 256; di = di < 0 ? 0 : (di > 512 ? 512 : di);
    const float* drow = de_proj + ((size_t)f * 513 + di) * 1024;
    const float* blr = bl + f * 1024;
    const float* gr  = ln_g + f * 1024;
    const float* br  = ln_b + f * 1024;
    const float* xr  = xl + (size_t)n * 1024;

    float4 s4 = *(const float4*)&sim[(size_t)n * 4];
    float smax = fmaxf(fmaxf(s4.x, s4.y), fmaxf(s4.z, s4.w));
    float e0 = expf(s4.x - smax), e1 = expf(s4.y - smax);
    float e2 = expf(s4.z - smax), e3 = expf(s4.w - smax);
    float swk = (k == 0 ? e0 : k == 1 ? e1 : k == 2 ? e2 : e3) / (e0 + e1 + e2 + e3);

    float gv[16];
    float ssum = 0.f;
#pragma unroll
    for (int j = 0; j < 4; ++j) {
        int d4 = lane + j * 64;
        float4 h  = *(const float4*)&hrow[d4 * 4];
        float4 dd = *(const float4*)&drow[d4 * 4];
        float4 bb = *(const float4*)&blr[d4 * 4];
        float4 xv = *(const float4*)&xr[d4 * 4];
        float a0 = gelu_f(h.x + xv.x + dd.x + bb.x);
        float a1 = gelu_f(h.y + xv.y + dd.y + bb.y);
        float a2 = gelu_f(h.z + xv.z + dd.z + bb.z);
        float a3 = gelu_f(h.w + xv.w + dd.w + bb.w);
        gv[j*4+0] = a0; gv[j*4+1] = a1; gv[j*4+2] = a2; gv[j*4+3] = a3;
        ssum += a0 + a1 + a2 + a3;
    }
    for (int o = 32; o; o >>= 1) ssum += __shfl_xor(ssum, o);
    float mu = ssum * 0.0009765625f;
    float vs = 0.f;
#pragma unroll
    for (int i = 0; i < 16; ++i) { float dm = gv[i] - mu; vs += dm * dm; }
    for (int o = 32; o; o >>= 1) vs += __shfl_xor(vs, o);
    float rstd = 1.0f / sqrtf(vs * 0.0009765625f + 1e-5f);
#pragma unroll
    for (int j = 0; j < 4; ++j) {
        int d4 = lane + j * 64;
        float4 g4 = *(const float4*)&gr[d4 * 4];
        float4 b4 = *(const float4*)&br[d4 * 4];
        float4 y;
        y.x = ((gv[j*4+0] - mu) * rstd * g4.x + b4.x) * swk;
        y.y = ((gv[j*4+1] - mu) * rstd * g4.y + b4.y) * swk;
        y.z = ((gv[j*4+2] - mu) * rstd * g4.z + b4.z) * swk;
        y.w = ((gv[j*4+3] - mu) * rstd * g4.w + b4.w) * swk;
        *(float4*)&red[k * 1024 + d4 * 4] = y;
    }
    __syncthreads();
    const int p = threadIdx.x;
    float4 r0 = *(const float4*)&red[0 * 1024 + p * 4];
    float4 r1 = *(const float4*)&red[1 * 1024 + p * 4];
    float4 r2 = *(const float4*)&red[2 * 1024 + p * 4];
    float4 r3 = *(const float4*)&red[3 * 1024 + p * 4];
    float4 o;
    o.x = r0.x + r1.x + r2.x + r3.x;
    o.y = r0.y + r1.y + r2.y + r3.y;
    o.z = r0.z + r1.z + r2.z + r3.z;
    o.w = r0.w + r1.w + r2.w + r3.w;
    *(float4*)&arg[((size_t)f * 4096 + n) * 1024 + p * 4] = o;
}

// ---------------------------------------------------------------------------
// uf = (sum_f fw*arg) * (g2[0]+g2[1]); VQ argmin over 32 codes; gather.
// ---------------------------------------------------------------------------
__global__ __launch_bounds__(256) void final_kernel(
    const float* __restrict__ fw, const float* __restrict__ arg,
    const float* __restrict__ g2, const float* __restrict__ cb,
    float* __restrict__ out)
{
    __shared__ float uf_s[1024];
    __shared__ float score_s[32];
    __shared__ int enc_s;
    const int n = blockIdx.x;
    const int tid = threadIdx.x, w = tid >> 6, lane = tid & 63;

    float4 fwv = *(const float4*)&fw[(size_t)n * 4];
    float fwa[4] = { fwv.x, fwv.y, fwv.z, fwv.w };

    float4 prop = {0, 0, 0, 0};
#pragma unroll
    for (int f = 0; f < 4; ++f) {
        float4 av = *(const float4*)&arg[((size_t)f * 4096 + n) * 1024 + tid * 4];
        prop.x += fwa[f] * av.x; prop.y += fwa[f] * av.y;
        prop.z += fwa[f] * av.z; prop.w += fwa[f] * av.w;
    }
    float4 ga = *(const float4*)&g2[(size_t)n * 1024 + tid * 4];
    float4 gb = *(const float4*)&g2[(size_t)(4096 + n) * 1024 + tid * 4];
    float4 uf;
    uf.x = prop.x * (ga.x + gb.x); uf.y = prop.y * (ga.y + gb.y);
    uf.z = prop.z * (ga.z + gb.z); uf.w = prop.w * (ga.w + gb.w);
    *(float4*)&uf_s[tid * 4] = uf;
    __syncthreads();

#pragma unroll
    for (int cc = 0; cc < 8; ++cc) {
        int c = w * 8 + cc;
        float p = 0.f, q = 0.f;
#pragma unroll
        for (int j = 0; j < 4; ++j) {
            int d4 = lane + j * 64;
            float4 u4 = *(const float4*)&uf_s[d4 * 4];
            float4 c4 = *(const float4*)&cb[(size_t)c * 1024 + d4 * 4];
            p += u4.x * c4.x + u4.y * c4.y + u4.z * c4.z + u4.w * c4.w;
            q += c4.x * c4.x + c4.y * c4.y + c4.z * c4.z + c4.w * c4.w;
        }
        float s = q - 2.0f * p;
        for (int o = 32; o; o >>= 1) s += __shfl_xor(s, o);
        if (lane == 0) score_s[c] = s;
    }
    __syncthreads();
    if (tid < 64) {
        float v; int idx;
        if (lane < 32) { v = score_s[lane]; idx = lane; }
        else           { v = INFINITY;      idx = 1 << 30; }
        for (int o = 16; o; o >>= 1) {
            float ov = __shfl_xor(v, o); int oi = __shfl_xor(idx, o);
            if (ov < v || (ov == v && oi < idx)) { v = ov; idx = oi; }
        }
        if (lane == 0) enc_s = idx;
    }
    __syncthreads();
    const int enc = enc_s;
    float4 o4 = *(const float4*)&cb[(size_t)enc * 1024 + tid * 4];
    *(float4*)&out[(size_t)n * 1024 + tid * 4] = o4;
}

// ---------------------------------------------------------------------------
extern "C" void kernel_launch(void* const* d_in, const int* in_sizes, int n_in,
                              void* d_out, int out_size, void* d_ws, size_t ws_size,
                              hipStream_t stream)
{
    const float* x    = (const float*)d_in[0];
    const float* rf   = (const float*)d_in[1];
    const float* sim  = (const float*)d_in[2];
    const float* Wl   = (const float*)d_in[3];
    const float* bl   = (const float*)d_in[4];
    const float* ln_g = (const float*)d_in[5];
    const float* ln_b = (const float*)d_in[6];
    const float* Wg   = (const float*)d_in[7];
    const float* bg   = (const float*)d_in[8];
    const float* Wsel = (const float*)d_in[9];
    const float* bsel = (const float*)d_in[10];
    const float* dtab = (const float*)d_in[11];
    const float* cb   = (const float*)d_in[12];
    const int*   topk = (const int*)d_in[13];
    float* out = (float*)d_out;
    dim3 blk(256);

    // ws layout (bytes), budget 142,622,720:
    //   arg     @ 0            67,108,864   (xl written in-place, then ln output)
    //   phase B:
    //     de_proj @ 67,108,864  8,404,992
    //     hbuf    @ 75,513,856 33,554,432
    //     Wl1img  @109,068,288 16,777,216   (ends 125,845,504)
    //   phase C (B pool dead):
    //     Wgimg   @ 67,108,864 33,554,432
    //     g2      @100,663,296 33,554,432
    //     fw      @134,217,728     65,536   (ends 134,283,264)
    const size_t NEED = 142622720ull;
    if (ws_size < NEED) return;
    char* ws = (char*)d_ws;
    float* arg     = (float*)(ws + 0);
    float* de_proj = (float*)(ws + 67108864);
    float* hbuf    = (float*)(ws + 75513856);
    char*  Wl1img  = ws + 109068288;
    char*  Wgimg   = ws + 67108864;
    float* g2      = (float*)(ws + 100663296);
    float* fw      = (float*)(ws + 134217728);

    // 1) de_proj[f] = dtab(513, clamped) @ Wl[f][2048:3072]
    gemm64<<<dim3(5, 8, 4), blk, 0, stream>>>(
        dtab, 0, 512, Wl, 2048, de_proj, 16,
        (size_t)3072 * 1024, (size_t)513 * 1024, 513);

    // 2) xl4: arg[f] = x @ Wl[f][0:1024]  (one z=4 dispatch, 1024 blocks)
    gemm64<<<dim3(32, 8, 4), blk, 0, stream>>>(
        x, 0, 4095, Wl, 0, arg, 16,
        (size_t)3072 * 1024, (size_t)4096 * 1024, 4096);

    // 3) Wl1 image (hi/lo split, swizzled tile layout)
    precvt_img<<<512, blk, 0, stream>>>(Wl, Wl1img, 1024, 5, 99);

    // 4) per f, per chunk: h GEMM (image path) + fused GELU/LN/softmax-reduce
    for (int f = 0; f < 4; ++f) {
        const float* xlf = arg + (size_t)f * 4096 * 1024;
        for (int ch = 0; ch < 2; ++ch) {
            himg<<<dim3(64, 8), blk, 0, stream>>>(
                rf, ch * 8192, Wl1img, f, hbuf);
            ln_fuse_kernel<<<2048, blk, 0, stream>>>(
                hbuf, de_proj, bl, ln_g, ln_b, sim, topk, arg,
                f, ch * 2048, xlf);
        }
    }

    // 5) Wg image (summed k>=1024, split, swizzled) — phase-B pool dead
    precvt_img<<<1024, blk, 0, stream>>>(Wg, Wgimg, 0, 6, 32);

    // 6) fw = softmax(x @ Wsel + bsel)
    fw_kernel<<<4096, blk, 0, stream>>>(x, Wsel, bsel, fw);

    // 7) g2[z] = fw[:,z] * sigmoid([x|arg_z] @ Wg[z] + bg[z]); then += f=z+2
    gate_img<<<dim3(32, 8, 2), blk, 0, stream>>>(x, arg, Wgimg, fw, bg, g2, 0);
    gate_img<<<dim3(32, 8, 2), blk, 0, stream>>>(x, arg, Wgimg, fw, bg, g2, 2);

    // 8) uf = (sum_f fw*arg) * (g2[0]+g2[1]); VQ argmin; codebook gather
    final_kernel<<<4096, blk, 0, stream>>>(fw, arg, g2, cb, out);
}

// Round 7
// 994.713 us; speedup vs baseline: 3.5656x; 1.0175x over previous
//
#include <hip/hip_runtime.h>
#include <hip/hip_bf16.h>
#include <cmath>

// ============================================================================
// System2Graph fused pipeline, MI355X (gfx950) — round 7
// All GEMMs on the image path (pre-split hi/lo bf16 B staged via
// global_load_lds, single-barrier A/B double-buffered K-loop) except de_proj,
// which is K-split x4 (640 blocks) with a deterministic partial reduce.
// ws budget: 142,622,720 bytes.
// ============================================================================

typedef __bf16 bf16x8 __attribute__((ext_vector_type(8)));
typedef float  f32x4  __attribute__((ext_vector_type(4)));

__device__ __forceinline__ float gelu_f(float v) {
    return 0.5f * v * (1.0f + erff(v * 0.7071067811865476f));
}

__device__ __forceinline__ void split8(const float* v, bf16x8& H, bf16x8& L) {
#pragma unroll
    for (int j = 0; j < 8; ++j) {
        float x = v[j];
        __bf16 h = (__bf16)x;
        H[j] = h;
        L[j] = (__bf16)(x - (float)h);
    }
}

#define GLL16(src, dst)                                                        \
    __builtin_amdgcn_global_load_lds(                                          \
        (const __attribute__((address_space(1))) void*)(src),                  \
        (__attribute__((address_space(3))) void*)(dst), 16, 0, 0)

// XCD-chunked bijective remap; requires gridDim product % 8 == 0.
#define SWZ_DECODE()                                                           \
    int bx, by, bz;                                                            \
    {                                                                          \
        const int nx = gridDim.x, ny = gridDim.y;                              \
        const int nwg = nx * ny * (int)gridDim.z;                              \
        const int bid = blockIdx.x + nx * (blockIdx.y + ny * blockIdx.z);      \
        const int q = nwg >> 3;                                                \
        const int rm = (bid & 7) * q + (bid >> 3);                             \
        bx = rm % nx; by = (rm / nx) % ny; bz = rm / (nx * ny);                \
    }

// ---------------------------------------------------------------------------
// Image tile layout: per (f, colTile ct, kTile kt): 16 KB (hi 8K | lo 8K);
// unit(col, g) at col*64 + ((g ^ ((col>>1)&3))<<4), 8 bf16 of k.
// Tile base = (((f*8 + ct) << nktLog) + kt) * 16384.
// ---------------------------------------------------------------------------
__global__ __launch_bounds__(256) void precvt_img(
    const float* __restrict__ W, char* __restrict__ img,
    int krowBase, int nktLog, int sumFromKt)
{
    const int u = blockIdx.x * 256 + threadIdx.x;
    const int col = u & 127;
    const int kt  = (u >> 7) & ((1 << nktLog) - 1);
    const int ct  = (u >> (7 + nktLog)) & 7;
    const int f   = u >> (10 + nktLog);
    const int colg = ct * 128 + col;
    const float* Wf = W + (size_t)f * 3072 * 1024;
    const bool sum2 = (kt >= sumFromKt);

    float vv[32];
#pragma unroll
    for (int j = 0; j < 32; ++j) {
        int k = krowBase + kt * 32 + j;
        float v = Wf[(size_t)k * 1024 + colg];
        if (sum2) v += Wf[(size_t)(k + 1024) * 1024 + colg];
        vv[j] = v;
    }
    char* tb = img + ((((size_t)f * 8 + ct) << nktLog) + kt) * 16384;
    const int swz = (col >> 1) & 3;
#pragma unroll
    for (int g = 0; g < 4; ++g) {
        bf16x8 H, L; split8(&vv[g * 8], H, L);
        char* dst = tb + col * 64 + ((g ^ swz) << 4);
        *(bf16x8*)dst = H;
        *(bf16x8*)(dst + 8192) = L;
    }
}

// ---------------------------------------------------------------------------
// Shared macros for image GEMMs (BK=32, A/B double-buffered, 1 barrier/kt)
// LDS: A0 [0,16K) | A1 [16K,32K) | B0 [32K,48K) | B1 [48K,64K)
// ---------------------------------------------------------------------------
#define WRITEA_SPLIT(AB)                                                       \
    {                                                                          \
        int row = tid >> 2, ag = tid & 3;                                      \
        bf16x8 H, L; split8(ra[0], H, L);                                      \
        char* d = (AB) + row * 64 + ((ag ^ ((row >> 1) & 3)) << 4);            \
        *(bf16x8*)d = H; *(bf16x8*)(d + 8192) = L;                             \
        int row2 = row + 64;                                                   \
        split8(ra[1], H, L);                                                   \
        char* d2 = (AB) + row2 * 64 + ((ag ^ ((row2 >> 1) & 3)) << 4);         \
        *(bf16x8*)d2 = H; *(bf16x8*)(d2 + 8192) = L;                           \
    }

#define LOADB_IMG(KT, BB)                                                      \
    {                                                                          \
        const char* sb = Bt + (size_t)(KT) * 16384 + boff;                     \
        char* db = (BB) + boff;                                                \
        GLL16(sb,        db);                                                  \
        GLL16(sb + 1024, db + 1024);                                           \
        GLL16(sb + 2048, db + 2048);                                           \
        GLL16(sb + 3072, db + 3072);                                           \
    }

#define MFMA32(AB, BB)                                                         \
    {                                                                          \
        bf16x8 ah[4], al[4], bh[4], bl_[4];                                    \
        _Pragma("unroll")                                                      \
        for (int mi = 0; mi < 4; ++mi) {                                       \
            const char* pa = (AB) + (wr + mi * 16 + rl) * 64 + goff;           \
            ah[mi] = *(const bf16x8*)pa;                                       \
            al[mi] = *(const bf16x8*)(pa + 8192);                              \
        }                                                                      \
        _Pragma("unroll")                                                      \
        for (int ni = 0; ni < 4; ++ni) {                                       \
            const char* pb = (BB) + (wc + ni * 16 + rl) * 64 + goff;           \
            bh[ni]  = *(const bf16x8*)pb;                                      \
            bl_[ni] = *(const bf16x8*)(pb + 8192);                             \
        }                                                                      \
        _Pragma("unroll")                                                      \
        for (int mi = 0; mi < 4; ++mi)                                         \
            _Pragma("unroll")                                                  \
            for (int ni = 0; ni < 4; ++ni) {                                   \
                acc[mi][ni] = __builtin_amdgcn_mfma_f32_16x16x32_bf16(ah[mi], bh[ni],  acc[mi][ni], 0, 0, 0); \
                acc[mi][ni] = __builtin_amdgcn_mfma_f32_16x16x32_bf16(ah[mi], bl_[ni], acc[mi][ni], 0, 0, 0); \
                acc[mi][ni] = __builtin_amdgcn_mfma_f32_16x16x32_bf16(al[mi], bh[ni],  acc[mi][ni], 0, 0, 0); \
            }                                                                  \
    }

// ---------------------------------------------------------------------------
// gemm_img: C[z] = A[rowBase + rows][1024] @ img[fimgBase + z]  (K=1024, 32 kt)
// Used for: himg (z=1, fimgBase=f) and xl4 (z=4, fimgBase=0).
// ---------------------------------------------------------------------------
__global__ __launch_bounds__(256, 2) void gemm_img(
    const float* __restrict__ A, int rowBase,
    const char* __restrict__ img, int fimgBase,
    float* __restrict__ C, size_t cStrideZ)
{
    __shared__ __align__(16) char lds[65536];
    const int tid = threadIdx.x, wid = tid >> 6, lane = tid & 63;
    SWZ_DECODE();
    const int bm0 = bx * 128, bn0 = by * 128;
    const int fimg = fimgBase + bz;
    const char* Bt = img + (size_t)((fimg * 8 + by) << 5) * 16384;
    float* Cp = C + (size_t)bz * cStrideZ;
    const int wr = (wid >> 1) * 64, wc = (wid & 1) * 64;
    const int g = lane >> 4, rl = lane & 15;
    const int goff = ((g ^ ((rl >> 1) & 3)) << 4);
    const int boff = wid * 4096 + lane * 16;
    char* A0 = lds;            char* A1 = lds + 16384;
    char* B0 = lds + 32768;    char* B1 = lds + 49152;

    const float* abase = A + (size_t)(rowBase + bm0 + (tid >> 2)) * 1024 + (tid & 3) * 8;
    float ra[2][8];
#define LOADA_H(KT)                                                            \
    {                                                                          \
        const float* s = abase + (KT) * 32;                                    \
        *(float4*)&ra[0][0] = ((const float4*)s)[0];                           \
        *(float4*)&ra[0][4] = ((const float4*)s)[1];                           \
        const float* s2 = s + 64 * 1024;                                       \
        *(float4*)&ra[1][0] = ((const float4*)s2)[0];                          \
        *(float4*)&ra[1][4] = ((const float4*)s2)[1];                          \
    }

    f32x4 acc[4][4];
    f32x4 zero = {0.f, 0.f, 0.f, 0.f};
#pragma unroll
    for (int i = 0; i < 4; ++i)
#pragma unroll
        for (int j = 0; j < 4; ++j) acc[i][j] = zero;

    LOADA_H(0)
    LOADB_IMG(0, B0)
    WRITEA_SPLIT(A0)
    LOADA_H(1)
    __syncthreads();                // B0 GLL16 drained, A0 visible
    for (int kt = 0; kt < 32; ++kt) {
        char* Ac = (kt & 1) ? A1 : A0;  char* Bc = (kt & 1) ? B1 : B0;
        char* An = (kt & 1) ? A0 : A1;  char* Bn = (kt & 1) ? B0 : B1;
        if (kt < 31) {
            LOADB_IMG(kt + 1, Bn)
            WRITEA_SPLIT(An)
            if (kt < 30) LOADA_H(kt + 2)
        }
        MFMA32(Ac, Bc)
        __syncthreads();
    }
#undef LOADA_H

    const int cg = lane & 15, rg = (lane >> 4) * 4;
#pragma unroll
    for (int mi = 0; mi < 4; ++mi)
#pragma unroll
        for (int i = 0; i < 4; ++i) {
            int row_out = bm0 + wr + mi * 16 + rg + i;
#pragma unroll
            for (int ni = 0; ni < 4; ++ni) {
                int col = bn0 + wc + ni * 16 + cg;
                Cp[(size_t)row_out * 1024 + col] = acc[mi][ni][i];
            }
        }
}

// ---------------------------------------------------------------------------
// gate_img: T = [x | arg_f] @ WgImg (K=2048, 64 kt); epilogue:
// g2[z] (+)= fw[:,f] * sigmoid(T + bg[f]),  f = fbase + z.
// ---------------------------------------------------------------------------
__global__ __launch_bounds__(256, 2) void gate_img(
    const float* __restrict__ x, const float* __restrict__ arg,
    const char* __restrict__ img, const float* __restrict__ fw,
    const float* __restrict__ bg, float* __restrict__ g2, int fbase)
{
    __shared__ __align__(16) char lds[65536];
    const int tid = threadIdx.x, wid = tid >> 6, lane = tid & 63;
    SWZ_DECODE();
    const int bm0 = bx * 128, bn0 = by * 128;
    const int z = bz, f = fbase + z;
    const float* argf = arg + (size_t)f * 4096 * 1024;
    const char* Bt = img + (size_t)((f * 8 + by) << 6) * 16384;
    const int wr = (wid >> 1) * 64, wc = (wid & 1) * 64;
    const int g = lane >> 4, rl = lane & 15;
    const int goff = ((g ^ ((rl >> 1) & 3)) << 4);
    const int boff = wid * 4096 + lane * 16;
    char* A0 = lds;            char* A1 = lds + 16384;
    char* B0 = lds + 32768;    char* B1 = lds + 49152;

    const int arow = bm0 + (tid >> 2);
    const int akc  = (tid & 3) * 8;
    float ra[2][8];
#define LOADA_G(KT)                                                            \
    {                                                                          \
        int k0 = (KT) * 32 + akc;                                              \
        const float* base = (k0 < 1024) ? x : (argf - 1024);                   \
        const float* s  = base + (size_t)arow * 1024 + k0;                     \
        const float* s2 = base + (size_t)(arow + 64) * 1024 + k0;              \
        *(float4*)&ra[0][0] = ((const float4*)s)[0];                           \
        *(float4*)&ra[0][4] = ((const float4*)s)[1];                           \
        *(float4*)&ra[1][0] = ((const float4*)s2)[0];                          \
        *(float4*)&ra[1][4] = ((const float4*)s2)[1];                          \
    }

    f32x4 acc[4][4];
    f32x4 zero = {0.f, 0.f, 0.f, 0.f};
#pragma unroll
    for (int i = 0; i < 4; ++i)
#pragma unroll
        for (int j = 0; j < 4; ++j) acc[i][j] = zero;

    LOADA_G(0)
    LOADB_IMG(0, B0)
    WRITEA_SPLIT(A0)
    LOADA_G(1)
    __syncthreads();
    for (int kt = 0; kt < 64; ++kt) {
        char* Ac = (kt & 1) ? A1 : A0;  char* Bc = (kt & 1) ? B1 : B0;
        char* An = (kt & 1) ? A0 : A1;  char* Bn = (kt & 1) ? B0 : B1;
        if (kt < 63) {
            LOADB_IMG(kt + 1, Bn)
            WRITEA_SPLIT(An)
            if (kt < 62) LOADA_G(kt + 2)
        }
        MFMA32(Ac, Bc)
        __syncthreads();
    }
#undef LOADA_G

    const int cg = lane & 15, rg = (lane >> 4) * 4;
    const bool accum = (fbase > 0);
#pragma unroll
    for (int mi = 0; mi < 4; ++mi)
#pragma unroll
        for (int i = 0; i < 4; ++i) {
            int row_out = bm0 + wr + mi * 16 + rg + i;
            float fwv = fw[(size_t)row_out * 4 + f];
#pragma unroll
            for (int ni = 0; ni < 4; ++ni) {
                int col = bn0 + wc + ni * 16 + cg;
                float v = acc[mi][ni][i] + bg[f * 1024 + col];
                float s = fwv / (1.0f + expf(-v));
                size_t off = ((size_t)z * 4096 + row_out) * 1024 + col;
                if (accum) g2[off] += s; else g2[off] = s;
            }
        }
}

// ---------------------------------------------------------------------------
// deproj_part: K-split x4 partials of de_proj = dtab @ Wl[f][2048:3072].
// z = ks*4 + f (16 z-slices, grid 5x8x16 = 640 blocks). BK=64, nkt=4 (K=256).
// Partial (ks,f) written at pbase + ks*2101248 + f*525312 floats (contiguous
// across de_proj buffer + adjacent hbuf region).
// ---------------------------------------------------------------------------
#define STAGE_WRITE64()                                                        \
    _Pragma("unroll")                                                          \
    for (int i = 0; i < 4; ++i) {                                              \
        int u = tid + i * 256;                                                 \
        int arow = u >> 3, ag = u & 7;                                         \
        bf16x8 H, L; split8(rav[i], H, L);                                     \
        char* dst = lds + arow * 128 + ((ag ^ (arow & 7)) << 4);               \
        *(bf16x8*)dst = H; *(bf16x8*)(dst + 16384) = L;                        \
    }                                                                          \
    _Pragma("unroll")                                                          \
    for (int i = 0; i < 4; ++i) {                                              \
        int u = tid + i * 256;                                                 \
        int bcol = u & 127, bgu = u >> 7;                                      \
        bf16x8 H, L; split8(rbv[i], H, L);                                     \
        char* dst = lds + 32768 + bcol * 128 + ((bgu ^ (bcol & 7)) << 4);      \
        *(bf16x8*)dst = H; *(bf16x8*)(dst + 16384) = L;                        \
    }

#define MFMA64()                                                               \
    _Pragma("unroll")                                                          \
    for (int ks2 = 0; ks2 < 2; ++ks2) {                                        \
        bf16x8 ah[4], al[4], bh[4], bl_[4];                                    \
        _Pragma("unroll")                                                      \
        for (int mi = 0; mi < 4; ++mi) {                                       \
            const char* pa = lds + (wr + mi * 16 + rl) * 128                   \
                             + (((ks2 * 4 + g) ^ (rl & 7)) << 4);              \
            ah[mi] = *(const bf16x8*)pa;                                       \
            al[mi] = *(const bf16x8*)(pa + 16384);                             \
        }                                                                      \
        _Pragma("unroll")                                                      \
        for (int ni = 0; ni < 4; ++ni) {                                       \
            const char* pb = lds + 32768 + (wc + ni * 16 + rl) * 128           \
                             + (((ks2 * 4 + g) ^ (rl & 7)) << 4);              \
            bh[ni]  = *(const bf16x8*)pb;                                      \
            bl_[ni] = *(const bf16x8*)(pb + 16384);                            \
        }                                                                      \
        _Pragma("unroll")                                                      \
        for (int mi = 0; mi < 4; ++mi)                                         \
            _Pragma("unroll")                                                  \
            for (int ni = 0; ni < 4; ++ni) {                                   \
                acc[mi][ni] = __builtin_amdgcn_mfma_f32_16x16x32_bf16(ah[mi], bh[ni],  acc[mi][ni], 0, 0, 0); \
                acc[mi][ni] = __builtin_amdgcn_mfma_f32_16x16x32_bf16(ah[mi], bl_[ni], acc[mi][ni], 0, 0, 0); \
                acc[mi][ni] = __builtin_amdgcn_mfma_f32_16x16x32_bf16(al[mi], bh[ni],  acc[mi][ni], 0, 0, 0); \
            }                                                                  \
    }

__global__ __launch_bounds__(256, 2) void deproj_part(
    const float* __restrict__ dtab, const float* __restrict__ Wl,
    float* __restrict__ pbase)
{
    __shared__ __align__(16) char lds[65536];
    const int tid = threadIdx.x, wid = tid >> 6, lane = tid & 63;
    SWZ_DECODE();
    const int bm0 = bx * 128, bn0 = by * 128;
    const int f = bz & 3, ks = bz >> 2;
    const int akb = ks * 256;
    const float* Bf = Wl + (size_t)f * 3072 * 1024 + (size_t)(2048 + ks * 256) * 1024;
    float* Cp = pbase + (size_t)ks * 2101248 + (size_t)f * 525312;
    const int wr = (wid >> 1) * 64, wc = (wid & 1) * 64;
    const int g = lane >> 4, rl = lane & 15;

    float rav[4][8], rbv[4][8];

#define LOADA_D(KC0)                                                           \
    _Pragma("unroll")                                                          \
    for (int i = 0; i < 4; ++i) {                                              \
        int u = tid + i * 256;                                                 \
        int r = bm0 + (u >> 3); if (r > 512) r = 512;                          \
        const float* s = dtab + (size_t)r * 1024 + akb + (KC0) + (u & 7) * 8;  \
        *(float4*)&rav[i][0] = ((const float4*)s)[0];                          \
        *(float4*)&rav[i][4] = ((const float4*)s)[1];                          \
    }
#define LOADB_D(KC0)                                                           \
    _Pragma("unroll")                                                          \
    for (int i = 0; i < 4; ++i) {                                              \
        int u = tid + i * 256;                                                 \
        int bcol = bn0 + (u & 127);                                            \
        int k0 = (KC0) + (u >> 7) * 8;                                         \
        _Pragma("unroll")                                                      \
        for (int j = 0; j < 8; ++j)                                            \
            rbv[i][j] = Bf[(size_t)(k0 + j) * 1024 + bcol];                    \
    }

    f32x4 acc[4][4];
    f32x4 zero = {0.f, 0.f, 0.f, 0.f};
#pragma unroll
    for (int i = 0; i < 4; ++i)
#pragma unroll
        for (int j = 0; j < 4; ++j) acc[i][j] = zero;

    LOADA_D(0) LOADB_D(0)
    for (int kt = 0; kt < 4; ++kt) {
        STAGE_WRITE64()
        __syncthreads();
        if (kt + 1 < 4) { LOADA_D((kt + 1) * 64) LOADB_D((kt + 1) * 64) }
        MFMA64()
        __syncthreads();
    }
#undef LOADA_D
#undef LOADB_D

    const int cg = lane & 15, rg = (lane >> 4) * 4;
#pragma unroll
    for (int mi = 0; mi < 4; ++mi)
#pragma unroll
        for (int i = 0; i < 4; ++i) {
            int row_out = bm0 + wr + mi * 16 + rg + i;
            if (row_out >= 513) continue;
#pragma unroll
            for (int ni = 0; ni < 4; ++ni) {
                int col = bn0 + wc + ni * 16 + cg;
                Cp[(size_t)row_out * 1024 + col] = acc[mi][ni][i];
            }
        }
}

// de_proj = ((p0 + p1) + p2) + p3  (fixed order, deterministic)
__global__ __launch_bounds__(256) void deproj_reduce(float* __restrict__ p)
{
    const size_t i = ((size_t)blockIdx.x * 256 + threadIdx.x) * 4;
    float4 a = *(float4*)&p[i];
    float4 b = *(const float4*)&p[i + 2101248];
    float4 c = *(const float4*)&p[i + 4202496];
    float4 d = *(const float4*)&p[i + 6303744];
    a.x = ((a.x + b.x) + c.x) + d.x;
    a.y = ((a.y + b.y) + c.y) + d.y;
    a.z = ((a.z + b.z) + c.z) + d.z;
    a.w = ((a.w + b.w) + c.w) + d.w;
    *(float4*)&p[i] = a;
}

// ---------------------------------------------------------------------------
// fw[n][0..3] = softmax(x[n] @ Wsel + bsel)
// ---------------------------------------------------------------------------
__global__ __launch_bounds__(256) void fw_kernel(
    const float* __restrict__ x, const float* __restrict__ Wsel,
    const float* __restrict__ bsel, float* __restrict__ fw)
{
    __shared__ float sred[16];
    const int n = blockIdx.x;
    const int tid = threadIdx.x, w = tid >> 6, lane = tid & 63;

    float4 xv = *(const float4*)&x[(size_t)n * 1024 + tid * 4];
    float pf0 = 0, pf1 = 0, pf2 = 0, pf3 = 0;
    const float* wrp = &Wsel[(size_t)tid * 16];
    pf0 += xv.x * wrp[0];  pf1 += xv.x * wrp[1];  pf2 += xv.x * wrp[2];  pf3 += xv.x * wrp[3];
    pf0 += xv.y * wrp[4];  pf1 += xv.y * wrp[5];  pf2 += xv.y * wrp[6];  pf3 += xv.y * wrp[7];
    pf0 += xv.z * wrp[8];  pf1 += xv.z * wrp[9];  pf2 += xv.z * wrp[10]; pf3 += xv.z * wrp[11];
    pf0 += xv.w * wrp[12]; pf1 += xv.w * wrp[13]; pf2 += xv.w * wrp[14]; pf3 += xv.w * wrp[15];
    for (int o = 32; o; o >>= 1) {
        pf0 += __shfl_xor(pf0, o); pf1 += __shfl_xor(pf1, o);
        pf2 += __shfl_xor(pf2, o); pf3 += __shfl_xor(pf3, o);
    }
    if (lane == 0) { sred[w*4+0] = pf0; sred[w*4+1] = pf1; sred[w*4+2] = pf2; sred[w*4+3] = pf3; }
    __syncthreads();
    if (tid == 0) {
        float s0 = sred[0] + sred[4] + sred[8]  + sred[12] + bsel[0];
        float s1 = sred[1] + sred[5] + sred[9]  + sred[13] + bsel[1];
        float s2 = sred[2] + sred[6] + sred[10] + sred[14] + bsel[2];
        float s3 = sred[3] + sred[7] + sred[11] + sred[15] + bsel[3];
        float mx = fmaxf(fmaxf(s0, s1), fmaxf(s2, s3));
        float e0 = expf(s0 - mx), e1 = expf(s1 - mx), e2 = expf(s2 - mx), e3 = expf(s3 - mx);
        float inv = 1.0f / (e0 + e1 + e2 + e3);
        float4 o = { e0 * inv, e1 * inv, e2 * inv, e3 * inv };
        *(float4*)&fw[(size_t)n * 4] = o;
    }
}

// ---------------------------------------------------------------------------
// h = hpre + xl + de_proj[idx] + bl -> GELU -> LN -> *g+b; arg = sum_k sw*h
// xl aliases the output row (arg[f,n]) — read-before-write within the block.
// ---------------------------------------------------------------------------
__global__ __launch_bounds__(256) void ln_fuse_kernel(
    const float* __restrict__ hpre, const float* __restrict__ de_proj,
    const float* __restrict__ bl, const float* __restrict__ ln_g,
    const float* __restrict__ ln_b, const float* __restrict__ sim,
    const int* __restrict__ topk, float* arg,
    int f, int token_base, const float* xl)
{
    __shared__ float red[4 * 1024];
    const int n = token_base + blockIdx.x;
    const int k = threadIdx.x >> 6, lane = threadIdx.x & 63;
    const float* hrow = hpre + ((size_t)blockIdx.x * 4 + k) * 1024;
    const int t  = n & 1023;
    const int tk = topk[(size_t)n * 4 + k];
    int di = t - tk + 256; di = di < 0 ? 0 : (di > 512 ? 512 : di);
    const float* drow = de_proj + ((size_t)f * 513 + di) * 1024;
    const float* blr = bl + f * 1024;
    const float* gr  = ln_g + f * 1024;
    const float* br  = ln_b + f * 1024;
    const float* xr  = xl + (size_t)n * 1024;

    float4 s4 = *(const float4*)&sim[(size_t)n * 4];
    float smax = fmaxf(fmaxf(s4.x, s4.y), fmaxf(s4.z, s4.w));
    float e0 = expf(s4.x - smax), e1 = expf(s4.y - smax);
    float e2 = expf(s4.z - smax), e3 = expf(s4.w - smax);
    float swk = (k == 0 ? e0 : k == 1 ? e1 : k == 2 ? e2 : e3) / (e0 + e1 + e2 + e3);

    float gv[16];
    float ssum = 0.f;
#pragma unroll
    for (int j = 0; j < 4; ++j) {
        int d4 = lane + j * 64;
        float4 h  = *(const float4*)&hrow[d4 * 4];
        float4 dd = *(const float4*)&drow[d4 * 4];
        float4 bb = *(const float4*)&blr[d4 * 4];
        float4 xv = *(const float4*)&xr[d4 * 4];
        float a0 = gelu_f(h.x + xv.x + dd.x + bb.x);
        float a1 = gelu_f(h.y + xv.y + dd.y + bb.y);
        float a2 = gelu_f(h.z + xv.z + dd.z + bb.z);
        float a3 = gelu_f(h.w + xv.w + dd.w + bb.w);
        gv[j*4+0] = a0; gv[j*4+1] = a1; gv[j*4+2] = a2; gv[j*4+3] = a3;
        ssum += a0 + a1 + a2 + a3;
    }
    for (int o = 32; o; o >>= 1) ssum += __shfl_xor(ssum, o);
    float mu = ssum * 0.0009765625f;
    float vs = 0.f;
#pragma unroll
    for (int i = 0; i < 16; ++i) { float dm = gv[i] - mu; vs += dm * dm; }
    for (int o = 32; o; o >>= 1) vs += __shfl_xor(vs, o);
    float rstd = 1.0f / sqrtf(vs * 0.0009765625f + 1e-5f);
#pragma unroll
    for (int j = 0; j < 4; ++j) {
        int d4 = lane + j * 64;
        float4 g4 = *(const float4*)&gr[d4 * 4];
        float4 b4 = *(const float4*)&br[d4 * 4];
        float4 y;
        y.x = ((gv[j*4+0] - mu) * rstd * g4.x + b4.x) * swk;
        y.y = ((gv[j*4+1] - mu) * rstd * g4.y + b4.y) * swk;
        y.z = ((gv[j*4+2] - mu) * rstd * g4.z + b4.z) * swk;
        y.w = ((gv[j*4+3] - mu) * rstd * g4.w + b4.w) * swk;
        *(float4*)&red[k * 1024 + d4 * 4] = y;
    }
    __syncthreads();
    const int p = threadIdx.x;
    float4 r0 = *(const float4*)&red[0 * 1024 + p * 4];
    float4 r1 = *(const float4*)&red[1 * 1024 + p * 4];
    float4 r2 = *(const float4*)&red[2 * 1024 + p * 4];
    float4 r3 = *(const float4*)&red[3 * 1024 + p * 4];
    float4 o;
    o.x = r0.x + r1.x + r2.x + r3.x;
    o.y = r0.y + r1.y + r2.y + r3.y;
    o.z = r0.z + r1.z + r2.z + r3.z;
    o.w = r0.w + r1.w + r2.w + r3.w;
    *(float4*)&arg[((size_t)f * 4096 + n) * 1024 + p * 4] = o;
}

// ---------------------------------------------------------------------------
// uf = (sum_f fw*arg) * (g2[0]+g2[1]); VQ argmin over 32 codes; gather.
// ---------------------------------------------------------------------------
__global__ __launch_bounds__(256) void final_kernel(
    const float* __restrict__ fw, const float* __restrict__ arg,
    const float* __restrict__ g2, const float* __restrict__ cb,
    float* __restrict__ out)
{
    __shared__ float uf_s[1024];
    __shared__ float score_s[32];
    __shared__ int enc_s;
    const int n = blockIdx.x;
    const int tid = threadIdx.x, w = tid >> 6, lane = tid & 63;

    float4 fwv = *(const float4*)&fw[(size_t)n * 4];
    float fwa[4] = { fwv.x, fwv.y, fwv.z, fwv.w };

    float4 prop = {0, 0, 0, 0};
#pragma unroll
    for (int f = 0; f < 4; ++f) {
        float4 av = *(const float4*)&arg[((size_t)f * 4096 + n) * 1024 + tid * 4];
        prop.x += fwa[f] * av.x; prop.y += fwa[f] * av.y;
        prop.z += fwa[f] * av.z; prop.w += fwa[f] * av.w;
    }
    float4 ga = *(const float4*)&g2[(size_t)n * 1024 + tid * 4];
    float4 gb = *(const float4*)&g2[(size_t)(4096 + n) * 1024 + tid * 4];
    float4 uf;
    uf.x = prop.x * (ga.x + gb.x); uf.y = prop.y * (ga.y + gb.y);
    uf.z = prop.z * (ga.z + gb.z); uf.w = prop.w * (ga.w + gb.w);
    *(float4*)&uf_s[tid * 4] = uf;
    __syncthreads();

#pragma unroll
    for (int cc = 0; cc < 8; ++cc) {
        int c = w * 8 + cc;
        float p = 0.f, q = 0.f;
#pragma unroll
        for (int j = 0; j < 4; ++j) {
            int d4 = lane + j * 64;
            float4 u4 = *(const float4*)&uf_s[d4 * 4];
            float4 c4 = *(const float4*)&cb[(size_t)c * 1024 + d4 * 4];
            p += u4.x * c4.x + u4.y * c4.y + u4.z * c4.z + u4.w * c4.w;
            q += c4.x * c4.x + c4.y * c4.y + c4.z * c4.z + c4.w * c4.w;
        }
        float s = q - 2.0f * p;
        for (int o = 32; o; o >>= 1) s += __shfl_xor(s, o);
        if (lane == 0) score_s[c] = s;
    }
    __syncthreads();
    if (tid < 64) {
        float v; int idx;
        if (lane < 32) { v = score_s[lane]; idx = lane; }
        else           { v = INFINITY;      idx = 1 << 30; }
        for (int o = 16; o; o >>= 1) {
            float ov = __shfl_xor(v, o); int oi = __shfl_xor(idx, o);
            if (ov < v || (ov == v && oi < idx)) { v = ov; idx = oi; }
        }
        if (lane == 0) enc_s = idx;
    }
    __syncthreads();
    const int enc = enc_s;
    float4 o4 = *(const float4*)&cb[(size_t)enc * 1024 + tid * 4];
    *(float4*)&out[(size_t)n * 1024 + tid * 4] = o4;
}

// ---------------------------------------------------------------------------
extern "C" void kernel_launch(void* const* d_in, const int* in_sizes, int n_in,
                              void* d_out, int out_size, void* d_ws, size_t ws_size,
                              hipStream_t stream)
{
    const float* x    = (const float*)d_in[0];
    const float* rf   = (const float*)d_in[1];
    const float* sim  = (const float*)d_in[2];
    const float* Wl   = (const float*)d_in[3];
    const float* bl   = (const float*)d_in[4];
    const float* ln_g = (const float*)d_in[5];
    const float* ln_b = (const float*)d_in[6];
    const float* Wg   = (const float*)d_in[7];
    const float* bg   = (const float*)d_in[8];
    const float* Wsel = (const float*)d_in[9];
    const float* bsel = (const float*)d_in[10];
    const float* dtab = (const float*)d_in[11];
    const float* cb   = (const float*)d_in[12];
    const int*   topk = (const int*)d_in[13];
    float* out = (float*)d_out;
    dim3 blk(256);

    // ws layout (bytes), budget 142,622,720:
    //   arg     @ 0            67,108,864   (xl written in-place, then ln output)
    //   phase B:
    //     de_proj @ 67,108,864  8,404,992   (also K-split partial 0; p1..p3
    //                                        extend into hbuf region)
    //     hbuf    @ 75,513,856 33,554,432
    //     Wl1img  @109,068,288 16,777,216   (ends 125,845,504)
    //     Wl0img  @125,845,504 16,777,216   (ends 142,622,720)
    //   phase C (B pool dead):
    //     Wgimg   @ 67,108,864 33,554,432
    //     g2      @100,663,296 33,554,432
    //     fw      @134,217,728     65,536
    const size_t NEED = 142622720ull;
    if (ws_size < NEED) return;
    char* ws = (char*)d_ws;
    float* arg     = (float*)(ws + 0);
    float* de_proj = (float*)(ws + 67108864);
    float* hbuf    = (float*)(ws + 75513856);
    char*  Wl1img  = ws + 109068288;
    char*  Wl0img  = ws + 125845504;
    char*  Wgimg   = ws + 67108864;
    float* g2      = (float*)(ws + 100663296);
    float* fw      = (float*)(ws + 134217728);

    // 1) de_proj partials (K-split x4, 640 blocks) + deterministic reduce
    deproj_part<<<dim3(5, 8, 16), blk, 0, stream>>>(dtab, Wl, de_proj);
    deproj_reduce<<<2052, blk, 0, stream>>>(de_proj);

    // 2) Wl0 image; xl4: arg[f] = x @ Wl0img[f]  (1024 blocks, image path)
    precvt_img<<<512, blk, 0, stream>>>(Wl, Wl0img, 0, 5, 99);
    gemm_img<<<dim3(32, 8, 4), blk, 0, stream>>>(
        x, 0, Wl0img, 0, arg, (size_t)4096 * 1024);

    // 3) Wl1 image
    precvt_img<<<512, blk, 0, stream>>>(Wl, Wl1img, 1024, 5, 99);

    // 4) per f, per chunk: h GEMM (image path) + fused GELU/LN/softmax-reduce
    for (int f = 0; f < 4; ++f) {
        const float* xlf = arg + (size_t)f * 4096 * 1024;
        for (int ch = 0; ch < 2; ++ch) {
            gemm_img<<<dim3(64, 8, 1), blk, 0, stream>>>(
                rf, ch * 8192, Wl1img, f, hbuf, 0);
            ln_fuse_kernel<<<2048, blk, 0, stream>>>(
                hbuf, de_proj, bl, ln_g, ln_b, sim, topk, arg,
                f, ch * 2048, xlf);
        }
    }

    // 5) Wg image (summed k>=1024) — phase-B pool dead
    precvt_img<<<1024, blk, 0, stream>>>(Wg, Wgimg, 0, 6, 32);

    // 6) fw = softmax(x @ Wsel + bsel)
    fw_kernel<<<4096, blk, 0, stream>>>(x, Wsel, bsel, fw);

    // 7) g2[z] = fw[:,z] * sigmoid([x|arg_z] @ Wg[z] + bg[z]); then += f=z+2
    gate_img<<<dim3(32, 8, 2), blk, 0, stream>>>(x, arg, Wgimg, fw, bg, g2, 0);
    gate_img<<<dim3(32, 8, 2), blk, 0, stream>>>(x, arg, Wgimg, fw, bg, g2, 2);

    // 8) uf = (sum_f fw*arg) * (g2[0]+g2[1]); VQ argmin; codebook gather
    final_kernel<<<4096, blk, 0, stream>>>(fw, arg, g2, cb, out);
}

// Round 8
// 948.856 us; speedup vs baseline: 3.7379x; 1.0483x over previous
//
#include <hip/hip_runtime.h>
#include <hip/hip_bf16.h>
#include <cmath>

// ============================================================================
// System2Graph fused pipeline, MI355X (gfx950) — round 8
// Image GEMMs upgraded to a counted-vmcnt deep pipeline (T3/T4): B triple-
// buffered via global_load_lds with s_waitcnt vmcnt(8) + raw s_barrier (never
// vmcnt(0) in the main loop). Numerically identical to round 7 (absmax 0).
// ws budget: 142,622,720 bytes.
// ============================================================================

typedef __bf16 bf16x8 __attribute__((ext_vector_type(8)));
typedef float  f32x4  __attribute__((ext_vector_type(4)));

__device__ __forceinline__ float gelu_f(float v) {
    return 0.5f * v * (1.0f + erff(v * 0.7071067811865476f));
}

__device__ __forceinline__ void split8(const float* v, bf16x8& H, bf16x8& L) {
#pragma unroll
    for (int j = 0; j < 8; ++j) {
        float x = v[j];
        __bf16 h = (__bf16)x;
        H[j] = h;
        L[j] = (__bf16)(x - (float)h);
    }
}

#define GLL16(src, dst)                                                        \
    __builtin_amdgcn_global_load_lds(                                          \
        (const __attribute__((address_space(1))) void*)(src),                  \
        (__attribute__((address_space(3))) void*)(dst), 16, 0, 0)

// XCD-chunked bijective remap; requires gridDim product % 8 == 0.
#define SWZ_DECODE()                                                           \
    int bx, by, bz;                                                            \
    {                                                                          \
        const int nx = gridDim.x, ny = gridDim.y;                              \
        const int nwg = nx * ny * (int)gridDim.z;                              \
        const int bid = blockIdx.x + nx * (blockIdx.y + ny * blockIdx.z);      \
        const int q = nwg >> 3;                                                \
        const int rm = (bid & 7) * q + (bid >> 3);                             \
        bx = rm % nx; by = (rm / nx) % ny; bz = rm / (nx * ny);                \
    }

#define WAIT_VM(N)                                                             \
    asm volatile("s_waitcnt vmcnt(" #N ")" ::: "memory");                      \
    __builtin_amdgcn_sched_barrier(0);
#define WAIT_LGKM0()                                                           \
    asm volatile("s_waitcnt lgkmcnt(0)" ::: "memory");                         \
    __builtin_amdgcn_sched_barrier(0);

// ---------------------------------------------------------------------------
// Image tile layout: per (f, colTile ct, kTile kt): 16 KB (hi 8K | lo 8K);
// unit(col, g) at col*64 + ((g ^ ((col>>1)&3))<<4), 8 bf16 of k.
// Tile base = (((f*8 + ct) << nktLog) + kt) * 16384.
// ---------------------------------------------------------------------------
__global__ __launch_bounds__(256) void precvt_img(
    const float* __restrict__ W, char* __restrict__ img,
    int krowBase, int nktLog, int sumFromKt)
{
    const int u = blockIdx.x * 256 + threadIdx.x;
    const int col = u & 127;
    const int kt  = (u >> 7) & ((1 << nktLog) - 1);
    const int ct  = (u >> (7 + nktLog)) & 7;
    const int f   = u >> (10 + nktLog);
    const int colg = ct * 128 + col;
    const float* Wf = W + (size_t)f * 3072 * 1024;
    const bool sum2 = (kt >= sumFromKt);

    float vv[32];
#pragma unroll
    for (int j = 0; j < 32; ++j) {
        int k = krowBase + kt * 32 + j;
        float v = Wf[(size_t)k * 1024 + colg];
        if (sum2) v += Wf[(size_t)(k + 1024) * 1024 + colg];
        vv[j] = v;
    }
    char* tb = img + ((((size_t)f * 8 + ct) << nktLog) + kt) * 16384;
    const int swz = (col >> 1) & 3;
#pragma unroll
    for (int g = 0; g < 4; ++g) {
        bf16x8 H, L; split8(&vv[g * 8], H, L);
        char* dst = tb + col * 64 + ((g ^ swz) << 4);
        *(bf16x8*)dst = H;
        *(bf16x8*)(dst + 8192) = L;
    }
}

// ---------------------------------------------------------------------------
// Shared macros for image GEMMs.
// LDS: A0 [0,16K) | A1 [16K,32K) | B0 | B1 | B2  (80 KB total)
// ---------------------------------------------------------------------------
#define WRITEA_SPLIT(AB)                                                       \
    {                                                                          \
        int row = tid >> 2, ag = tid & 3;                                      \
        bf16x8 H, L; split8(ra[0], H, L);                                      \
        char* d = (AB) + row * 64 + ((ag ^ ((row >> 1) & 3)) << 4);            \
        *(bf16x8*)d = H; *(bf16x8*)(d + 8192) = L;                             \
        int row2 = row + 64;                                                   \
        split8(ra[1], H, L);                                                   \
        char* d2 = (AB) + row2 * 64 + ((ag ^ ((row2 >> 1) & 3)) << 4);         \
        *(bf16x8*)d2 = H; *(bf16x8*)(d2 + 8192) = L;                           \
    }

#define LOADB_IMG(KT, BB)                                                      \
    {                                                                          \
        const char* sb = Bt + (size_t)(KT) * 16384 + boff;                     \
        char* db = (BB) + boff;                                                \
        GLL16(sb,        db);                                                  \
        GLL16(sb + 1024, db + 1024);                                           \
        GLL16(sb + 2048, db + 2048);                                           \
        GLL16(sb + 3072, db + 3072);                                           \
    }

#define MFMA32(AB, BB)                                                         \
    {                                                                          \
        bf16x8 ah[4], al[4], bh[4], bl_[4];                                    \
        _Pragma("unroll")                                                      \
        for (int mi = 0; mi < 4; ++mi) {                                       \
            const char* pa = (AB) + (wr + mi * 16 + rl) * 64 + goff;           \
            ah[mi] = *(const bf16x8*)pa;                                       \
            al[mi] = *(const bf16x8*)(pa + 8192);                              \
        }                                                                      \
        _Pragma("unroll")                                                      \
        for (int ni = 0; ni < 4; ++ni) {                                       \
            const char* pb = (BB) + (wc + ni * 16 + rl) * 64 + goff;           \
            bh[ni]  = *(const bf16x8*)pb;                                      \
            bl_[ni] = *(const bf16x8*)(pb + 8192);                             \
        }                                                                      \
        _Pragma("unroll")                                                      \
        for (int mi = 0; mi < 4; ++mi)                                         \
            _Pragma("unroll")                                                  \
            for (int ni = 0; ni < 4; ++ni) {                                   \
                acc[mi][ni] = __builtin_amdgcn_mfma_f32_16x16x32_bf16(ah[mi], bh[ni],  acc[mi][ni], 0, 0, 0); \
                acc[mi][ni] = __builtin_amdgcn_mfma_f32_16x16x32_bf16(ah[mi], bl_[ni], acc[mi][ni], 0, 0, 0); \
                acc[mi][ni] = __builtin_amdgcn_mfma_f32_16x16x32_bf16(al[mi], bh[ni],  acc[mi][ni], 0, 0, 0); \
            }                                                                  \
    }

// Deep-pipelined K-loop body. Invariant at top of iter kt (post-barrier):
//   A(kt) in LDS (Ac), B(kt) complete (Bc0), in flight: A(kt+1) regs + B(kt+1).
#define PIPE_LOOP(NKT, LOADA_MACRO)                                            \
    LOADA_MACRO(0)                                                             \
    LOADB_IMG(0, Bc0)                                                          \
    WRITEA_SPLIT(Ac)                                                           \
    LOADA_MACRO(1)                                                             \
    LOADB_IMG(1, Bc1)                                                          \
    WAIT_VM(8)                                                                 \
    WAIT_LGKM0()                                                               \
    __builtin_amdgcn_s_barrier();                                              \
    for (int kt = 0; kt < (NKT); ++kt) {                                       \
        if (kt + 1 < (NKT)) { WRITEA_SPLIT(An) }                               \
        if (kt + 2 < (NKT)) { LOADA_MACRO(kt + 2) LOADB_IMG(kt + 2, Bc2) }     \
        MFMA32(Ac, Bc0)                                                        \
        if (kt + 1 < (NKT)) {                                                  \
            if (kt + 2 < (NKT)) { WAIT_VM(8) } else { WAIT_VM(0) }             \
            WAIT_LGKM0()                                                       \
            __builtin_amdgcn_s_barrier();                                      \
        }                                                                      \
        char* bt = Bc0; Bc0 = Bc1; Bc1 = Bc2; Bc2 = bt;                        \
        char* at = Ac; Ac = An; An = at;                                       \
    }

// ---------------------------------------------------------------------------
// gemm_img: C[z] = A[rowBase + rows][1024] @ img[fimgBase + z]  (K=1024, 32 kt)
// ---------------------------------------------------------------------------
__global__ __launch_bounds__(256, 2) void gemm_img(
    const float* __restrict__ A, int rowBase,
    const char* __restrict__ img, int fimgBase,
    float* __restrict__ C, size_t cStrideZ)
{
    __shared__ __align__(16) char lds[81920];
    const int tid = threadIdx.x, wid = tid >> 6, lane = tid & 63;
    SWZ_DECODE();
    const int bm0 = bx * 128, bn0 = by * 128;
    const int fimg = fimgBase + bz;
    const char* Bt = img + (size_t)((fimg * 8 + by) << 5) * 16384;
    float* Cp = C + (size_t)bz * cStrideZ;
    const int wr = (wid >> 1) * 64, wc = (wid & 1) * 64;
    const int g = lane >> 4, rl = lane & 15;
    const int goff = ((g ^ ((rl >> 1) & 3)) << 4);
    const int boff = wid * 4096 + lane * 16;
    char* Ac = lds;            char* An = lds + 16384;
    char* Bc0 = lds + 32768;   char* Bc1 = lds + 49152;   char* Bc2 = lds + 65536;

    const float* abase = A + (size_t)(rowBase + bm0 + (tid >> 2)) * 1024 + (tid & 3) * 8;
    float ra[2][8];
#define LOADA_H(KT)                                                            \
    {                                                                          \
        const float* s = abase + (KT) * 32;                                    \
        *(float4*)&ra[0][0] = ((const float4*)s)[0];                           \
        *(float4*)&ra[0][4] = ((const float4*)s)[1];                           \
        const float* s2 = s + 64 * 1024;                                       \
        *(float4*)&ra[1][0] = ((const float4*)s2)[0];                          \
        *(float4*)&ra[1][4] = ((const float4*)s2)[1];                          \
    }

    f32x4 acc[4][4];
    f32x4 zero = {0.f, 0.f, 0.f, 0.f};
#pragma unroll
    for (int i = 0; i < 4; ++i)
#pragma unroll
        for (int j = 0; j < 4; ++j) acc[i][j] = zero;

    PIPE_LOOP(32, LOADA_H)
#undef LOADA_H

    const int cg = lane & 15, rg = (lane >> 4) * 4;
#pragma unroll
    for (int mi = 0; mi < 4; ++mi)
#pragma unroll
        for (int i = 0; i < 4; ++i) {
            int row_out = bm0 + wr + mi * 16 + rg + i;
#pragma unroll
            for (int ni = 0; ni < 4; ++ni) {
                int col = bn0 + wc + ni * 16 + cg;
                Cp[(size_t)row_out * 1024 + col] = acc[mi][ni][i];
            }
        }
}

// ---------------------------------------------------------------------------
// gate_img: T = [x | arg_f] @ WgImg (K=2048, 64 kt); epilogue:
// g2[z] (+)= fw[:,f] * sigmoid(T + bg[f]),  f = fbase + z.
// ---------------------------------------------------------------------------
__global__ __launch_bounds__(256, 2) void gate_img(
    const float* __restrict__ x, const float* __restrict__ arg,
    const char* __restrict__ img, const float* __restrict__ fw,
    const float* __restrict__ bg, float* __restrict__ g2, int fbase)
{
    __shared__ __align__(16) char lds[81920];
    const int tid = threadIdx.x, wid = tid >> 6, lane = tid & 63;
    SWZ_DECODE();
    const int bm0 = bx * 128, bn0 = by * 128;
    const int z = bz, f = fbase + z;
    const float* argf = arg + (size_t)f * 4096 * 1024;
    const char* Bt = img + (size_t)((f * 8 + by) << 6) * 16384;
    const int wr = (wid >> 1) * 64, wc = (wid & 1) * 64;
    const int g = lane >> 4, rl = lane & 15;
    const int goff = ((g ^ ((rl >> 1) & 3)) << 4);
    const int boff = wid * 4096 + lane * 16;
    char* Ac = lds;            char* An = lds + 16384;
    char* Bc0 = lds + 32768;   char* Bc1 = lds + 49152;   char* Bc2 = lds + 65536;

    const int arow = bm0 + (tid >> 2);
    const int akc  = (tid & 3) * 8;
    float ra[2][8];
#define LOADA_G(KT)                                                            \
    {                                                                          \
        int k0 = (KT) * 32 + akc;                                              \
        const float* base = (k0 < 1024) ? x : (argf - 1024);                   \
        const float* s  = base + (size_t)arow * 1024 + k0;                     \
        const float* s2 = base + (size_t)(arow + 64) * 1024 + k0;              \
        *(float4*)&ra[0][0] = ((const float4*)s)[0];                           \
        *(float4*)&ra[0][4] = ((const float4*)s)[1];                           \
        *(float4*)&ra[1][0] = ((const float4*)s2)[0];                          \
        *(float4*)&ra[1][4] = ((const float4*)s2)[1];                          \
    }

    f32x4 acc[4][4];
    f32x4 zero = {0.f, 0.f, 0.f, 0.f};
#pragma unroll
    for (int i = 0; i < 4; ++i)
#pragma unroll
        for (int j = 0; j < 4; ++j) acc[i][j] = zero;

    PIPE_LOOP(64, LOADA_G)
#undef LOADA_G

    const int cg = lane & 15, rg = (lane >> 4) * 4;
    const bool accum = (fbase > 0);
#pragma unroll
    for (int mi = 0; mi < 4; ++mi)
#pragma unroll
        for (int i = 0; i < 4; ++i) {
            int row_out = bm0 + wr + mi * 16 + rg + i;
            float fwv = fw[(size_t)row_out * 4 + f];
#pragma unroll
            for (int ni = 0; ni < 4; ++ni) {
                int col = bn0 + wc + ni * 16 + cg;
                float v = acc[mi][ni][i] + bg[f * 1024 + col];
                float s = fwv / (1.0f + expf(-v));
                size_t off = ((size_t)z * 4096 + row_out) * 1024 + col;
                if (accum) g2[off] += s; else g2[off] = s;
            }
        }
}

// ---------------------------------------------------------------------------
// deproj_part: K-split x4 partials of de_proj = dtab @ Wl[f][2048:3072].
// ---------------------------------------------------------------------------
#define STAGE_WRITE64()                                                        \
    _Pragma("unroll")                                                          \
    for (int i = 0; i < 4; ++i) {                                              \
        int u = tid + i * 256;                                                 \
        int arow = u >> 3, ag = u & 7;                                         \
        bf16x8 H, L; split8(rav[i], H, L);                                     \
        char* dst = lds + arow * 128 + ((ag ^ (arow & 7)) << 4);               \
        *(bf16x8*)dst = H; *(bf16x8*)(dst + 16384) = L;                        \
    }                                                                          \
    _Pragma("unroll")                                                          \
    for (int i = 0; i < 4; ++i) {                                              \
        int u = tid + i * 256;                                                 \
        int bcol = u & 127, bgu = u >> 7;                                      \
        bf16x8 H, L; split8(rbv[i], H, L);                                     \
        char* dst = lds + 32768 + bcol * 128 + ((bgu ^ (bcol & 7)) << 4);      \
        *(bf16x8*)dst = H; *(bf16x8*)(dst + 16384) = L;                        \
    }

#define MFMA64()                                                               \
    _Pragma("unroll")                                                          \
    for (int ks2 = 0; ks2 < 2; ++ks2) {                                        \
        bf16x8 ah[4], al[4], bh[4], bl_[4];                                    \
        _Pragma("unroll")                                                      \
        for (int mi = 0; mi < 4; ++mi) {                                       \
            const char* pa = lds + (wr + mi * 16 + rl) * 128                   \
                             + (((ks2 * 4 + g) ^ (rl & 7)) << 4);              \
            ah[mi] = *(const bf16x8*)pa;                                       \
            al[mi] = *(const bf16x8*)(pa + 16384);                             \
        }                                                                      \
        _Pragma("unroll")                                                      \
        for (int ni = 0; ni < 4; ++ni) {                                       \
            const char* pb = lds + 32768 + (wc + ni * 16 + rl) * 128           \
                             + (((ks2 * 4 + g) ^ (rl & 7)) << 4);              \
            bh[ni]  = *(const bf16x8*)pb;                                      \
            bl_[ni] = *(const bf16x8*)(pb + 16384);                            \
        }                                                                      \
        _Pragma("unroll")                                                      \
        for (int mi = 0; mi < 4; ++mi)                                         \
            _Pragma("unroll")                                                  \
            for (int ni = 0; ni < 4; ++ni) {                                   \
                acc[mi][ni] = __builtin_amdgcn_mfma_f32_16x16x32_bf16(ah[mi], bh[ni],  acc[mi][ni], 0, 0, 0); \
                acc[mi][ni] = __builtin_amdgcn_mfma_f32_16x16x32_bf16(ah[mi], bl_[ni], acc[mi][ni], 0, 0, 0); \
                acc[mi][ni] = __builtin_amdgcn_mfma_f32_16x16x32_bf16(al[mi], bh[ni],  acc[mi][ni], 0, 0, 0); \
            }                                                                  \
    }

__global__ __launch_bounds__(256, 2) void deproj_part(
    const float* __restrict__ dtab, const float* __restrict__ Wl,
    float* __restrict__ pbase)
{
    __shared__ __align__(16) char lds[65536];
    const int tid = threadIdx.x, wid = tid >> 6, lane = tid & 63;
    SWZ_DECODE();
    const int bm0 = bx * 128, bn0 = by * 128;
    const int f = bz & 3, ks = bz >> 2;
    const int akb = ks * 256;
    const float* Bf = Wl + (size_t)f * 3072 * 1024 + (size_t)(2048 + ks * 256) * 1024;
    float* Cp = pbase + (size_t)ks * 2101248 + (size_t)f * 525312;
    const int wr = (wid >> 1) * 64, wc = (wid & 1) * 64;
    const int g = lane >> 4, rl = lane & 15;

    float rav[4][8], rbv[4][8];

#define LOADA_D(KC0)                                                           \
    _Pragma("unroll")                                                          \
    for (int i = 0; i < 4; ++i) {                                              \
        int u = tid + i * 256;                                                 \
        int r = bm0 + (u >> 3); if (r > 512) r = 512;                          \
        const float* s = dtab + (size_t)r * 1024 + akb + (KC0) + (u & 7) * 8;  \
        *(float4*)&rav[i][0] = ((const float4*)s)[0];                          \
        *(float4*)&rav[i][4] = ((const float4*)s)[1];                          \
    }
#define LOADB_D(KC0)                                                           \
    _Pragma("unroll")                                                          \
    for (int i = 0; i < 4; ++i) {                                              \
        int u = tid + i * 256;                                                 \
        int bcol = bn0 + (u & 127);                                            \
        int k0 = (KC0) + (u >> 7) * 8;                                         \
        _Pragma("unroll")                                                      \
        for (int j = 0; j < 8; ++j)                                            \
            rbv[i][j] = Bf[(size_t)(k0 + j) * 1024 + bcol];                    \
    }

    f32x4 acc[4][4];
    f32x4 zero = {0.f, 0.f, 0.f, 0.f};
#pragma unroll
    for (int i = 0; i < 4; ++i)
#pragma unroll
        for (int j = 0; j < 4; ++j) acc[i][j] = zero;

    LOADA_D(0) LOADB_D(0)
    for (int kt = 0; kt < 4; ++kt) {
        STAGE_WRITE64()
        __syncthreads();
        if (kt + 1 < 4) { LOADA_D((kt + 1) * 64) LOADB_D((kt + 1) * 64) }
        MFMA64()
        __syncthreads();
    }
#undef LOADA_D
#undef LOADB_D

    const int cg = lane & 15, rg = (lane >> 4) * 4;
#pragma unroll
    for (int mi = 0; mi < 4; ++mi)
#pragma unroll
        for (int i = 0; i < 4; ++i) {
            int row_out = bm0 + wr + mi * 16 + rg + i;
            if (row_out >= 513) continue;
#pragma unroll
            for (int ni = 0; ni < 4; ++ni) {
                int col = bn0 + wc + ni * 16 + cg;
                Cp[(size_t)row_out * 1024 + col] = acc[mi][ni][i];
            }
        }
}

// de_proj = ((p0 + p1) + p2) + p3  (fixed order, deterministic)
__global__ __launch_bounds__(256) void deproj_reduce(float* __restrict__ p)
{
    const size_t i = ((size_t)blockIdx.x * 256 + threadIdx.x) * 4;
    float4 a = *(float4*)&p[i];
    float4 b = *(const float4*)&p[i + 2101248];
    float4 c = *(const float4*)&p[i + 4202496];
    float4 d = *(const float4*)&p[i + 6303744];
    a.x = ((a.x + b.x) + c.x) + d.x;
    a.y = ((a.y + b.y) + c.y) + d.y;
    a.z = ((a.z + b.z) + c.z) + d.z;
    a.w = ((a.w + b.w) + c.w) + d.w;
    *(float4*)&p[i] = a;
}

// ---------------------------------------------------------------------------
// fw[n][0..3] = softmax(x[n] @ Wsel + bsel)
// ---------------------------------------------------------------------------
__global__ __launch_bounds__(256) void fw_kernel(
    const float* __restrict__ x, const float* __restrict__ Wsel,
    const float* __restrict__ bsel, float* __restrict__ fw)
{
    __shared__ float sred[16];
    const int n = blockIdx.x;
    const int tid = threadIdx.x, w = tid >> 6, lane = tid & 63;

    float4 xv = *(const float4*)&x[(size_t)n * 1024 + tid * 4];
    float pf0 = 0, pf1 = 0, pf2 = 0, pf3 = 0;
    const float* wrp = &Wsel[(size_t)tid * 16];
    pf0 += xv.x * wrp[0];  pf1 += xv.x * wrp[1];  pf2 += xv.x * wrp[2];  pf3 += xv.x * wrp[3];
    pf0 += xv.y * wrp[4];  pf1 += xv.y * wrp[5];  pf2 += xv.y * wrp[6];  pf3 += xv.y * wrp[7];
    pf0 += xv.z * wrp[8];  pf1 += xv.z * wrp[9];  pf2 += xv.z * wrp[10]; pf3 += xv.z * wrp[11];
    pf0 += xv.w * wrp[12]; pf1 += xv.w * wrp[13]; pf2 += xv.w * wrp[14]; pf3 += xv.w * wrp[15];
    for (int o = 32; o; o >>= 1) {
        pf0 += __shfl_xor(pf0, o); pf1 += __shfl_xor(pf1, o);
        pf2 += __shfl_xor(pf2, o); pf3 += __shfl_xor(pf3, o);
    }
    if (lane == 0) { sred[w*4+0] = pf0; sred[w*4+1] = pf1; sred[w*4+2] = pf2; sred[w*4+3] = pf3; }
    __syncthreads();
    if (tid == 0) {
        float s0 = sred[0] + sred[4] + sred[8]  + sred[12] + bsel[0];
        float s1 = sred[1] + sred[5] + sred[9]  + sred[13] + bsel[1];
        float s2 = sred[2] + sred[6] + sred[10] + sred[14] + bsel[2];
        float s3 = sred[3] + sred[7] + sred[11] + sred[15] + bsel[3];
        float mx = fmaxf(fmaxf(s0, s1), fmaxf(s2, s3));
        float e0 = expf(s0 - mx), e1 = expf(s1 - mx), e2 = expf(s2 - mx), e3 = expf(s3 - mx);
        float inv = 1.0f / (e0 + e1 + e2 + e3);
        float4 o = { e0 * inv, e1 * inv, e2 * inv, e3 * inv };
        *(float4*)&fw[(size_t)n * 4] = o;
    }
}

// ---------------------------------------------------------------------------
// h = hpre + xl + de_proj[idx] + bl -> GELU -> LN -> *g+b; arg = sum_k sw*h
// xl aliases the output row (arg[f,n]) — read-before-write within the block.
// ---------------------------------------------------------------------------
__global__ __launch_bounds__(256) void ln_fuse_kernel(
    const float* __restrict__ hpre, const float* __restrict__ de_proj,
    const float* __restrict__ bl, const float* __restrict__ ln_g,
    const float* __restrict__ ln_b, const float* __restrict__ sim,
    const int* __restrict__ topk, float* arg,
    int f, int token_base, const float* xl)
{
    __shared__ float red[4 * 1024];
    const int n = token_base + blockIdx.x;
    const int k = threadIdx.x >> 6, lane = threadIdx.x & 63;
    const float* hrow = hpre + ((size_t)blockIdx.x * 4 + k) * 1024;
    const int t  = n & 1023;
    const int tk = topk[(size_t)n * 4 + k];
    int di = t - tk + 256; di = di < 0 ? 0 : (di > 512 ? 512 : di);
    const float* drow = de_proj + ((size_t)f * 513 + di) * 1024;
    const float* blr = bl + f * 1024;
    const float* gr  = ln_g + f * 1024;
    const float* br  = ln_b + f * 1024;
    const float* xr  = xl + (size_t)n * 1024;

    float4 s4 = *(const float4*)&sim[(size_t)n * 4];
    float smax = fmaxf(fmaxf(s4.x, s4.y), fmaxf(s4.z, s4.w));
    float e0 = expf(s4.x - smax), e1 = expf(s4.y - smax);
    float e2 = expf(s4.z - smax), e3 = expf(s4.w - smax);
    float swk = (k == 0 ? e0 : k == 1 ? e1 : k == 2 ? e2 : e3) / (e0 + e1 + e2 + e3);

    float gv[16];
    float ssum = 0.f;
#pragma unroll
    for (int j = 0; j < 4; ++j) {
        int d4 = lane + j * 64;
        float4 h  = *(const float4*)&hrow[d4 * 4];
        float4 dd = *(const float4*)&drow[d4 * 4];
        float4 bb = *(const float4*)&blr[d4 * 4];
        float4 xv = *(const float4*)&xr[d4 * 4];
        float a0 = gelu_f(h.x + xv.x + dd.x + bb.x);
        float a1 = gelu_f(h.y + xv.y + dd.y + bb.y);
        float a2 = gelu_f(h.z + xv.z + dd.z + bb.z);
        float a3 = gelu_f(h.w + xv.w + dd.w + bb.w);
        gv[j*4+0] = a0; gv[j*4+1] = a1; gv[j*4+2] = a2; gv[j*4+3] = a3;
        ssum += a0 + a1 + a2 + a3;
    }
    for (int o = 32; o; o >>= 1) ssum += __shfl_xor(ssum, o);
    float mu = ssum * 0.0009765625f;
    float vs = 0.f;
#pragma unroll
    for (int i = 0; i < 16; ++i) { float dm = gv[i] - mu; vs += dm * dm; }
    for (int o = 32; o; o >>= 1) vs += __shfl_xor(vs, o);
    float rstd = 1.0f / sqrtf(vs * 0.0009765625f + 1e-5f);
#pragma unroll
    for (int j = 0; j < 4; ++j) {
        int d4 = lane + j * 64;
        float4 g4 = *(const float4*)&gr[d4 * 4];
        float4 b4 = *(const float4*)&br[d4 * 4];
        float4 y;
        y.x = ((gv[j*4+0] - mu) * rstd * g4.x + b4.x) * swk;
        y.y = ((gv[j*4+1] - mu) * rstd * g4.y + b4.y) * swk;
        y.z = ((gv[j*4+2] - mu) * rstd * g4.z + b4.z) * swk;
        y.w = ((gv[j*4+3] - mu) * rstd * g4.w + b4.w) * swk;
        *(float4*)&red[k * 1024 + d4 * 4] = y;
    }
    __syncthreads();
    const int p = threadIdx.x;
    float4 r0 = *(const float4*)&red[0 * 1024 + p * 4];
    float4 r1 = *(const float4*)&red[1 * 1024 + p * 4];
    float4 r2 = *(const float4*)&red[2 * 1024 + p * 4];
    float4 r3 = *(const float4*)&red[3 * 1024 + p * 4];
    float4 o;
    o.x = r0.x + r1.x + r2.x + r3.x;
    o.y = r0.y + r1.y + r2.y + r3.y;
    o.z = r0.z + r1.z + r2.z + r3.z;
    o.w = r0.w + r1.w + r2.w + r3.w;
    *(float4*)&arg[((size_t)f * 4096 + n) * 1024 + p * 4] = o;
}

// ---------------------------------------------------------------------------
// uf = (sum_f fw*arg) * (g2[0]+g2[1]); VQ argmin over 32 codes; gather.
// ---------------------------------------------------------------------------
__global__ __launch_bounds__(256) void final_kernel(
    const float* __restrict__ fw, const float* __restrict__ arg,
    const float* __restrict__ g2, const float* __restrict__ cb,
    float* __restrict__ out)
{
    __shared__ float uf_s[1024];
    __shared__ float score_s[32];
    __shared__ int enc_s;
    const int n = blockIdx.x;
    const int tid = threadIdx.x, w = tid >> 6, lane = tid & 63;

    float4 fwv = *(const float4*)&fw[(size_t)n * 4];
    float fwa[4] = { fwv.x, fwv.y, fwv.z, fwv.w };

    float4 prop = {0, 0, 0, 0};
#pragma unroll
    for (int f = 0; f < 4; ++f) {
        float4 av = *(const float4*)&arg[((size_t)f * 4096 + n) * 1024 + tid * 4];
        prop.x += fwa[f] * av.x; prop.y += fwa[f] * av.y;
        prop.z += fwa[f] * av.z; prop.w += fwa[f] * av.w;
    }
    float4 ga = *(const float4*)&g2[(size_t)n * 1024 + tid * 4];
    float4 gb = *(const float4*)&g2[(size_t)(4096 + n) * 1024 + tid * 4];
    float4 uf;
    uf.x = prop.x * (ga.x + gb.x); uf.y = prop.y * (ga.y + gb.y);
    uf.z = prop.z * (ga.z + gb.z); uf.w = prop.w * (ga.w + gb.w);
    *(float4*)&uf_s[tid * 4] = uf;
    __syncthreads();

#pragma unroll
    for (int cc = 0; cc < 8; ++cc) {
        int c = w * 8 + cc;
        float p = 0.f, q = 0.f;
#pragma unroll
        for (int j = 0; j < 4; ++j) {
            int d4 = lane + j * 64;
            float4 u4 = *(const float4*)&uf_s[d4 * 4];
            float4 c4 = *(const float4*)&cb[(size_t)c * 1024 + d4 * 4];
            p += u4.x * c4.x + u4.y * c4.y + u4.z * c4.z + u4.w * c4.w;
            q += c4.x * c4.x + c4.y * c4.y + c4.z * c4.z + c4.w * c4.w;
        }
        float s = q - 2.0f * p;
        for (int o = 32; o; o >>= 1) s += __shfl_xor(s, o);
        if (lane == 0) score_s[c] = s;
    }
    __syncthreads();
    if (tid < 64) {
        float v; int idx;
        if (lane < 32) { v = score_s[lane]; idx = lane; }
        else           { v = INFINITY;      idx = 1 << 30; }
        for (int o = 16; o; o >>= 1) {
            float ov = __shfl_xor(v, o); int oi = __shfl_xor(idx, o);
            if (ov < v || (ov == v && oi < idx)) { v = ov; idx = oi; }
        }
        if (lane == 0) enc_s = idx;
    }
    __syncthreads();
    const int enc = enc_s;
    float4 o4 = *(const float4*)&cb[(size_t)enc * 1024 + tid * 4];
    *(float4*)&out[(size_t)n * 1024 + tid * 4] = o4;
}

// ---------------------------------------------------------------------------
extern "C" void kernel_launch(void* const* d_in, const int* in_sizes, int n_in,
                              void* d_out, int out_size, void* d_ws, size_t ws_size,
                              hipStream_t stream)
{
    const float* x    = (const float*)d_in[0];
    const float* rf   = (const float*)d_in[1];
    const float* sim  = (const float*)d_in[2];
    const float* Wl   = (const float*)d_in[3];
    const float* bl   = (const float*)d_in[4];
    const float* ln_g = (const float*)d_in[5];
    const float* ln_b = (const float*)d_in[6];
    const float* Wg   = (const float*)d_in[7];
    const float* bg   = (const float*)d_in[8];
    const float* Wsel = (const float*)d_in[9];
    const float* bsel = (const float*)d_in[10];
    const float* dtab = (const float*)d_in[11];
    const float* cb   = (const float*)d_in[12];
    const int*   topk = (const int*)d_in[13];
    float* out = (float*)d_out;
    dim3 blk(256);

    // ws layout (bytes), budget 142,622,720:
    //   arg     @ 0            67,108,864   (xl written in-place, then ln output)
    //   phase B:
    //     de_proj @ 67,108,864  8,404,992   (K-split partials extend into hbuf)
    //     hbuf    @ 75,513,856 33,554,432
    //     Wl1img  @109,068,288 16,777,216
    //     Wl0img  @125,845,504 16,777,216   (ends exactly at budget)
    //   phase C (B pool dead):
    //     Wgimg   @ 67,108,864 33,554,432
    //     g2      @100,663,296 33,554,432
    //     fw      @134,217,728     65,536
    const size_t NEED = 142622720ull;
    if (ws_size < NEED) return;
    char* ws = (char*)d_ws;
    float* arg     = (float*)(ws + 0);
    float* de_proj = (float*)(ws + 67108864);
    float* hbuf    = (float*)(ws + 75513856);
    char*  Wl1img  = ws + 109068288;
    char*  Wl0img  = ws + 125845504;
    char*  Wgimg   = ws + 67108864;
    float* g2      = (float*)(ws + 100663296);
    float* fw      = (float*)(ws + 134217728);

    // 1) de_proj partials (K-split x4, 640 blocks) + deterministic reduce
    deproj_part<<<dim3(5, 8, 16), blk, 0, stream>>>(dtab, Wl, de_proj);
    deproj_reduce<<<2052, blk, 0, stream>>>(de_proj);

    // 2) Wl0 image; xl4: arg[f] = x @ Wl0img[f]  (1024 blocks, image path)
    precvt_img<<<512, blk, 0, stream>>>(Wl, Wl0img, 0, 5, 99);
    gemm_img<<<dim3(32, 8, 4), blk, 0, stream>>>(
        x, 0, Wl0img, 0, arg, (size_t)4096 * 1024);

    // 3) Wl1 image
    precvt_img<<<512, blk, 0, stream>>>(Wl, Wl1img, 1024, 5, 99);

    // 4) per f, per chunk: h GEMM (image path) + fused GELU/LN/softmax-reduce
    for (int f = 0; f < 4; ++f) {
        const float* xlf = arg + (size_t)f * 4096 * 1024;
        for (int ch = 0; ch < 2; ++ch) {
            gemm_img<<<dim3(64, 8, 1), blk, 0, stream>>>(
                rf, ch * 8192, Wl1img, f, hbuf, 0);
            ln_fuse_kernel<<<2048, blk, 0, stream>>>(
                hbuf, de_proj, bl, ln_g, ln_b, sim, topk, arg,
                f, ch * 2048, xlf);
        }
    }

    // 5) Wg image (summed k>=1024) — phase-B pool dead
    precvt_img<<<1024, blk, 0, stream>>>(Wg, Wgimg, 0, 6, 32);

    // 6) fw = softmax(x @ Wsel + bsel)
    fw_kernel<<<4096, blk, 0, stream>>>(x, Wsel, bsel, fw);

    // 7) g2[z] = fw[:,z] * sigmoid([x|arg_z] @ Wg[z] + bg[z]); then += f=z+2
    gate_img<<<dim3(32, 8, 2), blk, 0, stream>>>(x, arg, Wgimg, fw, bg, g2, 0);
    gate_img<<<dim3(32, 8, 2), blk, 0, stream>>>(x, arg, Wgimg, fw, bg, g2, 2);

    // 8) uf = (sum_f fw*arg) * (g2[0]+g2[1]); VQ argmin; codebook gather
    final_kernel<<<4096, blk, 0, stream>>>(fw, arg, g2, cb, out);
}